// Round 8
// baseline (6193.790 us; speedup 1.0000x reference)
//
#include <hip/hip_runtime.h>
#include <math.h>
#include <stdio.h>
#include <stdint.h>

#define NH 256
#define NH3 768
#define FNODE 133
#define FEDGE 7
#define LDW_GATE1 263   // H + F_EDGE
#define NGRAPH 4096
#define NTASK 12
#define SLOPE 0.01f
#define CHUNK 12500
#define PADK 40         // f16 elems per LDS row: 32 + 8 pad (80B stride, 16B aligned)
#define KPAD_X 160      // x padded K (133 -> 160)

typedef __attribute__((ext_vector_type(4))) float f32x4;
typedef __attribute__((ext_vector_type(8))) _Float16 f16x8;

static __device__ __forceinline__ float lrelu_f(float x) { return x > 0.f ? x : SLOPE * x; }

// ---------------- MFMA fp16 GEMM core (BM=64, BN=256) ----------------
// C[M,Nout] = act(A[M,K] @ W[Nout, ldW]^T + bias)
// ACT: 0 none, 1 lrelu, 2 elu ; OB: 0 f32 out, 1 fp16 out ; AF16: A is f16
// Kw: valid K range for W reads (cols beyond Kw read as 0; A must be 0-padded there)
template<int ACT, int OB, int AF16>
static __device__ __forceinline__ void gemm_core(
    _Float16* As, _Float16* Ws,
    const void* __restrict__ Av, const float* __restrict__ W,
    const float* __restrict__ bias, void* __restrict__ Cout,
    int M, int K, int Nout, int ldW, int Kw)
{
    const int bm = blockIdx.y * 64;
    const int bn = blockIdx.x * 256;
    const int tid = threadIdx.x;
    const int wv = tid >> 6, lane = tid & 63;
    const int l15 = lane & 15, l4 = lane >> 4;
    const bool kvec = ((K & 31) == 0);
    const bool wvec = kvec && ((ldW & 3) == 0) && (Kw == K);
    const int ar = tid >> 2, akq = (tid & 3) * 8;   // 16B-chunk staging (2-way banks, free)

    f32x4 acc[16];
#pragma unroll
    for (int c = 0; c < 16; ++c) acc[c] = (f32x4){0.f, 0.f, 0.f, 0.f};

    for (int k0 = 0; k0 < K; k0 += 32) {
        // ---- stage A: 64 rows x 32 k ; 8 f16 (16B) per thread
        {
            const int ga = bm + ar;
            _Float16* dstA = &As[ar * PADK + akq];
            if (AF16) {
                const _Float16* A = (const _Float16*)Av;
                if (ga < M) {
                    *reinterpret_cast<f16x8*>(dstA) =
                        *reinterpret_cast<const f16x8*>(A + (size_t)ga * K + k0 + akq);
                } else {
#pragma unroll
                    for (int j = 0; j < 8; ++j) dstA[j] = (_Float16)0.f;
                }
            } else {
                const float* A = (const float*)Av;
                if (ga < M && kvec) {
                    const float4* ap4 = reinterpret_cast<const float4*>(A + (size_t)ga * K + k0 + akq);
                    float4 v0 = ap4[0], v1 = ap4[1];
                    dstA[0] = (_Float16)v0.x; dstA[1] = (_Float16)v0.y;
                    dstA[2] = (_Float16)v0.z; dstA[3] = (_Float16)v0.w;
                    dstA[4] = (_Float16)v1.x; dstA[5] = (_Float16)v1.y;
                    dstA[6] = (_Float16)v1.z; dstA[7] = (_Float16)v1.w;
                } else {
                    const float* ap = A + (size_t)ga * K + k0 + akq;
#pragma unroll
                    for (int j = 0; j < 8; ++j) {
                        int gk = k0 + akq + j;
                        float v = (ga < M && gk < K) ? ap[j] : 0.f;
                        dstA[j] = (_Float16)v;
                    }
                }
            }
        }
        // ---- stage W: 256 rows x 32 k ; 4 chunks of 8 f16 per thread
#pragma unroll
        for (int q = 0; q < 4; ++q) {
            const int r = ar + 64 * q;
            const int gw = bn + r;
            _Float16* dstW = &Ws[r * PADK + akq];
            if (gw < Nout && wvec) {
                const float4* wp4 = reinterpret_cast<const float4*>(W + (size_t)gw * ldW + k0 + akq);
                float4 v0 = wp4[0], v1 = wp4[1];
                dstW[0] = (_Float16)v0.x; dstW[1] = (_Float16)v0.y;
                dstW[2] = (_Float16)v0.z; dstW[3] = (_Float16)v0.w;
                dstW[4] = (_Float16)v1.x; dstW[5] = (_Float16)v1.y;
                dstW[6] = (_Float16)v1.z; dstW[7] = (_Float16)v1.w;
            } else {
                const float* wp = W + (size_t)gw * ldW + k0 + akq;
#pragma unroll
                for (int j = 0; j < 8; ++j) {
                    int gk = k0 + akq + j;
                    float v = (gw < Nout && gk < Kw) ? wp[j] : 0.f;
                    dstW[j] = (_Float16)v;
                }
            }
        }
        __syncthreads();
        f16x8 af = *reinterpret_cast<const f16x8*>(&As[(wv * 16 + l15) * PADK + l4 * 8]);
#pragma unroll
        for (int c = 0; c < 16; ++c) {
            f16x8 wf = *reinterpret_cast<const f16x8*>(&Ws[(c * 16 + l15) * PADK + l4 * 8]);
            acc[c] = __builtin_amdgcn_mfma_f32_16x16x32_f16(af, wf, acc[c], 0, 0, 0);
        }
        __syncthreads();
    }

#pragma unroll
    for (int c = 0; c < 16; ++c) {
        int gc = bn + c * 16 + l15;
        if (gc >= Nout) continue;
        float bv = bias ? bias[gc] : 0.f;
#pragma unroll
        for (int q = 0; q < 4; ++q) {
            int gr = bm + wv * 16 + l4 * 4 + q;
            if (gr >= M) continue;
            float v = acc[c][q] + bv;
            if (ACT == 1) v = lrelu_f(v);
            else if (ACT == 2) v = (v > 0.f ? v : expm1f(v));
            size_t off = (size_t)gr * Nout + gc;
            if (OB) ((_Float16*)Cout)[off] = (_Float16)v;
            else    ((float*)Cout)[off] = v;
        }
    }
}

template<int ACT, int OB, int AF16>
__global__ __launch_bounds__(256, 4) void gemm_mfma(
    const void* __restrict__ A, const float* __restrict__ W,
    const float* __restrict__ bias, void* __restrict__ Cout,
    int M, int K, int Nout, int ldW, int Kw)
{
    __shared__ _Float16 As[64 * PADK];
    __shared__ _Float16 Ws[256 * PADK];
    gemm_core<ACT, OB, AF16>(As, Ws, A, W, bias, Cout, M, K, Nout, ldW, Kw);
}

// dual GEMM: z=0 -> C0 = A0@W0^T ; z=1 -> C1 = A1@W1^T  (no bias/act), ldW=K
template<int ACT, int OB, int AF16>
__global__ __launch_bounds__(256, 4) void gemm_mfma2(
    const void* __restrict__ A0, const void* __restrict__ A1,
    const float* __restrict__ W0, const float* __restrict__ W1,
    void* __restrict__ C0, void* __restrict__ C1,
    int M, int K, int Nout)
{
    __shared__ _Float16 As[64 * PADK];
    __shared__ _Float16 Ws[256 * PADK];
    if (blockIdx.z == 0)
        gemm_core<ACT, OB, AF16>(As, Ws, A0, W0, nullptr, C0, M, K, Nout, K, K);
    else
        gemm_core<ACT, OB, AF16>(As, Ws, A1, W1, nullptr, C1, M, K, Nout, K, K);
}

// pad + cast: out[r, k] = k < Kin ? (f16)in[r, k] : 0
__global__ void pad_cast_f16(const float* __restrict__ in, _Float16* __restrict__ out,
                             int M, int Kin, int Kout)
{
    size_t i = (size_t)blockIdx.x * 256 + threadIdx.x;
    if (i >= (size_t)M * Kout) return;
    int r = (int)(i / Kout), k = (int)(i % Kout);
    out[i] = (k < Kin) ? (_Float16)in[(size_t)r * Kin + k] : (_Float16)0.f;
}

// ---------------- fp32 fallback GEMM (final 12-col fc only) ----------------
__global__ __launch_bounds__(256) void gemm_nt(
    const float* __restrict__ A, const float* __restrict__ W,
    const float* __restrict__ bias, float* __restrict__ C,
    int M, int K, int Nout, int ldW, int act)
{
    __shared__ float As[16][65];
    __shared__ float Ws[16][65];
    const int bm = blockIdx.y * 64;
    const int bn = blockIdx.x * 64;
    const int tid = threadIdx.x;
    const int tr = tid >> 4, tc = tid & 15;
    const int lrow = tid >> 2, lk = (tid & 3) * 4;
    float acc[4][4] = {};
    for (int k0 = 0; k0 < K; k0 += 16) {
#pragma unroll
        for (int j = 0; j < 4; ++j) {
            int gk = k0 + lk + j;
            int ga = bm + lrow;
            As[lk + j][lrow] = (ga < M && gk < K) ? A[(size_t)ga * K + gk] : 0.f;
            int gw = bn + lrow;
            Ws[lk + j][lrow] = (gw < Nout && gk < K) ? W[(size_t)gw * ldW + gk] : 0.f;
        }
        __syncthreads();
#pragma unroll
        for (int kk = 0; kk < 16; ++kk) {
            float av[4], bv[4];
#pragma unroll
            for (int i = 0; i < 4; ++i) av[i] = As[kk][tr * 4 + i];
#pragma unroll
            for (int i = 0; i < 4; ++i) bv[i] = Ws[kk][tc * 4 + i];
#pragma unroll
            for (int i = 0; i < 4; ++i)
#pragma unroll
                for (int j = 0; j < 4; ++j) acc[i][j] += av[i] * bv[j];
        }
        __syncthreads();
    }
#pragma unroll
    for (int i = 0; i < 4; ++i) {
        int m = bm + tr * 4 + i;
        if (m >= M) continue;
#pragma unroll
        for (int j = 0; j < 4; ++j) {
            int n = bn + tc * 4 + j;
            if (n >= Nout) continue;
            float v = acc[i][j];
            if (bias) v += bias[n];
            if (act == 1) v = lrelu_f(v);
            C[(size_t)m * Nout + n] = v;
        }
    }
}

// ---------------- CSR/CSC build ----------------
__global__ void zero_i32(int* p, int n) {
    int i = blockIdx.x * 256 + threadIdx.x;
    if (i < n) p[i] = 0;
}
__global__ void hist_k(const int* __restrict__ key, int* __restrict__ deg, int E) {
    int i = blockIdx.x * 256 + threadIdx.x;
    if (i < E) atomicAdd(&deg[key[i]], 1);
}
__global__ __launch_bounds__(256) void scan_rowptr(
    const int* __restrict__ deg, int* __restrict__ rowptr, int* __restrict__ cursor, int Nn)
{
    __shared__ int lds[256];
    const int t = threadIdx.x;
    const int C = (Nn + 255) / 256;
    const int lo = t * C, hi = min((t + 1) * C, Nn);
    int s = 0;
    for (int i = lo; i < hi; ++i) s += deg[i];
    lds[t] = s;
    __syncthreads();
    for (int off = 1; off < 256; off <<= 1) {
        int v = (t >= off) ? lds[t - off] : 0;
        __syncthreads();
        lds[t] += v;
        __syncthreads();
    }
    int run = lds[t] - s;
    for (int i = lo; i < hi; ++i) {
        rowptr[i] = run; cursor[i] = run; run += deg[i];
    }
    if (lo < Nn && hi >= Nn) rowptr[Nn] = run;
}
__global__ void csr_scatter(const int* __restrict__ src, const int* __restrict__ dst,
                            int* __restrict__ cursor, int* __restrict__ esrc,
                            int* __restrict__ pos, int E)
{
    int e = blockIdx.x * 256 + threadIdx.x;
    if (e < E) {
        int p = atomicAdd(&cursor[dst[e]], 1);
        esrc[p] = src[e];
        pos[e] = p;
    }
}
__global__ void csc_scatter(const int* __restrict__ src, int* __restrict__ cursor,
                            int* __restrict__ seid, int E)
{
    int e = blockIdx.x * 256 + threadIdx.x;
    if (e < E) {
        int p = atomicAdd(&cursor[src[e]], 1);
        seid[p] = e;
    }
}
__global__ void gptr_build(const int* __restrict__ batch, int* __restrict__ gptr, int Nn, int G) {
    int g = blockIdx.x * 256 + threadIdx.x;
    if (g > G) return;
    int lo = 0, hi = Nn;
    while (lo < hi) { int mid = (lo + hi) >> 1; if (batch[mid] < g) lo = mid + 1; else hi = mid; }
    gptr[g] = lo;
}

// ---------------- GATE src-side partial logit (CSC, 8 edges/wave) ----------------
// elogp[pos[e]] = dot(lrelu(nodepart[s] + edge_attr[e]@W1b^T), att_l)
// wave = one src node; 8 groups x 8 lanes; lane covers h = (lane&7) + 8*hh
__global__ __launch_bounds__(256) void gate_part_csc(
    const _Float16* __restrict__ nodepart, const float* __restrict__ edge_attr,
    const float* __restrict__ gate_lin1_w, const float* __restrict__ att_l,
    const int* __restrict__ srowptr, const int* __restrict__ seid, const int* __restrict__ pos,
    float* __restrict__ elogp, int Nn)
{
    __shared__ float wrs[NH * 8];   // [h][8]: wr[0..6], al at [7]
    int tid = threadIdx.x;
    {
        const float* wp = gate_lin1_w + (size_t)tid * LDW_GATE1 + NH;
#pragma unroll
        for (int f = 0; f < FEDGE; ++f) wrs[tid * 8 + f] = wp[f];
        wrs[tid * 8 + 7] = att_l[tid];
    }
    __syncthreads();
    int wv = tid >> 6, lane = tid & 63;
    int grp = lane >> 3, hsl = lane & 7;
    for (int s = blockIdx.x * 4 + wv; s < Nn; s += gridDim.x * 4) {
        int beg = srowptr[s], end = srowptr[s + 1];
        if (beg >= end) continue;
        float np[32];
#pragma unroll
        for (int hh = 0; hh < 32; ++hh)
            np[hh] = (float)nodepart[(size_t)s * NH + hsl + 8 * hh];
        for (int j0 = beg; j0 < end; j0 += 8) {
            int j = j0 + grp;
            bool active = (j < end);
            int e = active ? seid[j] : seid[beg];
            const float* ep = edge_attr + (size_t)e * FEDGE;
            float ea[FEDGE];
#pragma unroll
            for (int f = 0; f < FEDGE; ++f) ea[f] = ep[f];
            float acc = 0.f;
#pragma unroll
            for (int hh = 0; hh < 32; ++hh) {
                int h = hsl + 8 * hh;
                float4 w0 = *reinterpret_cast<const float4*>(&wrs[h * 8]);
                float4 w1 = *reinterpret_cast<const float4*>(&wrs[h * 8 + 4]);
                float v = np[hh] + ea[0] * w0.x + ea[1] * w0.y + ea[2] * w0.z + ea[3] * w0.w
                                 + ea[4] * w1.x + ea[5] * w1.y + ea[6] * w1.z;
                acc += lrelu_f(v) * w1.w;
            }
            acc += __shfl_xor(acc, 1);
            acc += __shfl_xor(acc, 2);
            acc += __shfl_xor(acc, 4);
            if (active && hsl == 0) elogp[pos[e]] = acc;
        }
    }
}

// ---------------- fused attention aggregation (CSR, wave per dst) ----------------
__global__ __launch_bounds__(256) void gat_agg_csr(
    const _Float16* __restrict__ X, const float* __restrict__ asrc, const float* __restrict__ adst,
    const int* __restrict__ rowptr, const int* __restrict__ esrc,
    _Float16* __restrict__ hout, int Nn)
{
    int wv = threadIdx.x >> 6, lane = threadIdx.x & 63;
    int d = blockIdx.x * 4 + wv;
    if (d >= Nn) return;
    int beg = rowptr[d], end = rowptr[d + 1];
    float a0 = 0.f, a1 = 0.f, a2 = 0.f, a3 = 0.f;
    if (beg < end) {
        float ad = adst[d];
        float m = -3.4e38f;
        for (int j = beg + lane; j < end; j += 64)
            m = fmaxf(m, lrelu_f(asrc[esrc[j]] + ad));
#pragma unroll
        for (int off = 32; off; off >>= 1) m = fmaxf(m, __shfl_xor(m, off));
        float s = 0.f;
        for (int j = beg + lane; j < end; j += 64)
            s += expf(lrelu_f(asrc[esrc[j]] + ad) - m);
#pragma unroll
        for (int off = 32; off; off >>= 1) s += __shfl_xor(s, off);
        float inv = 1.f / (s + 1e-16f);
        for (int j = beg; j < end; ++j) {
            int sj = esrc[j];
            float a = expf(lrelu_f(asrc[sj] + ad) - m) * inv;
            const _Float16* xr = X + (size_t)sj * NH;
            a0 += a * (float)xr[lane];       a1 += a * (float)xr[64 + lane];
            a2 += a * (float)xr[128 + lane]; a3 += a * (float)xr[192 + lane];
        }
    }
    _Float16* hr = hout + (size_t)d * NH;
    hr[lane] = (_Float16)a0; hr[64 + lane] = (_Float16)a1;
    hr[128 + lane] = (_Float16)a2; hr[192 + lane] = (_Float16)a3;
}

__global__ __launch_bounds__(256) void gate_agg_csr(
    const _Float16* __restrict__ X, const float* __restrict__ elogp, const float* __restrict__ dotr,
    const int* __restrict__ rowptr, const int* __restrict__ esrc,
    _Float16* __restrict__ hout, int Nn)
{
    int wv = threadIdx.x >> 6, lane = threadIdx.x & 63;
    int d = blockIdx.x * 4 + wv;
    if (d >= Nn) return;
    int beg = rowptr[d], end = rowptr[d + 1];
    float a0 = 0.f, a1 = 0.f, a2 = 0.f, a3 = 0.f;
    if (beg < end) {
        float dd = dotr[d];
        float m = -3.4e38f;
        for (int j = beg + lane; j < end; j += 64)
            m = fmaxf(m, lrelu_f(elogp[j] + dd));
#pragma unroll
        for (int off = 32; off; off >>= 1) m = fmaxf(m, __shfl_xor(m, off));
        float s = 0.f;
        for (int j = beg + lane; j < end; j += 64)
            s += expf(lrelu_f(elogp[j] + dd) - m);
#pragma unroll
        for (int off = 32; off; off >>= 1) s += __shfl_xor(s, off);
        float inv = 1.f / (s + 1e-16f);
        for (int j = beg; j < end; ++j) {
            int sj = esrc[j];
            float a = expf(lrelu_f(elogp[j] + dd) - m) * inv;
            const _Float16* xr = X + (size_t)sj * NH;
            a0 += a * (float)xr[lane];       a1 += a * (float)xr[64 + lane];
            a2 += a * (float)xr[128 + lane]; a3 += a * (float)xr[192 + lane];
        }
    }
    _Float16* hr = hout + (size_t)d * NH;
    hr[lane] = (_Float16)a0; hr[64 + lane] = (_Float16)a1;
    hr[128 + lane] = (_Float16)a2; hr[192 + lane] = (_Float16)a3;
}

__global__ __launch_bounds__(256) void mol_agg_csr(
    const _Float16* __restrict__ X, const float* __restrict__ dotr, const float* __restrict__ ddot,
    const int* __restrict__ gptr, float* __restrict__ hout, int G)
{
    int wv = threadIdx.x >> 6, lane = threadIdx.x & 63;
    int g = blockIdx.x * 4 + wv;
    if (g >= G) return;
    int beg = gptr[g], end = gptr[g + 1];
    float a0 = 0.f, a1 = 0.f, a2 = 0.f, a3 = 0.f;
    if (beg < end) {
        float dg = ddot[g];
        float m = -3.4e38f;
        for (int i = beg + lane; i < end; i += 64)
            m = fmaxf(m, lrelu_f(dotr[i] + dg));
#pragma unroll
        for (int off = 32; off; off >>= 1) m = fmaxf(m, __shfl_xor(m, off));
        float s = 0.f;
        for (int i = beg + lane; i < end; i += 64)
            s += expf(lrelu_f(dotr[i] + dg) - m);
#pragma unroll
        for (int off = 32; off; off >>= 1) s += __shfl_xor(s, off);
        float inv = 1.f / (s + 1e-16f);
        for (int i = beg; i < end; ++i) {
            float a = expf(lrelu_f(dotr[i] + dg) - m) * inv;
            const _Float16* xr = X + (size_t)i * NH;
            a0 += a * (float)xr[lane];       a1 += a * (float)xr[64 + lane];
            a2 += a * (float)xr[128 + lane]; a3 += a * (float)xr[192 + lane];
        }
    }
    float* hr = hout + (size_t)g * NH;
    hr[lane] = a0; hr[64 + lane] = a1; hr[128 + lane] = a2; hr[192 + lane] = a3;
}

__global__ __launch_bounds__(256) void graph_sum_relu(
    const _Float16* __restrict__ X, const int* __restrict__ gptr, float* __restrict__ out, int G)
{
    int wv = threadIdx.x >> 6, lane = threadIdx.x & 63;
    int g = blockIdx.x * 4 + wv;
    if (g >= G) return;
    int beg = gptr[g], end = gptr[g + 1];
    float a0 = 0.f, a1 = 0.f, a2 = 0.f, a3 = 0.f;
    for (int i = beg; i < end; ++i) {
        const _Float16* xr = X + (size_t)i * NH;
        a0 += (float)xr[lane];       a1 += (float)xr[64 + lane];
        a2 += (float)xr[128 + lane]; a3 += (float)xr[192 + lane];
    }
    float* hr = out + (size_t)g * NH;
    hr[lane] = fmaxf(a0, 0.f); hr[64 + lane] = fmaxf(a1, 0.f);
    hr[128 + lane] = fmaxf(a2, 0.f); hr[192 + lane] = fmaxf(a3, 0.f);
}

template<typename TX>
__global__ __launch_bounds__(256) void node_dot(
    const TX* __restrict__ X, const float* __restrict__ v1, const float* __restrict__ v2,
    float* __restrict__ o1, float* __restrict__ o2, int M)
{
    __shared__ float s1[NH], s2[NH];
    int tid = threadIdx.x;
    s1[tid] = v1[tid];
    s2[tid] = v2 ? v2[tid] : 0.f;
    __syncthreads();
    int wv = tid >> 6, lane = tid & 63;
    for (int n = blockIdx.x * 4 + wv; n < M; n += gridDim.x * 4) {
        float a1 = 0.f, a2 = 0.f;
#pragma unroll
        for (int i = 0; i < 4; ++i) {
            int hh = i * 64 + lane;
            float xv = (float)X[(size_t)n * NH + hh];
            a1 += xv * s1[hh];
            a2 += xv * s2[hh];
        }
#pragma unroll
        for (int off = 32; off; off >>= 1) { a1 += __shfl_xor(a1, off); a2 += __shfl_xor(a2, off); }
        if (lane == 0) { o1[n] = a1; if (o2) o2[n] = a2; }
    }
}

__global__ __launch_bounds__(256) void matvec_left(
    const float* __restrict__ Wm, const float* __restrict__ a, float* __restrict__ v)
{
    int j = threadIdx.x;
    float s = 0.f;
    for (int i = 0; i < NH; ++i) s += a[i] * Wm[(size_t)i * NH + j];
    v[j] = s;
}

// GRU combine (gates r,z,n) + ReLU ; gi/gh f16 ; hprev/out TH ; 8 elems/thread
template<typename TH>
__global__ __launch_bounds__(256) void gru_combine(
    const _Float16* __restrict__ gi, const _Float16* __restrict__ gh,
    const float* __restrict__ b_ih, const float* __restrict__ b_hh,
    const TH* __restrict__ hprev, TH* __restrict__ out, int M)
{
    size_t t = (size_t)blockIdx.x * 256 + threadIdx.x;
    if (t >= (size_t)M * 32) return;
    int n = (int)(t >> 5), j0 = ((int)t & 31) * 8;
    size_t b3 = (size_t)n * NH3;
    f16x8 vir = *reinterpret_cast<const f16x8*>(&gi[b3 + j0]);
    f16x8 viz = *reinterpret_cast<const f16x8*>(&gi[b3 + NH + j0]);
    f16x8 vin = *reinterpret_cast<const f16x8*>(&gi[b3 + 2 * NH + j0]);
    f16x8 vhr = *reinterpret_cast<const f16x8*>(&gh[b3 + j0]);
    f16x8 vhz = *reinterpret_cast<const f16x8*>(&gh[b3 + NH + j0]);
    f16x8 vhn = *reinterpret_cast<const f16x8*>(&gh[b3 + 2 * NH + j0]);
    size_t hb = (size_t)n * NH + j0;
    float hp[8];
#pragma unroll
    for (int q = 0; q < 8; ++q) hp[q] = (float)hprev[hb + q];
    float o[8];
#pragma unroll
    for (int q = 0; q < 8; ++q) {
        int j = j0 + q;
        float ir = (float)vir[q] + b_ih[j];
        float iz = (float)viz[q] + b_ih[NH + j];
        float inn = (float)vin[q] + b_ih[2 * NH + j];
        float hr = (float)vhr[q] + b_hh[j];
        float hz = (float)vhz[q] + b_hh[NH + j];
        float hn = (float)vhn[q] + b_hh[2 * NH + j];
        float r = 1.f / (1.f + expf(-(ir + hr)));
        float z = 1.f / (1.f + expf(-(iz + hz)));
        float nn = tanhf(inn + r * hn);
        o[q] = fmaxf((1.f - z) * nn + z * hp[q], 0.f);
    }
#pragma unroll
    for (int q = 0; q < 8; ++q) out[hb + q] = (TH)o[q];
}

extern "C" void kernel_launch(void* const* d_in, const int* in_sizes, int n_in,
                              void* d_out, int out_size, void* d_ws, size_t ws_size,
                              hipStream_t stream)
{
    const float* x          = (const float*)d_in[0];
    const float* edge_attr  = (const float*)d_in[1];
    const float* lin1_w     = (const float*)d_in[2];
    const float* lin1_b     = (const float*)d_in[3];
    const float* gate_att_l = (const float*)d_in[4];
    const float* gate_att_r = (const float*)d_in[5];
    const float* gate_lin1_w= (const float*)d_in[6];
    const float* gate_lin2_w= (const float*)d_in[7];
    const float* gate_bias  = (const float*)d_in[8];
    const float* atom_lin_w = (const float*)d_in[9];
    const float* atom_att_src=(const float*)d_in[10];
    const float* atom_att_dst=(const float*)d_in[11];
    const float* atom_bias  = (const float*)d_in[12];
    const float* gru_w_ih   = (const float*)d_in[13];
    const float* gru_w_hh   = (const float*)d_in[14];
    const float* gru_b_ih   = (const float*)d_in[15];
    const float* gru_b_hh   = (const float*)d_in[16];
    const float* mol_lin_w  = (const float*)d_in[17];
    const float* mol_att_src= (const float*)d_in[18];
    const float* mol_att_dst= (const float*)d_in[19];
    const float* mol_bias   = (const float*)d_in[20];
    const float* mol_gru_w_ih=(const float*)d_in[21];
    const float* mol_gru_w_hh=(const float*)d_in[22];
    const float* mol_gru_b_ih=(const float*)d_in[23];
    const float* mol_gru_b_hh=(const float*)d_in[24];
    const float* lin2_w     = (const float*)d_in[25];
    const float* lin2_b     = (const float*)d_in[26];
    const float* fc_w       = (const float*)d_in[27];
    const float* fc_b       = (const float*)d_in[28];
    const int*   edge_index = (const int*)d_in[29];
    const int*   batch      = (const int*)d_in[30];

    const int N = in_sizes[0] / FNODE;
    const int E = in_sizes[1] / FEDGE;
    const int G = NGRAPH;
    const int* src = edge_index;
    const int* dst = edge_index + E;

    float* w = (float*)d_ws;
    size_t o = 0;
    auto alloc = [&](size_t cnt) { size_t r = o; o += cnt; return r; };
    const size_t o_B1    = alloc((size_t)N * NH / 2);      // f16 x0 -> xcur
    const size_t o_B2    = alloc((size_t)N * NH / 2);      // f16 nodepart -> hraw ; mol f32 bufs
    const size_t o_B3    = alloc((size_t)CHUNK * 896);     // tmp f16(256) + gi/gh f16(768 ea)
    const size_t o_elog  = alloc((size_t)E);
    const size_t o_dotr  = alloc((size_t)N);
    const size_t o_adst  = alloc((size_t)N);
    const size_t o_ddot  = alloc((size_t)G);
    const size_t o_vvec  = alloc((size_t)NH);
    const size_t o_usrc  = alloc((size_t)NH);
    const size_t o_udst  = alloc((size_t)NH);
    const size_t o_rowp  = alloc((size_t)N + 1);
    const size_t o_srowp = alloc((size_t)N + 1);
    const size_t o_deg   = alloc((size_t)N);
    const size_t o_curs  = alloc((size_t)N);
    const size_t o_esrc  = alloc((size_t)E);
    const size_t o_pos   = alloc((size_t)E);
    const size_t o_seid  = alloc((size_t)E);
    const size_t o_gptr  = alloc((size_t)G + 1);
    if (o * sizeof(float) > ws_size) {
        fprintf(stderr, "kernel_launch: ws too small: need %zu have %zu\n", o * 4, ws_size);
        return;
    }

    _Float16* B1 = (_Float16*)(w + o_B1);
    _Float16* B2 = (_Float16*)(w + o_B2);
    float* B3   = w + o_B3;
    float* elog = w + o_elog;
    float* dotr = w + o_dotr;
    float* adst = w + o_adst;
    float* ddot = w + o_ddot;
    float* vvec = w + o_vvec;
    float* usrc = w + o_usrc;
    float* udst = w + o_udst;
    int* rowptr  = (int*)(w + o_rowp);
    int* srowptr = (int*)(w + o_srowp);
    int* deg     = (int*)(w + o_deg);
    int* cursor  = (int*)(w + o_curs);
    int* esrc    = (int*)(w + o_esrc);
    int* pos     = (int*)(w + o_pos);
    int* seid    = (int*)(w + o_seid);
    int* gptr    = (int*)(w + o_gptr);

    // mol-phase sub-buffers inside B2 (f32 views; node hraw dead by then)
    float* B2f = (float*)B2;
    float*    gout   = B2f;                                     // G*NH f32
    float*    hraw_g = B2f + (size_t)G * NH;                    // G*NH f32
    float*    h_g    = B2f + (size_t)2 * G * NH;                // G*NH f32
    _Float16* gig    = (_Float16*)(B2f + (size_t)3 * G * NH);   // G*NH3 f16
    _Float16* ghg    = (_Float16*)(B2f + (size_t)3 * G * NH + (size_t)G * NH3 / 2);
    float*    emb    = B2f + (size_t)3 * G * NH + (size_t)G * NH3;

    const int BLK = 256;
    auto cdiv = [](size_t a, size_t b) { return (int)((a + b - 1) / b); };
    const int gridNodeWave = cdiv(N, 4);
    const int gridEdgeThr = cdiv(E, BLK);
    const int gridNodeThr = cdiv(N, BLK);
    const int CAP = 4096;
    const int gridNodeCap = gridNodeWave < CAP ? gridNodeWave : CAP;

    // ---------- CSR + CSC build (once) ----------
    zero_i32<<<gridNodeThr, BLK, 0, stream>>>(deg, N);
    hist_k<<<gridEdgeThr, BLK, 0, stream>>>(dst, deg, E);
    scan_rowptr<<<1, BLK, 0, stream>>>(deg, rowptr, cursor, N);
    csr_scatter<<<gridEdgeThr, BLK, 0, stream>>>(src, dst, cursor, esrc, pos, E);
    zero_i32<<<gridNodeThr, BLK, 0, stream>>>(deg, N);
    hist_k<<<gridEdgeThr, BLK, 0, stream>>>(src, deg, E);
    scan_rowptr<<<1, BLK, 0, stream>>>(deg, srowptr, cursor, N);
    csc_scatter<<<gridEdgeThr, BLK, 0, stream>>>(src, cursor, seid, E);
    gptr_build<<<cdiv(G + 1, BLK), BLK, 0, stream>>>(batch, gptr, N, G);

    // Per-layer tail: h = elu(hraw@Wh^T + bh) ; GRU(h, xbuf) -> xbuf (chunked, in place)
    auto run_tail = [&](const float* Wh, const float* bh,
                        const float* wih, const float* whh,
                        const float* bih, const float* bhh, _Float16* xbuf) {
        _Float16* tmp = (_Float16*)B3;                        // CHUNK*NH f16
        _Float16* gi  = (_Float16*)(B3 + (size_t)CHUNK * 128);// CHUNK*NH3 f16
        _Float16* gh  = (_Float16*)(B3 + (size_t)CHUNK * 512);// CHUNK*NH3 f16
        for (int c0 = 0; c0 < N; c0 += CHUNK) {
            int mc = (N - c0) < CHUNK ? (N - c0) : CHUNK;
            dim3 gH(1, cdiv(mc, 64));
            dim3 gD(3, cdiv(mc, 64), 2);
            gemm_mfma<2, 1, 1><<<gH, BLK, 0, stream>>>(B2 + (size_t)c0 * NH, Wh, bh, tmp,
                                                       mc, NH, NH, NH, NH);
            gemm_mfma2<0, 1, 1><<<gD, BLK, 0, stream>>>(tmp, xbuf + (size_t)c0 * NH, wih, whh,
                                                        gi, gh, mc, NH, NH3);
            gru_combine<_Float16><<<cdiv((size_t)mc * 32, BLK), BLK, 0, stream>>>(
                gi, gh, bih, bhh, xbuf + (size_t)c0 * NH, xbuf + (size_t)c0 * NH, mc);
        }
    };

    dim3 gridNH(1, cdiv(N, 64));

    // ---------- x0 = lrelu(x @ lin1_w^T + lin1_b) via padded f16 A ----------
    _Float16* xpad = (_Float16*)B3;     // N*160 f16 = 32 MB < B3 (44.8 MB); dead before tails
    pad_cast_f16<<<cdiv((size_t)N * KPAD_X, BLK), BLK, 0, stream>>>(x, xpad, N, FNODE, KPAD_X);
    gemm_mfma<1, 1, 1><<<gridNH, BLK, 0, stream>>>(xpad, lin1_w, lin1_b, B1,
                                                   N, KPAD_X, NH, FNODE, FNODE);

    // ---------- GATEConv ----------
    gemm_mfma<0, 1, 1><<<gridNH, BLK, 0, stream>>>(B1, gate_lin1_w, nullptr, B2,
                                                   N, NH, NH, LDW_GATE1, NH);
    node_dot<_Float16><<<gridNodeCap, BLK, 0, stream>>>(B1, gate_att_r, nullptr, dotr, nullptr, N);
    gate_part_csc<<<gridNodeCap, BLK, 0, stream>>>(B2, edge_attr, gate_lin1_w, gate_att_l,
                                                   srowptr, seid, pos, elog, N);
    gate_agg_csr<<<gridNodeWave, BLK, 0, stream>>>(B1, elog, dotr, rowptr, esrc, B2, N);
    run_tail(gate_lin2_w, gate_bias, gru_w_ih, gru_w_hh, gru_b_ih, gru_b_hh, B1);

    // ---------- 3 GATConv layers ----------
    for (int l = 0; l < 3; ++l) {
        const float* wl = atom_lin_w + (size_t)l * NH * NH;
        matvec_left<<<1, BLK, 0, stream>>>(wl, atom_att_src + l * NH, usrc);
        matvec_left<<<1, BLK, 0, stream>>>(wl, atom_att_dst + l * NH, udst);
        node_dot<_Float16><<<gridNodeCap, BLK, 0, stream>>>(B1, usrc, udst, dotr, adst, N);
        gat_agg_csr<<<gridNodeWave, BLK, 0, stream>>>(B1, dotr, adst, rowptr, esrc, B2, N);
        run_tail(wl, atom_bias + l * NH,
                 gru_w_ih + (size_t)(l + 1) * NH3 * NH, gru_w_hh + (size_t)(l + 1) * NH3 * NH,
                 gru_b_ih + (size_t)(l + 1) * NH3, gru_b_hh + (size_t)(l + 1) * NH3, B1);
    }

    // ---------- Molecule pooling ----------
    const size_t GHtot = (size_t)G * NH;
    const int gridGWave = cdiv(G, 4);
    graph_sum_relu<<<gridGWave, BLK, 0, stream>>>(B1, gptr, gout, G);
    matvec_left<<<1, BLK, 0, stream>>>(mol_lin_w, mol_att_src, usrc);
    matvec_left<<<1, BLK, 0, stream>>>(mol_lin_w, mol_att_dst, vvec);
    node_dot<_Float16><<<gridNodeCap, BLK, 0, stream>>>(B1, usrc, nullptr, dotr, nullptr, N);

    dim3 gridGH(1, cdiv(G, 64));
    dim3 gridGD(3, cdiv(G, 64), 2);
    for (int t = 0; t < 2; ++t) {
        node_dot<float><<<gridGWave, BLK, 0, stream>>>(gout, vvec, nullptr, ddot, nullptr, G);
        mol_agg_csr<<<gridGWave, BLK, 0, stream>>>(B1, dotr, ddot, gptr, hraw_g, G);
        gemm_mfma<2, 0, 0><<<gridGH, BLK, 0, stream>>>(hraw_g, mol_lin_w, mol_bias, h_g,
                                                       G, NH, NH, NH, NH);
        gemm_mfma2<0, 1, 0><<<gridGD, BLK, 0, stream>>>(h_g, gout, mol_gru_w_ih, mol_gru_w_hh,
                                                        gig, ghg, G, NH, NH3);
        gru_combine<float><<<cdiv((size_t)G * 32, BLK), BLK, 0, stream>>>(
            gig, ghg, mol_gru_b_ih, mol_gru_b_hh, gout, gout, G);
    }

    // ---------- readout ----------
    gemm_mfma<0, 0, 0><<<gridGH, BLK, 0, stream>>>(gout, lin2_w, lin2_b, emb, G, NH, NH, NH, NH);
    dim3 gridFc(1, cdiv(G, 64));
    gemm_nt<<<gridFc, BLK, 0, stream>>>(emb, fc_w, fc_b, (float*)d_out, G, NH, NTASK, NH, 0);
}

// Round 9
// 4771.316 us; speedup vs baseline: 1.2981x; 1.2981x over previous
//
#include <hip/hip_runtime.h>
#include <math.h>
#include <stdio.h>
#include <stdint.h>

#define NH 256
#define NH3 768
#define FNODE 133
#define FEDGE 7
#define LDW_GATE1 263   // H + F_EDGE
#define NGRAPH 4096
#define NTASK 12
#define SLOPE 0.01f
#define CHUNK 25000
#define PADK 40         // f16 elems per LDS row: 32 + 8 pad (80B stride, 16B aligned)
#define KPAD_X 160      // x padded K (133 -> 160)

typedef __attribute__((ext_vector_type(4))) float f32x4;
typedef __attribute__((ext_vector_type(8))) _Float16 f16x8;

static __device__ __forceinline__ float lrelu_f(float x) { return x > 0.f ? x : SLOPE * x; }

// ---------------- MFMA fp16 GEMM core (BM=64, BN=256) ----------------
// C[M,Nout] = act(A[M,K] @ W[Nout, ldW]^T + bias)
// ACT: 0 none, 1 lrelu, 2 elu ; OB: 0 f32 out, 1 fp16 out ; AF16: A is f16
// Kw: valid K range for W reads (cols beyond Kw read as 0; A must be 0-padded there)
template<int ACT, int OB, int AF16>
static __device__ __forceinline__ void gemm_core(
    _Float16* As, _Float16* Ws,
    const void* __restrict__ Av, const float* __restrict__ W,
    const float* __restrict__ bias, void* __restrict__ Cout,
    int M, int K, int Nout, int ldW, int Kw)
{
    const int bm = blockIdx.y * 64;
    const int bn = blockIdx.x * 256;
    const int tid = threadIdx.x;
    const int wv = tid >> 6, lane = tid & 63;
    const int l15 = lane & 15, l4 = lane >> 4;
    const bool kvec = ((K & 31) == 0);
    const bool wvec = kvec && ((ldW & 3) == 0) && (Kw == K);
    const int ar = tid >> 2, akq = (tid & 3) * 8;   // 16B-chunk staging (2-way banks, free)

    f32x4 acc[16];
#pragma unroll
    for (int c = 0; c < 16; ++c) acc[c] = (f32x4){0.f, 0.f, 0.f, 0.f};

    for (int k0 = 0; k0 < K; k0 += 32) {
        // ---- stage A: 64 rows x 32 k ; 8 f16 (16B) per thread
        {
            const int ga = bm + ar;
            _Float16* dstA = &As[ar * PADK + akq];
            if (AF16) {
                const _Float16* A = (const _Float16*)Av;
                if (ga < M) {
                    *reinterpret_cast<f16x8*>(dstA) =
                        *reinterpret_cast<const f16x8*>(A + (size_t)ga * K + k0 + akq);
                } else {
#pragma unroll
                    for (int j = 0; j < 8; ++j) dstA[j] = (_Float16)0.f;
                }
            } else {
                const float* A = (const float*)Av;
                if (ga < M && kvec) {
                    const float4* ap4 = reinterpret_cast<const float4*>(A + (size_t)ga * K + k0 + akq);
                    float4 v0 = ap4[0], v1 = ap4[1];
                    dstA[0] = (_Float16)v0.x; dstA[1] = (_Float16)v0.y;
                    dstA[2] = (_Float16)v0.z; dstA[3] = (_Float16)v0.w;
                    dstA[4] = (_Float16)v1.x; dstA[5] = (_Float16)v1.y;
                    dstA[6] = (_Float16)v1.z; dstA[7] = (_Float16)v1.w;
                } else {
                    const float* ap = A + (size_t)ga * K + k0 + akq;
#pragma unroll
                    for (int j = 0; j < 8; ++j) {
                        int gk = k0 + akq + j;
                        float v = (ga < M && gk < K) ? ap[j] : 0.f;
                        dstA[j] = (_Float16)v;
                    }
                }
            }
        }
        // ---- stage W: 256 rows x 32 k ; 4 chunks of 8 f16 per thread
#pragma unroll
        for (int q = 0; q < 4; ++q) {
            const int r = ar + 64 * q;
            const int gw = bn + r;
            _Float16* dstW = &Ws[r * PADK + akq];
            if (gw < Nout && wvec) {
                const float4* wp4 = reinterpret_cast<const float4*>(W + (size_t)gw * ldW + k0 + akq);
                float4 v0 = wp4[0], v1 = wp4[1];
                dstW[0] = (_Float16)v0.x; dstW[1] = (_Float16)v0.y;
                dstW[2] = (_Float16)v0.z; dstW[3] = (_Float16)v0.w;
                dstW[4] = (_Float16)v1.x; dstW[5] = (_Float16)v1.y;
                dstW[6] = (_Float16)v1.z; dstW[7] = (_Float16)v1.w;
            } else {
                const float* wp = W + (size_t)gw * ldW + k0 + akq;
#pragma unroll
                for (int j = 0; j < 8; ++j) {
                    int gk = k0 + akq + j;
                    float v = (gw < Nout && gk < Kw) ? wp[j] : 0.f;
                    dstW[j] = (_Float16)v;
                }
            }
        }
        __syncthreads();
        f16x8 af = *reinterpret_cast<const f16x8*>(&As[(wv * 16 + l15) * PADK + l4 * 8]);
#pragma unroll
        for (int c = 0; c < 16; ++c) {
            f16x8 wf = *reinterpret_cast<const f16x8*>(&Ws[(c * 16 + l15) * PADK + l4 * 8]);
            acc[c] = __builtin_amdgcn_mfma_f32_16x16x32_f16(af, wf, acc[c], 0, 0, 0);
        }
        __syncthreads();
    }

#pragma unroll
    for (int c = 0; c < 16; ++c) {
        int gc = bn + c * 16 + l15;
        if (gc >= Nout) continue;
        float bv = bias ? bias[gc] : 0.f;
#pragma unroll
        for (int q = 0; q < 4; ++q) {
            int gr = bm + wv * 16 + l4 * 4 + q;
            if (gr >= M) continue;
            float v = acc[c][q] + bv;
            if (ACT == 1) v = lrelu_f(v);
            else if (ACT == 2) v = (v > 0.f ? v : expm1f(v));
            size_t off = (size_t)gr * Nout + gc;
            if (OB) ((_Float16*)Cout)[off] = (_Float16)v;
            else    ((float*)Cout)[off] = v;
        }
    }
}

template<int ACT, int OB, int AF16>
__global__ __launch_bounds__(256, 4) void gemm_mfma(
    const void* __restrict__ A, const float* __restrict__ W,
    const float* __restrict__ bias, void* __restrict__ Cout,
    int M, int K, int Nout, int ldW, int Kw)
{
    __shared__ _Float16 As[64 * PADK];
    __shared__ _Float16 Ws[256 * PADK];
    gemm_core<ACT, OB, AF16>(As, Ws, A, W, bias, Cout, M, K, Nout, ldW, Kw);
}

// dual GEMM: z=0 -> C0 = A0@W0^T ; z=1 -> C1 = A1@W1^T  (no bias/act), ldW=K
template<int ACT, int OB, int AF16>
__global__ __launch_bounds__(256, 4) void gemm_mfma2(
    const void* __restrict__ A0, const void* __restrict__ A1,
    const float* __restrict__ W0, const float* __restrict__ W1,
    void* __restrict__ C0, void* __restrict__ C1,
    int M, int K, int Nout)
{
    __shared__ _Float16 As[64 * PADK];
    __shared__ _Float16 Ws[256 * PADK];
    if (blockIdx.z == 0)
        gemm_core<ACT, OB, AF16>(As, Ws, A0, W0, nullptr, C0, M, K, Nout, K, K);
    else
        gemm_core<ACT, OB, AF16>(As, Ws, A1, W1, nullptr, C1, M, K, Nout, K, K);
}

// pad + cast: out[r, k] = k < Kin ? (f16)in[r, k] : 0
__global__ void pad_cast_f16(const float* __restrict__ in, _Float16* __restrict__ out,
                             int M, int Kin, int Kout)
{
    size_t i = (size_t)blockIdx.x * 256 + threadIdx.x;
    if (i >= (size_t)M * Kout) return;
    int r = (int)(i / Kout), k = (int)(i % Kout);
    out[i] = (k < Kin) ? (_Float16)in[(size_t)r * Kin + k] : (_Float16)0.f;
}

// ---------------- fp32 fallback GEMM (final 12-col fc only) ----------------
__global__ __launch_bounds__(256) void gemm_nt(
    const float* __restrict__ A, const float* __restrict__ W,
    const float* __restrict__ bias, float* __restrict__ C,
    int M, int K, int Nout, int ldW, int act)
{
    __shared__ float As[16][65];
    __shared__ float Ws[16][65];
    const int bm = blockIdx.y * 64;
    const int bn = blockIdx.x * 64;
    const int tid = threadIdx.x;
    const int tr = tid >> 4, tc = tid & 15;
    const int lrow = tid >> 2, lk = (tid & 3) * 4;
    float acc[4][4] = {};
    for (int k0 = 0; k0 < K; k0 += 16) {
#pragma unroll
        for (int j = 0; j < 4; ++j) {
            int gk = k0 + lk + j;
            int ga = bm + lrow;
            As[lk + j][lrow] = (ga < M && gk < K) ? A[(size_t)ga * K + gk] : 0.f;
            int gw = bn + lrow;
            Ws[lk + j][lrow] = (gw < Nout && gk < K) ? W[(size_t)gw * ldW + gk] : 0.f;
        }
        __syncthreads();
#pragma unroll
        for (int kk = 0; kk < 16; ++kk) {
            float av[4], bv[4];
#pragma unroll
            for (int i = 0; i < 4; ++i) av[i] = As[kk][tr * 4 + i];
#pragma unroll
            for (int i = 0; i < 4; ++i) bv[i] = Ws[kk][tc * 4 + i];
#pragma unroll
            for (int i = 0; i < 4; ++i)
#pragma unroll
                for (int j = 0; j < 4; ++j) acc[i][j] += av[i] * bv[j];
        }
        __syncthreads();
    }
#pragma unroll
    for (int i = 0; i < 4; ++i) {
        int m = bm + tr * 4 + i;
        if (m >= M) continue;
#pragma unroll
        for (int j = 0; j < 4; ++j) {
            int n = bn + tc * 4 + j;
            if (n >= Nout) continue;
            float v = acc[i][j];
            if (bias) v += bias[n];
            if (act == 1) v = lrelu_f(v);
            C[(size_t)m * Nout + n] = v;
        }
    }
}

// ---------------- CSR/CSC build ----------------
__global__ void zero_i32(int* p, int n) {
    int i = blockIdx.x * 256 + threadIdx.x;
    if (i < n) p[i] = 0;
}
__global__ void hist_k(const int* __restrict__ key, int* __restrict__ deg, int E) {
    int i = blockIdx.x * 256 + threadIdx.x;
    if (i < E) atomicAdd(&deg[key[i]], 1);
}
__global__ __launch_bounds__(256) void scan_rowptr(
    const int* __restrict__ deg, int* __restrict__ rowptr, int* __restrict__ cursor, int Nn)
{
    __shared__ int lds[256];
    const int t = threadIdx.x;
    const int C = (Nn + 255) / 256;
    const int lo = t * C, hi = min((t + 1) * C, Nn);
    int s = 0;
    for (int i = lo; i < hi; ++i) s += deg[i];
    lds[t] = s;
    __syncthreads();
    for (int off = 1; off < 256; off <<= 1) {
        int v = (t >= off) ? lds[t - off] : 0;
        __syncthreads();
        lds[t] += v;
        __syncthreads();
    }
    int run = lds[t] - s;
    for (int i = lo; i < hi; ++i) {
        rowptr[i] = run; cursor[i] = run; run += deg[i];
    }
    if (lo < Nn && hi >= Nn) rowptr[Nn] = run;
}
__global__ void csr_scatter(const int* __restrict__ src, const int* __restrict__ dst,
                            int* __restrict__ cursor, int* __restrict__ esrc,
                            int* __restrict__ pos, int E)
{
    int e = blockIdx.x * 256 + threadIdx.x;
    if (e < E) {
        int p = atomicAdd(&cursor[dst[e]], 1);
        esrc[p] = src[e];
        pos[e] = p;
    }
}
__global__ void csc_scatter(const int* __restrict__ src, int* __restrict__ cursor,
                            int* __restrict__ seid, int E)
{
    int e = blockIdx.x * 256 + threadIdx.x;
    if (e < E) {
        int p = atomicAdd(&cursor[src[e]], 1);
        seid[p] = e;
    }
}
__global__ void gptr_build(const int* __restrict__ batch, int* __restrict__ gptr, int Nn, int G) {
    int g = blockIdx.x * 256 + threadIdx.x;
    if (g > G) return;
    int lo = 0, hi = Nn;
    while (lo < hi) { int mid = (lo + hi) >> 1; if (batch[mid] < g) lo = mid + 1; else hi = mid; }
    gptr[g] = lo;
}

// ---------------- GATE src-side partial logit (CSC, wave/src, 4-edge ILP) ----------------
// elogp[pos[e]] = dot(lrelu(nodepart[s] + edge_attr[e]@W1b^T), att_l)
__global__ __launch_bounds__(256) void gate_part_csc(
    const _Float16* __restrict__ nodepart, const float* __restrict__ edge_attr,
    const float* __restrict__ gate_lin1_w, const float* __restrict__ att_l,
    const int* __restrict__ srowptr, const int* __restrict__ seid, const int* __restrict__ pos,
    float* __restrict__ elogp, int Nn)
{
    int wv = threadIdx.x >> 6, lane = threadIdx.x & 63;
    float wr[4][FEDGE], al[4];
#pragma unroll
    for (int i = 0; i < 4; ++i) {
        int hh = i * 64 + lane;
        al[i] = att_l[hh];
#pragma unroll
        for (int f = 0; f < FEDGE; ++f)
            wr[i][f] = gate_lin1_w[(size_t)hh * LDW_GATE1 + NH + f];
    }
    for (int s = blockIdx.x * 4 + wv; s < Nn; s += gridDim.x * 4) {
        int beg = srowptr[s], end = srowptr[s + 1];
        if (beg >= end) continue;
        float np[4];
#pragma unroll
        for (int i = 0; i < 4; ++i) np[i] = (float)nodepart[(size_t)s * NH + i * 64 + lane];
        for (int j0 = beg; j0 < end; j0 += 4) {
            int nb = end - j0; if (nb > 4) nb = 4;
            float ea[4][FEDGE];
            int pp[4];
#pragma unroll
            for (int k = 0; k < 4; ++k) {
                int j = (k < nb) ? j0 + k : beg;
                int e = seid[j];
                pp[k] = pos[e];
                const float* ep = edge_attr + (size_t)e * FEDGE;
#pragma unroll
                for (int f = 0; f < FEDGE; ++f) ea[k][f] = ep[f];
            }
            float acc[4];
#pragma unroll
            for (int k = 0; k < 4; ++k) {
                float a = 0.f;
#pragma unroll
                for (int i = 0; i < 4; ++i) {
                    float v = np[i];
#pragma unroll
                    for (int f = 0; f < FEDGE; ++f) v += ea[k][f] * wr[i][f];
                    a += lrelu_f(v) * al[i];
                }
                acc[k] = a;
            }
#pragma unroll
            for (int off = 32; off; off >>= 1) {
#pragma unroll
                for (int k = 0; k < 4; ++k) acc[k] += __shfl_xor(acc[k], off);
            }
            if (lane == 0) {
#pragma unroll
                for (int k = 0; k < 4; ++k) if (k < nb) elogp[pp[k]] = acc[k];
            }
        }
    }
}

// ---------------- fused attention aggregation (CSR, wave per dst) ----------------
__global__ __launch_bounds__(256) void gat_agg_csr(
    const _Float16* __restrict__ X, const float* __restrict__ asrc, const float* __restrict__ adst,
    const int* __restrict__ rowptr, const int* __restrict__ esrc,
    _Float16* __restrict__ hout, int Nn)
{
    int wv = threadIdx.x >> 6, lane = threadIdx.x & 63;
    int d = blockIdx.x * 4 + wv;
    if (d >= Nn) return;
    int beg = rowptr[d], end = rowptr[d + 1];
    float a0 = 0.f, a1 = 0.f, a2 = 0.f, a3 = 0.f;
    if (beg < end) {
        float ad = adst[d];
        float m = -3.4e38f;
        for (int j = beg + lane; j < end; j += 64)
            m = fmaxf(m, lrelu_f(asrc[esrc[j]] + ad));
#pragma unroll
        for (int off = 32; off; off >>= 1) m = fmaxf(m, __shfl_xor(m, off));
        float s = 0.f;
        for (int j = beg + lane; j < end; j += 64)
            s += expf(lrelu_f(asrc[esrc[j]] + ad) - m);
#pragma unroll
        for (int off = 32; off; off >>= 1) s += __shfl_xor(s, off);
        float inv = 1.f / (s + 1e-16f);
        for (int j = beg; j < end; ++j) {
            int sj = esrc[j];
            float a = expf(lrelu_f(asrc[sj] + ad) - m) * inv;
            const _Float16* xr = X + (size_t)sj * NH;
            a0 += a * (float)xr[lane];       a1 += a * (float)xr[64 + lane];
            a2 += a * (float)xr[128 + lane]; a3 += a * (float)xr[192 + lane];
        }
    }
    _Float16* hr = hout + (size_t)d * NH;
    hr[lane] = (_Float16)a0; hr[64 + lane] = (_Float16)a1;
    hr[128 + lane] = (_Float16)a2; hr[192 + lane] = (_Float16)a3;
}

__global__ __launch_bounds__(256) void gate_agg_csr(
    const _Float16* __restrict__ X, const float* __restrict__ elogp, const float* __restrict__ dotr,
    const int* __restrict__ rowptr, const int* __restrict__ esrc,
    _Float16* __restrict__ hout, int Nn)
{
    int wv = threadIdx.x >> 6, lane = threadIdx.x & 63;
    int d = blockIdx.x * 4 + wv;
    if (d >= Nn) return;
    int beg = rowptr[d], end = rowptr[d + 1];
    float a0 = 0.f, a1 = 0.f, a2 = 0.f, a3 = 0.f;
    if (beg < end) {
        float dd = dotr[d];
        float m = -3.4e38f;
        for (int j = beg + lane; j < end; j += 64)
            m = fmaxf(m, lrelu_f(elogp[j] + dd));
#pragma unroll
        for (int off = 32; off; off >>= 1) m = fmaxf(m, __shfl_xor(m, off));
        float s = 0.f;
        for (int j = beg + lane; j < end; j += 64)
            s += expf(lrelu_f(elogp[j] + dd) - m);
#pragma unroll
        for (int off = 32; off; off >>= 1) s += __shfl_xor(s, off);
        float inv = 1.f / (s + 1e-16f);
        for (int j = beg; j < end; ++j) {
            int sj = esrc[j];
            float a = expf(lrelu_f(elogp[j] + dd) - m) * inv;
            const _Float16* xr = X + (size_t)sj * NH;
            a0 += a * (float)xr[lane];       a1 += a * (float)xr[64 + lane];
            a2 += a * (float)xr[128 + lane]; a3 += a * (float)xr[192 + lane];
        }
    }
    _Float16* hr = hout + (size_t)d * NH;
    hr[lane] = (_Float16)a0; hr[64 + lane] = (_Float16)a1;
    hr[128 + lane] = (_Float16)a2; hr[192 + lane] = (_Float16)a3;
}

__global__ __launch_bounds__(256) void mol_agg_csr(
    const _Float16* __restrict__ X, const float* __restrict__ dotr, const float* __restrict__ ddot,
    const int* __restrict__ gptr, float* __restrict__ hout, int G)
{
    int wv = threadIdx.x >> 6, lane = threadIdx.x & 63;
    int g = blockIdx.x * 4 + wv;
    if (g >= G) return;
    int beg = gptr[g], end = gptr[g + 1];
    float a0 = 0.f, a1 = 0.f, a2 = 0.f, a3 = 0.f;
    if (beg < end) {
        float dg = ddot[g];
        float m = -3.4e38f;
        for (int i = beg + lane; i < end; i += 64)
            m = fmaxf(m, lrelu_f(dotr[i] + dg));
#pragma unroll
        for (int off = 32; off; off >>= 1) m = fmaxf(m, __shfl_xor(m, off));
        float s = 0.f;
        for (int i = beg + lane; i < end; i += 64)
            s += expf(lrelu_f(dotr[i] + dg) - m);
#pragma unroll
        for (int off = 32; off; off >>= 1) s += __shfl_xor(s, off);
        float inv = 1.f / (s + 1e-16f);
        for (int i = beg; i < end; ++i) {
            float a = expf(lrelu_f(dotr[i] + dg) - m) * inv;
            const _Float16* xr = X + (size_t)i * NH;
            a0 += a * (float)xr[lane];       a1 += a * (float)xr[64 + lane];
            a2 += a * (float)xr[128 + lane]; a3 += a * (float)xr[192 + lane];
        }
    }
    float* hr = hout + (size_t)g * NH;
    hr[lane] = a0; hr[64 + lane] = a1; hr[128 + lane] = a2; hr[192 + lane] = a3;
}

__global__ __launch_bounds__(256) void graph_sum_relu(
    const _Float16* __restrict__ X, const int* __restrict__ gptr, float* __restrict__ out, int G)
{
    int wv = threadIdx.x >> 6, lane = threadIdx.x & 63;
    int g = blockIdx.x * 4 + wv;
    if (g >= G) return;
    int beg = gptr[g], end = gptr[g + 1];
    float a0 = 0.f, a1 = 0.f, a2 = 0.f, a3 = 0.f;
    for (int i = beg; i < end; ++i) {
        const _Float16* xr = X + (size_t)i * NH;
        a0 += (float)xr[lane];       a1 += (float)xr[64 + lane];
        a2 += (float)xr[128 + lane]; a3 += (float)xr[192 + lane];
    }
    float* hr = out + (size_t)g * NH;
    hr[lane] = fmaxf(a0, 0.f); hr[64 + lane] = fmaxf(a1, 0.f);
    hr[128 + lane] = fmaxf(a2, 0.f); hr[192 + lane] = fmaxf(a3, 0.f);
}

template<typename TX>
__global__ __launch_bounds__(256) void node_dot(
    const TX* __restrict__ X, const float* __restrict__ v1, const float* __restrict__ v2,
    float* __restrict__ o1, float* __restrict__ o2, int M)
{
    __shared__ float s1[NH], s2[NH];
    int tid = threadIdx.x;
    s1[tid] = v1[tid];
    s2[tid] = v2 ? v2[tid] : 0.f;
    __syncthreads();
    int wv = tid >> 6, lane = tid & 63;
    for (int n = blockIdx.x * 4 + wv; n < M; n += gridDim.x * 4) {
        float a1 = 0.f, a2 = 0.f;
#pragma unroll
        for (int i = 0; i < 4; ++i) {
            int hh = i * 64 + lane;
            float xv = (float)X[(size_t)n * NH + hh];
            a1 += xv * s1[hh];
            a2 += xv * s2[hh];
        }
#pragma unroll
        for (int off = 32; off; off >>= 1) { a1 += __shfl_xor(a1, off); a2 += __shfl_xor(a2, off); }
        if (lane == 0) { o1[n] = a1; if (o2) o2[n] = a2; }
    }
}

__global__ __launch_bounds__(256) void matvec_left(
    const float* __restrict__ Wm, const float* __restrict__ a, float* __restrict__ v)
{
    int j = threadIdx.x;
    float s = 0.f;
    for (int i = 0; i < NH; ++i) s += a[i] * Wm[(size_t)i * NH + j];
    v[j] = s;
}

// GRU combine (gates r,z,n) + ReLU ; gi/gh f16 ; hprev/out TH ; 8 elems/thread
template<typename TH>
__global__ __launch_bounds__(256) void gru_combine(
    const _Float16* __restrict__ gi, const _Float16* __restrict__ gh,
    const float* __restrict__ b_ih, const float* __restrict__ b_hh,
    const TH* __restrict__ hprev, TH* __restrict__ out, int M)
{
    size_t t = (size_t)blockIdx.x * 256 + threadIdx.x;
    if (t >= (size_t)M * 32) return;
    int n = (int)(t >> 5), j0 = ((int)t & 31) * 8;
    size_t b3 = (size_t)n * NH3;
    f16x8 vir = *reinterpret_cast<const f16x8*>(&gi[b3 + j0]);
    f16x8 viz = *reinterpret_cast<const f16x8*>(&gi[b3 + NH + j0]);
    f16x8 vin = *reinterpret_cast<const f16x8*>(&gi[b3 + 2 * NH + j0]);
    f16x8 vhr = *reinterpret_cast<const f16x8*>(&gh[b3 + j0]);
    f16x8 vhz = *reinterpret_cast<const f16x8*>(&gh[b3 + NH + j0]);
    f16x8 vhn = *reinterpret_cast<const f16x8*>(&gh[b3 + 2 * NH + j0]);
    size_t hb = (size_t)n * NH + j0;
    float hp[8];
#pragma unroll
    for (int q = 0; q < 8; ++q) hp[q] = (float)hprev[hb + q];
    float o[8];
#pragma unroll
    for (int q = 0; q < 8; ++q) {
        int j = j0 + q;
        float ir = (float)vir[q] + b_ih[j];
        float iz = (float)viz[q] + b_ih[NH + j];
        float inn = (float)vin[q] + b_ih[2 * NH + j];
        float hr = (float)vhr[q] + b_hh[j];
        float hz = (float)vhz[q] + b_hh[NH + j];
        float hn = (float)vhn[q] + b_hh[2 * NH + j];
        float r = 1.f / (1.f + expf(-(ir + hr)));
        float z = 1.f / (1.f + expf(-(iz + hz)));
        float nn = tanhf(inn + r * hn);
        o[q] = fmaxf((1.f - z) * nn + z * hp[q], 0.f);
    }
#pragma unroll
    for (int q = 0; q < 8; ++q) out[hb + q] = (TH)o[q];
}

extern "C" void kernel_launch(void* const* d_in, const int* in_sizes, int n_in,
                              void* d_out, int out_size, void* d_ws, size_t ws_size,
                              hipStream_t stream)
{
    const float* x          = (const float*)d_in[0];
    const float* edge_attr  = (const float*)d_in[1];
    const float* lin1_w     = (const float*)d_in[2];
    const float* lin1_b     = (const float*)d_in[3];
    const float* gate_att_l = (const float*)d_in[4];
    const float* gate_att_r = (const float*)d_in[5];
    const float* gate_lin1_w= (const float*)d_in[6];
    const float* gate_lin2_w= (const float*)d_in[7];
    const float* gate_bias  = (const float*)d_in[8];
    const float* atom_lin_w = (const float*)d_in[9];
    const float* atom_att_src=(const float*)d_in[10];
    const float* atom_att_dst=(const float*)d_in[11];
    const float* atom_bias  = (const float*)d_in[12];
    const float* gru_w_ih   = (const float*)d_in[13];
    const float* gru_w_hh   = (const float*)d_in[14];
    const float* gru_b_ih   = (const float*)d_in[15];
    const float* gru_b_hh   = (const float*)d_in[16];
    const float* mol_lin_w  = (const float*)d_in[17];
    const float* mol_att_src= (const float*)d_in[18];
    const float* mol_att_dst= (const float*)d_in[19];
    const float* mol_bias   = (const float*)d_in[20];
    const float* mol_gru_w_ih=(const float*)d_in[21];
    const float* mol_gru_w_hh=(const float*)d_in[22];
    const float* mol_gru_b_ih=(const float*)d_in[23];
    const float* mol_gru_b_hh=(const float*)d_in[24];
    const float* lin2_w     = (const float*)d_in[25];
    const float* lin2_b     = (const float*)d_in[26];
    const float* fc_w       = (const float*)d_in[27];
    const float* fc_b       = (const float*)d_in[28];
    const int*   edge_index = (const int*)d_in[29];
    const int*   batch      = (const int*)d_in[30];

    const int N = in_sizes[0] / FNODE;
    const int E = in_sizes[1] / FEDGE;
    const int G = NGRAPH;
    const int* src = edge_index;
    const int* dst = edge_index + E;

    float* w = (float*)d_ws;
    size_t o = 0;
    auto alloc = [&](size_t cnt) { size_t r = o; o += cnt; return r; };
    const size_t o_B1    = alloc((size_t)N * NH / 2);      // f16 x0 -> xcur
    const size_t o_B2    = alloc((size_t)N * NH / 2);      // f16 nodepart -> hraw ; mol f32 bufs
    const size_t o_B3    = alloc((size_t)N * NH / 2 + (size_t)2 * CHUNK * 384);
                          // [tmp_full f16 N*256 | gi f16 CHUNK*768 | gh f16 CHUNK*768]
    const size_t o_elog  = alloc((size_t)E);
    const size_t o_dotr  = alloc((size_t)N);
    const size_t o_adst  = alloc((size_t)N);
    const size_t o_ddot  = alloc((size_t)G);
    const size_t o_vvec  = alloc((size_t)NH);
    const size_t o_usrc  = alloc((size_t)NH);
    const size_t o_udst  = alloc((size_t)NH);
    const size_t o_rowp  = alloc((size_t)N + 1);
    const size_t o_srowp = alloc((size_t)N + 1);
    const size_t o_deg   = alloc((size_t)N);
    const size_t o_curs  = alloc((size_t)N);
    const size_t o_esrc  = alloc((size_t)E);
    const size_t o_pos   = alloc((size_t)E);
    const size_t o_seid  = alloc((size_t)E);
    const size_t o_gptr  = alloc((size_t)G + 1);
    if (o * sizeof(float) > ws_size) {
        fprintf(stderr, "kernel_launch: ws too small: need %zu have %zu\n", o * 4, ws_size);
        return;
    }

    _Float16* B1 = (_Float16*)(w + o_B1);
    _Float16* B2 = (_Float16*)(w + o_B2);
    float* B3   = w + o_B3;
    float* elog = w + o_elog;
    float* dotr = w + o_dotr;
    float* adst = w + o_adst;
    float* ddot = w + o_ddot;
    float* vvec = w + o_vvec;
    float* usrc = w + o_usrc;
    float* udst = w + o_udst;
    int* rowptr  = (int*)(w + o_rowp);
    int* srowptr = (int*)(w + o_srowp);
    int* deg     = (int*)(w + o_deg);
    int* cursor  = (int*)(w + o_curs);
    int* esrc    = (int*)(w + o_esrc);
    int* pos     = (int*)(w + o_pos);
    int* seid    = (int*)(w + o_seid);
    int* gptr    = (int*)(w + o_gptr);

    // mol-phase sub-buffers inside B2 (f32 views; node hraw dead by then)
    float* B2f = (float*)B2;
    float*    gout   = B2f;                                     // G*NH f32
    float*    hraw_g = B2f + (size_t)G * NH;                    // G*NH f32
    float*    h_g    = B2f + (size_t)2 * G * NH;                // G*NH f32
    _Float16* gig    = (_Float16*)(B2f + (size_t)3 * G * NH);   // G*NH3 f16
    _Float16* ghg    = (_Float16*)(B2f + (size_t)3 * G * NH + (size_t)G * NH3 / 2);
    float*    emb    = B2f + (size_t)3 * G * NH + (size_t)G * NH3;

    const int BLK = 256;
    auto cdiv = [](size_t a, size_t b) { return (int)((a + b - 1) / b); };
    const int gridNodeWave = cdiv(N, 4);
    const int gridEdgeThr = cdiv(E, BLK);
    const int gridNodeThr = cdiv(N, BLK);
    const int CAP = 4096;
    const int gridNodeCap = gridNodeWave < CAP ? gridNodeWave : CAP;

    // ---------- CSR + CSC build (once) ----------
    zero_i32<<<gridNodeThr, BLK, 0, stream>>>(deg, N);
    hist_k<<<gridEdgeThr, BLK, 0, stream>>>(dst, deg, E);
    scan_rowptr<<<1, BLK, 0, stream>>>(deg, rowptr, cursor, N);
    csr_scatter<<<gridEdgeThr, BLK, 0, stream>>>(src, dst, cursor, esrc, pos, E);
    zero_i32<<<gridNodeThr, BLK, 0, stream>>>(deg, N);
    hist_k<<<gridEdgeThr, BLK, 0, stream>>>(src, deg, E);
    scan_rowptr<<<1, BLK, 0, stream>>>(deg, srowptr, cursor, N);
    csc_scatter<<<gridEdgeThr, BLK, 0, stream>>>(src, cursor, seid, E);
    gptr_build<<<cdiv(G + 1, BLK), BLK, 0, stream>>>(batch, gptr, N, G);

    // Per-layer tail: tmp_full = elu(hraw@Wh^T + bh) [full N, one launch];
    // then chunked dual GEMM (gi,gh) + GRU combine (in place on xbuf)
    auto run_tail = [&](const float* Wh, const float* bh,
                        const float* wih, const float* whh,
                        const float* bih, const float* bhh, _Float16* xbuf) {
        _Float16* tmp = (_Float16*)B3;                              // N*NH f16
        _Float16* gi  = (_Float16*)(B3 + (size_t)N * NH / 2);       // CHUNK*NH3 f16
        _Float16* gh  = (_Float16*)(B3 + (size_t)N * NH / 2 + (size_t)CHUNK * 384);
        dim3 gFull(1, cdiv(N, 64));
        gemm_mfma<2, 1, 1><<<gFull, BLK, 0, stream>>>(B2, Wh, bh, tmp, N, NH, NH, NH, NH);
        for (int c0 = 0; c0 < N; c0 += CHUNK) {
            int mc = (N - c0) < CHUNK ? (N - c0) : CHUNK;
            dim3 gD(3, cdiv(mc, 64), 2);
            gemm_mfma2<0, 1, 1><<<gD, BLK, 0, stream>>>(tmp + (size_t)c0 * NH,
                                                        xbuf + (size_t)c0 * NH, wih, whh,
                                                        gi, gh, mc, NH, NH3);
            gru_combine<_Float16><<<cdiv((size_t)mc * 32, BLK), BLK, 0, stream>>>(
                gi, gh, bih, bhh, xbuf + (size_t)c0 * NH, xbuf + (size_t)c0 * NH, mc);
        }
    };

    dim3 gridNH(1, cdiv(N, 64));

    // ---------- x0 = lrelu(x @ lin1_w^T + lin1_b) via padded f16 A ----------
    _Float16* xpad = (_Float16*)B3;     // N*160 f16 = 32 MB, fits in tmp region; dead before tails
    pad_cast_f16<<<cdiv((size_t)N * KPAD_X, BLK), BLK, 0, stream>>>(x, xpad, N, FNODE, KPAD_X);
    gemm_mfma<1, 1, 1><<<gridNH, BLK, 0, stream>>>(xpad, lin1_w, lin1_b, B1,
                                                   N, KPAD_X, NH, FNODE, FNODE);

    // ---------- GATEConv ----------
    gemm_mfma<0, 1, 1><<<gridNH, BLK, 0, stream>>>(B1, gate_lin1_w, nullptr, B2,
                                                   N, NH, NH, LDW_GATE1, NH);
    node_dot<_Float16><<<gridNodeCap, BLK, 0, stream>>>(B1, gate_att_r, nullptr, dotr, nullptr, N);
    gate_part_csc<<<gridNodeCap, BLK, 0, stream>>>(B2, edge_attr, gate_lin1_w, gate_att_l,
                                                   srowptr, seid, pos, elog, N);
    gate_agg_csr<<<gridNodeWave, BLK, 0, stream>>>(B1, elog, dotr, rowptr, esrc, B2, N);
    run_tail(gate_lin2_w, gate_bias, gru_w_ih, gru_w_hh, gru_b_ih, gru_b_hh, B1);

    // ---------- 3 GATConv layers ----------
    for (int l = 0; l < 3; ++l) {
        const float* wl = atom_lin_w + (size_t)l * NH * NH;
        matvec_left<<<1, BLK, 0, stream>>>(wl, atom_att_src + l * NH, usrc);
        matvec_left<<<1, BLK, 0, stream>>>(wl, atom_att_dst + l * NH, udst);
        node_dot<_Float16><<<gridNodeCap, BLK, 0, stream>>>(B1, usrc, udst, dotr, adst, N);
        gat_agg_csr<<<gridNodeWave, BLK, 0, stream>>>(B1, dotr, adst, rowptr, esrc, B2, N);
        run_tail(wl, atom_bias + l * NH,
                 gru_w_ih + (size_t)(l + 1) * NH3 * NH, gru_w_hh + (size_t)(l + 1) * NH3 * NH,
                 gru_b_ih + (size_t)(l + 1) * NH3, gru_b_hh + (size_t)(l + 1) * NH3, B1);
    }

    // ---------- Molecule pooling ----------
    const int gridGWave = cdiv(G, 4);
    graph_sum_relu<<<gridGWave, BLK, 0, stream>>>(B1, gptr, gout, G);
    matvec_left<<<1, BLK, 0, stream>>>(mol_lin_w, mol_att_src, usrc);
    matvec_left<<<1, BLK, 0, stream>>>(mol_lin_w, mol_att_dst, vvec);
    node_dot<_Float16><<<gridNodeCap, BLK, 0, stream>>>(B1, usrc, nullptr, dotr, nullptr, N);

    dim3 gridGH(1, cdiv(G, 64));
    dim3 gridGD(3, cdiv(G, 64), 2);
    for (int t = 0; t < 2; ++t) {
        node_dot<float><<<gridGWave, BLK, 0, stream>>>(gout, vvec, nullptr, ddot, nullptr, G);
        mol_agg_csr<<<gridGWave, BLK, 0, stream>>>(B1, dotr, ddot, gptr, hraw_g, G);
        gemm_mfma<2, 0, 0><<<gridGH, BLK, 0, stream>>>(hraw_g, mol_lin_w, mol_bias, h_g,
                                                       G, NH, NH, NH, NH);
        gemm_mfma2<0, 1, 0><<<gridGD, BLK, 0, stream>>>(h_g, gout, mol_gru_w_ih, mol_gru_w_hh,
                                                        gig, ghg, G, NH, NH3);
        gru_combine<float><<<cdiv((size_t)G * 32, BLK), BLK, 0, stream>>>(
            gig, ghg, mol_gru_b_ih, mol_gru_b_hh, gout, gout, G);
    }

    // ---------- readout ----------
    gemm_mfma<0, 0, 0><<<gridGH, BLK, 0, stream>>>(gout, lin2_w, lin2_b, emb, G, NH, NH, NH, NH);
    dim3 gridFc(1, cdiv(G, 64));
    gemm_nt<<<gridFc, BLK, 0, stream>>>(emb, fc_w, fc_b, (float*)d_out, G, NH, NTASK, NH, 0);
}

// Round 10
// 4364.418 us; speedup vs baseline: 1.4192x; 1.0932x over previous
//
#include <hip/hip_runtime.h>
#include <math.h>
#include <stdio.h>
#include <stdint.h>

#define NH 256
#define NH3 768
#define FNODE 133
#define FEDGE 7
#define LDW_GATE1 263   // H + F_EDGE
#define NGRAPH 4096
#define NTASK 12
#define SLOPE 0.01f
#define CHUNK 25000
#define PADK 40         // f16 elems per LDS row: 32 + 8 pad (80B stride, 16B aligned)
#define KPAD_X 160      // x padded K (133 -> 160)
#define LDC2 512        // interleaved node-state row stride (f16): [tmp | xcur]

typedef __attribute__((ext_vector_type(4))) float f32x4;
typedef __attribute__((ext_vector_type(8))) _Float16 f16x8;

static __device__ __forceinline__ float lrelu_f(float x) { return x > 0.f ? x : SLOPE * x; }

// ---------------- MFMA fp16 GEMM core (BM=64, BN=256) ----------------
// C[M rows, cols bn..bn+255 of Nout] = act(A[M,K] @ W[Nout rows, ldW]^T + bias)
// ACT: 0 none, 1 lrelu, 2 elu ; OB: 0 f32 out, 1 f16 out ; AF16: A is f16
// Kw: valid K for W reads (cols >= Kw read 0; A zero-padded there). ldC/ocol: output layout.
template<int ACT, int OB, int AF16>
static __device__ __forceinline__ void gemm_core(
    _Float16* As, _Float16* Ws,
    const void* __restrict__ Av, const float* __restrict__ W,
    const float* __restrict__ bias, void* __restrict__ Cout,
    int M, int K, int Nout, int ldA, int ldW, int ldC, int ocol, int Kw, int bn)
{
    const int bm = blockIdx.y * 64;
    const int tid = threadIdx.x;
    const int wv = tid >> 6, lane = tid & 63;
    const int l15 = lane & 15, l4 = lane >> 4;
    const bool kvec = ((K & 31) == 0) && ((ldA & 3) == 0);
    const bool wvec = ((K & 31) == 0) && ((ldW & 3) == 0) && (Kw == K);
    const int ar = tid >> 2, akq = (tid & 3) * 8;   // 16B-chunk staging (2-way banks, free)

    f32x4 acc[16];
#pragma unroll
    for (int c = 0; c < 16; ++c) acc[c] = (f32x4){0.f, 0.f, 0.f, 0.f};

    for (int k0 = 0; k0 < K; k0 += 32) {
        // ---- stage A: 64 rows x 32 k ; 8 f16 (16B) per thread
        {
            const int ga = bm + ar;
            _Float16* dstA = &As[ar * PADK + akq];
            if (AF16) {
                const _Float16* A = (const _Float16*)Av;
                if (ga < M) {
                    *reinterpret_cast<f16x8*>(dstA) =
                        *reinterpret_cast<const f16x8*>(A + (size_t)ga * ldA + k0 + akq);
                } else {
#pragma unroll
                    for (int j = 0; j < 8; ++j) dstA[j] = (_Float16)0.f;
                }
            } else {
                const float* A = (const float*)Av;
                if (ga < M && kvec) {
                    const float4* ap4 = reinterpret_cast<const float4*>(A + (size_t)ga * ldA + k0 + akq);
                    float4 v0 = ap4[0], v1 = ap4[1];
                    dstA[0] = (_Float16)v0.x; dstA[1] = (_Float16)v0.y;
                    dstA[2] = (_Float16)v0.z; dstA[3] = (_Float16)v0.w;
                    dstA[4] = (_Float16)v1.x; dstA[5] = (_Float16)v1.y;
                    dstA[6] = (_Float16)v1.z; dstA[7] = (_Float16)v1.w;
                } else {
                    const float* ap = A + (size_t)ga * ldA + k0 + akq;
#pragma unroll
                    for (int j = 0; j < 8; ++j) {
                        int gk = k0 + akq + j;
                        float v = (ga < M && gk < K) ? ap[j] : 0.f;
                        dstA[j] = (_Float16)v;
                    }
                }
            }
        }
        // ---- stage W: 256 rows x 32 k ; 4 chunks of 8 f16 per thread
#pragma unroll
        for (int q = 0; q < 4; ++q) {
            const int r = ar + 64 * q;
            const int gw = bn + r;
            _Float16* dstW = &Ws[r * PADK + akq];
            if (gw < Nout && wvec) {
                const float4* wp4 = reinterpret_cast<const float4*>(W + (size_t)gw * ldW + k0 + akq);
                float4 v0 = wp4[0], v1 = wp4[1];
                dstW[0] = (_Float16)v0.x; dstW[1] = (_Float16)v0.y;
                dstW[2] = (_Float16)v0.z; dstW[3] = (_Float16)v0.w;
                dstW[4] = (_Float16)v1.x; dstW[5] = (_Float16)v1.y;
                dstW[6] = (_Float16)v1.z; dstW[7] = (_Float16)v1.w;
            } else {
                const float* wp = W + (size_t)gw * ldW + k0 + akq;
#pragma unroll
                for (int j = 0; j < 8; ++j) {
                    int gk = k0 + akq + j;
                    float v = (gw < Nout && gk < Kw) ? wp[j] : 0.f;
                    dstW[j] = (_Float16)v;
                }
            }
        }
        __syncthreads();
        f16x8 af = *reinterpret_cast<const f16x8*>(&As[(wv * 16 + l15) * PADK + l4 * 8]);
#pragma unroll
        for (int c = 0; c < 16; ++c) {
            f16x8 wf = *reinterpret_cast<const f16x8*>(&Ws[(c * 16 + l15) * PADK + l4 * 8]);
            acc[c] = __builtin_amdgcn_mfma_f32_16x16x32_f16(af, wf, acc[c], 0, 0, 0);
        }
        __syncthreads();
    }

#pragma unroll
    for (int c = 0; c < 16; ++c) {
        int gc = bn + c * 16 + l15;
        if (gc >= Nout) continue;
        float bv = bias ? bias[gc] : 0.f;
#pragma unroll
        for (int q = 0; q < 4; ++q) {
            int gr = bm + wv * 16 + l4 * 4 + q;
            if (gr >= M) continue;
            float v = acc[c][q] + bv;
            if (ACT == 1) v = lrelu_f(v);
            else if (ACT == 2) v = (v > 0.f ? v : expm1f(v));
            size_t off = (size_t)gr * ldC + ocol + gc;
            if (OB) ((_Float16*)Cout)[off] = (_Float16)v;
            else    ((float*)Cout)[off] = v;
        }
    }
}

template<int ACT, int OB, int AF16>
__global__ __launch_bounds__(256, 4) void gemm_mfma(
    const void* __restrict__ A, const float* __restrict__ W,
    const float* __restrict__ bias, void* __restrict__ Cout,
    int M, int K, int Nout, int ldA, int ldW, int ldC, int ocol, int Kw)
{
    __shared__ _Float16 As[64 * PADK];
    __shared__ _Float16 Ws[256 * PADK];
    gemm_core<ACT, OB, AF16>(As, Ws, A, W, bias, Cout, M, K, Nout, ldA, ldW, ldC, ocol, Kw,
                             blockIdx.x * 256);
}

// GRU triple GEMM over interleaved Acat[mc][512] = [tmp | xcur]:
// z=0: srz cols 0-255 ; z=1: srz cols 256-511 (Wcat, K=512)
// z=2: inn = tmp @ wih_n^T ; z=3: hn = xcur @ whh_n^T (K=256)
__global__ __launch_bounds__(256, 4) void gemm_gru(
    const _Float16* __restrict__ Acat, const float* __restrict__ wcat,
    const float* __restrict__ wih, const float* __restrict__ whh,
    _Float16* __restrict__ srz, _Float16* __restrict__ innb, _Float16* __restrict__ hnb, int mc)
{
    __shared__ _Float16 As[64 * PADK];
    __shared__ _Float16 Ws[256 * PADK];
    int z = blockIdx.z;
    if (z == 0)
        gemm_core<0, 1, 1>(As, Ws, Acat, wcat, nullptr, srz, mc, 512, 512, LDC2, 512, 512, 0, 512, 0);
    else if (z == 1)
        gemm_core<0, 1, 1>(As, Ws, Acat, wcat, nullptr, srz, mc, 512, 512, LDC2, 512, 512, 0, 512, 256);
    else if (z == 2)
        gemm_core<0, 1, 1>(As, Ws, Acat, wih + 512 * NH, nullptr, innb, mc, NH, NH, LDC2, NH, NH, 0, NH, 0);
    else
        gemm_core<0, 1, 1>(As, Ws, Acat + NH, whh + 512 * NH, nullptr, hnb, mc, NH, NH, LDC2, NH, NH, 0, NH, 0);
}

// dual GEMM for mol GRU (f32 A): z=0 -> C0=A0@W0^T ; z=1 -> C1=A1@W1^T
template<int ACT, int OB>
__global__ __launch_bounds__(256, 4) void gemm_mfma2(
    const float* __restrict__ A0, const float* __restrict__ A1,
    const float* __restrict__ W0, const float* __restrict__ W1,
    void* __restrict__ C0, void* __restrict__ C1, int M, int K, int Nout)
{
    __shared__ _Float16 As[64 * PADK];
    __shared__ _Float16 Ws[256 * PADK];
    int bn = blockIdx.x * 256;
    if (blockIdx.z == 0)
        gemm_core<ACT, OB, 0>(As, Ws, A0, W0, nullptr, C0, M, K, Nout, K, K, Nout, 0, K, bn);
    else
        gemm_core<ACT, OB, 0>(As, Ws, A1, W1, nullptr, C1, M, K, Nout, K, K, Nout, 0, K, bn);
}

// Wcat[j][k] (512x512): k<256 -> wih[j][k] ; else whh[j][k-256]   (j = r,z gate rows)
__global__ void build_wcat(const float* __restrict__ wih, const float* __restrict__ whh,
                           float* __restrict__ wcat)
{
    int i = blockIdx.x * 256 + threadIdx.x;
    if (i >= 512 * 512) return;
    int j = i >> 9, k = i & 511;
    wcat[i] = (k < 256) ? wih[j * 256 + k] : whh[j * 256 + (k - 256)];
}

// pad + cast: out[r, k] = k < Kin ? (f16)in[r, k] : 0
__global__ void pad_cast_f16(const float* __restrict__ in, _Float16* __restrict__ out,
                             int M, int Kin, int Kout)
{
    size_t i = (size_t)blockIdx.x * 256 + threadIdx.x;
    if (i >= (size_t)M * Kout) return;
    int r = (int)(i / Kout), k = (int)(i % Kout);
    out[i] = (k < Kin) ? (_Float16)in[(size_t)r * Kin + k] : (_Float16)0.f;
}

// ---------------- fp32 fallback GEMM (final 12-col fc only) ----------------
__global__ __launch_bounds__(256) void gemm_nt(
    const float* __restrict__ A, const float* __restrict__ W,
    const float* __restrict__ bias, float* __restrict__ C,
    int M, int K, int Nout, int ldW, int act)
{
    __shared__ float As[16][65];
    __shared__ float Ws[16][65];
    const int bm = blockIdx.y * 64;
    const int bn = blockIdx.x * 64;
    const int tid = threadIdx.x;
    const int tr = tid >> 4, tc = tid & 15;
    const int lrow = tid >> 2, lk = (tid & 3) * 4;
    float acc[4][4] = {};
    for (int k0 = 0; k0 < K; k0 += 16) {
#pragma unroll
        for (int j = 0; j < 4; ++j) {
            int gk = k0 + lk + j;
            int ga = bm + lrow;
            As[lk + j][lrow] = (ga < M && gk < K) ? A[(size_t)ga * K + gk] : 0.f;
            int gw = bn + lrow;
            Ws[lk + j][lrow] = (gw < Nout && gk < K) ? W[(size_t)gw * ldW + gk] : 0.f;
        }
        __syncthreads();
#pragma unroll
        for (int kk = 0; kk < 16; ++kk) {
            float av[4], bv[4];
#pragma unroll
            for (int i = 0; i < 4; ++i) av[i] = As[kk][tr * 4 + i];
#pragma unroll
            for (int i = 0; i < 4; ++i) bv[i] = Ws[kk][tc * 4 + i];
#pragma unroll
            for (int i = 0; i < 4; ++i)
#pragma unroll
                for (int j = 0; j < 4; ++j) acc[i][j] += av[i] * bv[j];
        }
        __syncthreads();
    }
#pragma unroll
    for (int i = 0; i < 4; ++i) {
        int m = bm + tr * 4 + i;
        if (m >= M) continue;
#pragma unroll
        for (int j = 0; j < 4; ++j) {
            int n = bn + tc * 4 + j;
            if (n >= Nout) continue;
            float v = acc[i][j];
            if (bias) v += bias[n];
            if (act == 1) v = lrelu_f(v);
            C[(size_t)m * Nout + n] = v;
        }
    }
}

// ---------------- CSR/CSC build ----------------
__global__ void zero_i32(int* p, int n) {
    int i = blockIdx.x * 256 + threadIdx.x;
    if (i < n) p[i] = 0;
}
__global__ void hist_k(const int* __restrict__ key, int* __restrict__ deg, int E) {
    int i = blockIdx.x * 256 + threadIdx.x;
    if (i < E) atomicAdd(&deg[key[i]], 1);
}
__global__ __launch_bounds__(256) void scan_rowptr(
    const int* __restrict__ deg, int* __restrict__ rowptr, int* __restrict__ cursor, int Nn)
{
    __shared__ int lds[256];
    const int t = threadIdx.x;
    const int C = (Nn + 255) / 256;
    const int lo = t * C, hi = min((t + 1) * C, Nn);
    int s = 0;
    for (int i = lo; i < hi; ++i) s += deg[i];
    lds[t] = s;
    __syncthreads();
    for (int off = 1; off < 256; off <<= 1) {
        int v = (t >= off) ? lds[t - off] : 0;
        __syncthreads();
        lds[t] += v;
        __syncthreads();
    }
    int run = lds[t] - s;
    for (int i = lo; i < hi; ++i) {
        rowptr[i] = run; cursor[i] = run; run += deg[i];
    }
    if (lo < Nn && hi >= Nn) rowptr[Nn] = run;
}
__global__ void csr_scatter(const int* __restrict__ src, const int* __restrict__ dst,
                            int* __restrict__ cursor, int* __restrict__ esrc,
                            int* __restrict__ pos, int E)
{
    int e = blockIdx.x * 256 + threadIdx.x;
    if (e < E) {
        int p = atomicAdd(&cursor[dst[e]], 1);
        esrc[p] = src[e];
        pos[e] = p;
    }
}
__global__ void csc_scatter(const int* __restrict__ src, int* __restrict__ cursor,
                            int* __restrict__ seid, int E)
{
    int e = blockIdx.x * 256 + threadIdx.x;
    if (e < E) {
        int p = atomicAdd(&cursor[src[e]], 1);
        seid[p] = e;
    }
}
// gather edge_attr + pos into CSC order (one-time): ecsc f16[E][8], pcsc[E]
__global__ void edge_csc_build(const float* __restrict__ edge_attr, const int* __restrict__ seid,
                               const int* __restrict__ pos, _Float16* __restrict__ ecsc,
                               int* __restrict__ pcsc, int E)
{
    int p = blockIdx.x * 256 + threadIdx.x;
    if (p >= E) return;
    int e = seid[p];
    pcsc[p] = pos[e];
    const float* ep = edge_attr + (size_t)e * FEDGE;
#pragma unroll
    for (int f = 0; f < FEDGE; ++f) ecsc[(size_t)p * 8 + f] = (_Float16)ep[f];
    ecsc[(size_t)p * 8 + 7] = (_Float16)0.f;
}
__global__ void gptr_build(const int* __restrict__ batch, int* __restrict__ gptr, int Nn, int G) {
    int g = blockIdx.x * 256 + threadIdx.x;
    if (g > G) return;
    int lo = 0, hi = Nn;
    while (lo < hi) { int mid = (lo + hi) >> 1; if (batch[mid] < g) lo = mid + 1; else hi = mid; }
    gptr[g] = lo;
}

// ---------------- GATE src-side partial logit (CSC, streaming, 4-edge ILP) ----------------
__global__ __launch_bounds__(256) void gate_part_csc(
    const _Float16* __restrict__ nodepart, const _Float16* __restrict__ ecsc,
    const float* __restrict__ gate_lin1_w, const float* __restrict__ att_l,
    const int* __restrict__ srowptr, const int* __restrict__ pcsc,
    float* __restrict__ elogp, int Nn)
{
    int wv = threadIdx.x >> 6, lane = threadIdx.x & 63;
    float wr[4][FEDGE], al[4];
#pragma unroll
    for (int i = 0; i < 4; ++i) {
        int hh = i * 64 + lane;
        al[i] = att_l[hh];
#pragma unroll
        for (int f = 0; f < FEDGE; ++f)
            wr[i][f] = gate_lin1_w[(size_t)hh * LDW_GATE1 + NH + f];
    }
    for (int s = blockIdx.x * 4 + wv; s < Nn; s += gridDim.x * 4) {
        int beg = srowptr[s], end = srowptr[s + 1];
        if (beg >= end) continue;
        float np[4];
#pragma unroll
        for (int i = 0; i < 4; ++i) np[i] = (float)nodepart[(size_t)s * NH + i * 64 + lane];
        for (int j0 = beg; j0 < end; j0 += 4) {
            int nb = end - j0; if (nb > 4) nb = 4;
            float ea[4][FEDGE];
            int pp[4];
#pragma unroll
            for (int k = 0; k < 4; ++k) {
                int j = (k < nb) ? j0 + k : beg;
                pp[k] = pcsc[j];
                f16x8 ev = *reinterpret_cast<const f16x8*>(ecsc + (size_t)j * 8);
#pragma unroll
                for (int f = 0; f < FEDGE; ++f) ea[k][f] = (float)ev[f];
            }
            float acc[4];
#pragma unroll
            for (int k = 0; k < 4; ++k) {
                float a = 0.f;
#pragma unroll
                for (int i = 0; i < 4; ++i) {
                    float v = np[i];
#pragma unroll
                    for (int f = 0; f < FEDGE; ++f) v += ea[k][f] * wr[i][f];
                    a += lrelu_f(v) * al[i];
                }
                acc[k] = a;
            }
#pragma unroll
            for (int off = 32; off; off >>= 1) {
#pragma unroll
                for (int k = 0; k < 4; ++k) acc[k] += __shfl_xor(acc[k], off);
            }
            if (lane == 0) {
#pragma unroll
                for (int k = 0; k < 4; ++k) if (k < nb) elogp[pp[k]] = acc[k];
            }
        }
    }
}

// ---------------- fused attention aggregation (CSR, wave per dst) ----------------
// X rows at stride ldX (f16); hout f16 stride 256
__global__ __launch_bounds__(256) void gat_agg_csr(
    const _Float16* __restrict__ X, int ldX,
    const float* __restrict__ asrc, const float* __restrict__ adst,
    const int* __restrict__ rowptr, const int* __restrict__ esrc,
    _Float16* __restrict__ hout, int Nn)
{
    int wv = threadIdx.x >> 6, lane = threadIdx.x & 63;
    int d = blockIdx.x * 4 + wv;
    if (d >= Nn) return;
    int beg = rowptr[d], end = rowptr[d + 1];
    float a0 = 0.f, a1 = 0.f, a2 = 0.f, a3 = 0.f;
    if (beg < end) {
        float ad = adst[d];
        float m = -3.4e38f;
        for (int j = beg + lane; j < end; j += 64)
            m = fmaxf(m, lrelu_f(asrc[esrc[j]] + ad));
#pragma unroll
        for (int off = 32; off; off >>= 1) m = fmaxf(m, __shfl_xor(m, off));
        float s = 0.f;
        for (int j = beg + lane; j < end; j += 64)
            s += expf(lrelu_f(asrc[esrc[j]] + ad) - m);
#pragma unroll
        for (int off = 32; off; off >>= 1) s += __shfl_xor(s, off);
        float inv = 1.f / (s + 1e-16f);
        for (int j = beg; j < end; ++j) {
            int sj = esrc[j];
            float a = expf(lrelu_f(asrc[sj] + ad) - m) * inv;
            const _Float16* xr = X + (size_t)sj * ldX;
            a0 += a * (float)xr[lane];       a1 += a * (float)xr[64 + lane];
            a2 += a * (float)xr[128 + lane]; a3 += a * (float)xr[192 + lane];
        }
    }
    _Float16* hr = hout + (size_t)d * NH;
    hr[lane] = (_Float16)a0; hr[64 + lane] = (_Float16)a1;
    hr[128 + lane] = (_Float16)a2; hr[192 + lane] = (_Float16)a3;
}

__global__ __launch_bounds__(256) void gate_agg_csr(
    const _Float16* __restrict__ X, int ldX,
    const float* __restrict__ elogp, const float* __restrict__ dotr,
    const int* __restrict__ rowptr, const int* __restrict__ esrc,
    _Float16* __restrict__ hout, int Nn)
{
    int wv = threadIdx.x >> 6, lane = threadIdx.x & 63;
    int d = blockIdx.x * 4 + wv;
    if (d >= Nn) return;
    int beg = rowptr[d], end = rowptr[d + 1];
    float a0 = 0.f, a1 = 0.f, a2 = 0.f, a3 = 0.f;
    if (beg < end) {
        float dd = dotr[d];
        float m = -3.4e38f;
        for (int j = beg + lane; j < end; j += 64)
            m = fmaxf(m, lrelu_f(elogp[j] + dd));
#pragma unroll
        for (int off = 32; off; off >>= 1) m = fmaxf(m, __shfl_xor(m, off));
        float s = 0.f;
        for (int j = beg + lane; j < end; j += 64)
            s += expf(lrelu_f(elogp[j] + dd) - m);
#pragma unroll
        for (int off = 32; off; off >>= 1) s += __shfl_xor(s, off);
        float inv = 1.f / (s + 1e-16f);
        for (int j = beg; j < end; ++j) {
            int sj = esrc[j];
            float a = expf(lrelu_f(elogp[j] + dd) - m) * inv;
            const _Float16* xr = X + (size_t)sj * ldX;
            a0 += a * (float)xr[lane];       a1 += a * (float)xr[64 + lane];
            a2 += a * (float)xr[128 + lane]; a3 += a * (float)xr[192 + lane];
        }
    }
    _Float16* hr = hout + (size_t)d * NH;
    hr[lane] = (_Float16)a0; hr[64 + lane] = (_Float16)a1;
    hr[128 + lane] = (_Float16)a2; hr[192 + lane] = (_Float16)a3;
}

__global__ __launch_bounds__(256) void mol_agg_csr(
    const _Float16* __restrict__ X, int ldX,
    const float* __restrict__ dotr, const float* __restrict__ ddot,
    const int* __restrict__ gptr, float* __restrict__ hout, int G)
{
    int wv = threadIdx.x >> 6, lane = threadIdx.x & 63;
    int g = blockIdx.x * 4 + wv;
    if (g >= G) return;
    int beg = gptr[g], end = gptr[g + 1];
    float a0 = 0.f, a1 = 0.f, a2 = 0.f, a3 = 0.f;
    if (beg < end) {
        float dg = ddot[g];
        float m = -3.4e38f;
        for (int i = beg + lane; i < end; i += 64)
            m = fmaxf(m, lrelu_f(dotr[i] + dg));
#pragma unroll
        for (int off = 32; off; off >>= 1) m = fmaxf(m, __shfl_xor(m, off));
        float s = 0.f;
        for (int i = beg + lane; i < end; i += 64)
            s += expf(lrelu_f(dotr[i] + dg) - m);
#pragma unroll
        for (int off = 32; off; off >>= 1) s += __shfl_xor(s, off);
        float inv = 1.f / (s + 1e-16f);
        for (int i = beg; i < end; ++i) {
            float a = expf(lrelu_f(dotr[i] + dg) - m) * inv;
            const _Float16* xr = X + (size_t)i * ldX;
            a0 += a * (float)xr[lane];       a1 += a * (float)xr[64 + lane];
            a2 += a * (float)xr[128 + lane]; a3 += a * (float)xr[192 + lane];
        }
    }
    float* hr = hout + (size_t)g * NH;
    hr[lane] = a0; hr[64 + lane] = a1; hr[128 + lane] = a2; hr[192 + lane] = a3;
}

__global__ __launch_bounds__(256) void graph_sum_relu(
    const _Float16* __restrict__ X, int ldX, const int* __restrict__ gptr,
    float* __restrict__ out, int G)
{
    int wv = threadIdx.x >> 6, lane = threadIdx.x & 63;
    int g = blockIdx.x * 4 + wv;
    if (g >= G) return;
    int beg = gptr[g], end = gptr[g + 1];
    float a0 = 0.f, a1 = 0.f, a2 = 0.f, a3 = 0.f;
    for (int i = beg; i < end; ++i) {
        const _Float16* xr = X + (size_t)i * ldX;
        a0 += (float)xr[lane];       a1 += (float)xr[64 + lane];
        a2 += (float)xr[128 + lane]; a3 += (float)xr[192 + lane];
    }
    float* hr = out + (size_t)g * NH;
    hr[lane] = fmaxf(a0, 0.f); hr[64 + lane] = fmaxf(a1, 0.f);
    hr[128 + lane] = fmaxf(a2, 0.f); hr[192 + lane] = fmaxf(a3, 0.f);
}

template<typename TX>
__global__ __launch_bounds__(256) void node_dot(
    const TX* __restrict__ X, int ldX, const float* __restrict__ v1, const float* __restrict__ v2,
    float* __restrict__ o1, float* __restrict__ o2, int M)
{
    __shared__ float s1[NH], s2[NH];
    int tid = threadIdx.x;
    s1[tid] = v1[tid];
    s2[tid] = v2 ? v2[tid] : 0.f;
    __syncthreads();
    int wv = tid >> 6, lane = tid & 63;
    for (int n = blockIdx.x * 4 + wv; n < M; n += gridDim.x * 4) {
        float a1 = 0.f, a2 = 0.f;
#pragma unroll
        for (int i = 0; i < 4; ++i) {
            int hh = i * 64 + lane;
            float xv = (float)X[(size_t)n * ldX + hh];
            a1 += xv * s1[hh];
            a2 += xv * s2[hh];
        }
#pragma unroll
        for (int off = 32; off; off >>= 1) { a1 += __shfl_xor(a1, off); a2 += __shfl_xor(a2, off); }
        if (lane == 0) { o1[n] = a1; if (o2) o2[n] = a2; }
    }
}

__global__ __launch_bounds__(256) void matvec_left(
    const float* __restrict__ Wm, const float* __restrict__ a, float* __restrict__ v)
{
    int j = threadIdx.x;
    float s = 0.f;
    for (int i = 0; i < NH; ++i) s += a[i] * Wm[(size_t)i * NH + j];
    v[j] = s;
}

// node GRU combine from srz/inn/hn ; xcur in B1cat cols 256-511 (in place), relu
__global__ __launch_bounds__(256) void gru_combine2(
    const _Float16* __restrict__ srz, const _Float16* __restrict__ innb,
    const _Float16* __restrict__ hnb, const float* __restrict__ b_ih,
    const float* __restrict__ b_hh, _Float16* __restrict__ xcat, int M)
{
    size_t t = (size_t)blockIdx.x * 256 + threadIdx.x;
    if (t >= (size_t)M * 32) return;
    int n = (int)(t >> 5), j0 = ((int)t & 31) * 8;
    f16x8 vr = *reinterpret_cast<const f16x8*>(&srz[(size_t)n * LDC2 + j0]);
    f16x8 vz = *reinterpret_cast<const f16x8*>(&srz[(size_t)n * LDC2 + 256 + j0]);
    f16x8 vi = *reinterpret_cast<const f16x8*>(&innb[(size_t)n * NH + j0]);
    f16x8 vh = *reinterpret_cast<const f16x8*>(&hnb[(size_t)n * NH + j0]);
    _Float16* xp = xcat + (size_t)n * LDC2 + 256 + j0;
    f16x8 hp8 = *reinterpret_cast<const f16x8*>(xp);
    f16x8 o8;
#pragma unroll
    for (int q = 0; q < 8; ++q) {
        int j = j0 + q;
        float r = 1.f / (1.f + expf(-((float)vr[q] + b_ih[j] + b_hh[j])));
        float z = 1.f / (1.f + expf(-((float)vz[q] + b_ih[NH + j] + b_hh[NH + j])));
        float nn = tanhf((float)vi[q] + b_ih[2 * NH + j] + r * ((float)vh[q] + b_hh[2 * NH + j]));
        float hv = (1.f - z) * nn + z * (float)hp8[q];
        o8[q] = (_Float16)fmaxf(hv, 0.f);
    }
    *reinterpret_cast<f16x8*>(xp) = o8;
}

// mol GRU combine (f32 hprev/out), gi/gh f16 dense NH3
__global__ __launch_bounds__(256) void gru_combine(
    const _Float16* __restrict__ gi, const _Float16* __restrict__ gh,
    const float* __restrict__ b_ih, const float* __restrict__ b_hh,
    const float* __restrict__ hprev, float* __restrict__ out, int M)
{
    size_t t = (size_t)blockIdx.x * 256 + threadIdx.x;
    if (t >= (size_t)M * 32) return;
    int n = (int)(t >> 5), j0 = ((int)t & 31) * 8;
    size_t b3 = (size_t)n * NH3;
    f16x8 vir = *reinterpret_cast<const f16x8*>(&gi[b3 + j0]);
    f16x8 viz = *reinterpret_cast<const f16x8*>(&gi[b3 + NH + j0]);
    f16x8 vin = *reinterpret_cast<const f16x8*>(&gi[b3 + 2 * NH + j0]);
    f16x8 vhr = *reinterpret_cast<const f16x8*>(&gh[b3 + j0]);
    f16x8 vhz = *reinterpret_cast<const f16x8*>(&gh[b3 + NH + j0]);
    f16x8 vhn = *reinterpret_cast<const f16x8*>(&gh[b3 + 2 * NH + j0]);
    size_t hb = (size_t)n * NH + j0;
#pragma unroll
    for (int q = 0; q < 8; ++q) {
        int j = j0 + q;
        float r = 1.f / (1.f + expf(-((float)vir[q] + b_ih[j] + (float)vhr[q] + b_hh[j])));
        float z = 1.f / (1.f + expf(-((float)viz[q] + b_ih[NH + j] + (float)vhz[q] + b_hh[NH + j])));
        float nn = tanhf((float)vin[q] + b_ih[2 * NH + j] + r * ((float)vhn[q] + b_hh[2 * NH + j]));
        out[hb + q] = fmaxf((1.f - z) * nn + z * hprev[hb + q], 0.f);
    }
}

extern "C" void kernel_launch(void* const* d_in, const int* in_sizes, int n_in,
                              void* d_out, int out_size, void* d_ws, size_t ws_size,
                              hipStream_t stream)
{
    const float* x          = (const float*)d_in[0];
    const float* edge_attr  = (const float*)d_in[1];
    const float* lin1_w     = (const float*)d_in[2];
    const float* lin1_b     = (const float*)d_in[3];
    const float* gate_att_l = (const float*)d_in[4];
    const float* gate_att_r = (const float*)d_in[5];
    const float* gate_lin1_w= (const float*)d_in[6];
    const float* gate_lin2_w= (const float*)d_in[7];
    const float* gate_bias  = (const float*)d_in[8];
    const float* atom_lin_w = (const float*)d_in[9];
    const float* atom_att_src=(const float*)d_in[10];
    const float* atom_att_dst=(const float*)d_in[11];
    const float* atom_bias  = (const float*)d_in[12];
    const float* gru_w_ih   = (const float*)d_in[13];
    const float* gru_w_hh   = (const float*)d_in[14];
    const float* gru_b_ih   = (const float*)d_in[15];
    const float* gru_b_hh   = (const float*)d_in[16];
    const float* mol_lin_w  = (const float*)d_in[17];
    const float* mol_att_src= (const float*)d_in[18];
    const float* mol_att_dst= (const float*)d_in[19];
    const float* mol_bias   = (const float*)d_in[20];
    const float* mol_gru_w_ih=(const float*)d_in[21];
    const float* mol_gru_w_hh=(const float*)d_in[22];
    const float* mol_gru_b_ih=(const float*)d_in[23];
    const float* mol_gru_b_hh=(const float*)d_in[24];
    const float* lin2_w     = (const float*)d_in[25];
    const float* lin2_b     = (const float*)d_in[26];
    const float* fc_w       = (const float*)d_in[27];
    const float* fc_b       = (const float*)d_in[28];
    const int*   edge_index = (const int*)d_in[29];
    const int*   batch      = (const int*)d_in[30];

    const int N = in_sizes[0] / FNODE;
    const int E = in_sizes[1] / FEDGE;
    const int G = NGRAPH;
    const int* src = edge_index;
    const int* dst = edge_index + E;

    float* w = (float*)d_ws;
    size_t o = 0;
    auto alloc = [&](size_t cnt) { size_t r = o; o += cnt; return r; };
    const size_t o_B1cat = alloc((size_t)N * NH);          // f16 N x 512: [tmp | xcur]
    const size_t o_B2    = alloc((size_t)N * NH / 2);      // f16 nodepart -> hraw ; mol f32 bufs
    const size_t o_B3    = alloc((size_t)CHUNK * 512);     // srz(512)+inn(256)+hn(256) f16 ; xpad
    const size_t o_wcat  = alloc((size_t)512 * 512);
    const size_t o_elog  = alloc((size_t)E);
    const size_t o_dotr  = alloc((size_t)N);
    const size_t o_adst  = alloc((size_t)N);
    const size_t o_ddot  = alloc((size_t)G);
    const size_t o_vvec  = alloc((size_t)NH);
    const size_t o_usrc  = alloc((size_t)NH);
    const size_t o_udst  = alloc((size_t)NH);
    const size_t o_rowp  = alloc((size_t)N + 1);
    const size_t o_srowp = alloc((size_t)N + 1);
    const size_t o_deg   = alloc((size_t)N);
    const size_t o_curs  = alloc((size_t)N);
    const size_t o_esrc  = alloc((size_t)E);
    const size_t o_pos   = alloc((size_t)E);
    const size_t o_seid  = alloc((size_t)E);
    const size_t o_ecsc  = alloc((size_t)E * 4);           // f16 E x 8
    const size_t o_pcsc  = alloc((size_t)E);
    const size_t o_gptr  = alloc((size_t)G + 1);
    if (o * sizeof(float) > ws_size) {
        fprintf(stderr, "kernel_launch: ws too small: need %zu have %zu\n", o * 4, ws_size);
        return;
    }

    _Float16* B1cat = (_Float16*)(w + o_B1cat);
    _Float16* xcur  = B1cat + NH;          // row stride LDC2, cols 256-511
    _Float16* B2 = (_Float16*)(w + o_B2);
    float* B3   = w + o_B3;
    float* wcat = w + o_wcat;
    float* elog = w + o_elog;
    float* dotr = w + o_dotr;
    float* adst = w + o_adst;
    float* ddot = w + o_ddot;
    float* vvec = w + o_vvec;
    float* usrc = w + o_usrc;
    float* udst = w + o_udst;
    int* rowptr  = (int*)(w + o_rowp);
    int* srowptr = (int*)(w + o_srowp);
    int* deg     = (int*)(w + o_deg);
    int* cursor  = (int*)(w + o_curs);
    int* esrc    = (int*)(w + o_esrc);
    int* pos     = (int*)(w + o_pos);
    int* seid    = (int*)(w + o_seid);
    _Float16* ecsc = (_Float16*)(w + o_ecsc);
    int* pcsc    = (int*)(w + o_pcsc);
    int* gptr    = (int*)(w + o_gptr);

    // mol-phase f32 sub-buffers inside B2 (node hraw dead by then)
    float* B2f = (float*)B2;
    float*    gout   = B2f;
    float*    hraw_g = B2f + (size_t)G * NH;
    float*    h_g    = B2f + (size_t)2 * G * NH;
    _Float16* gig    = (_Float16*)(B2f + (size_t)3 * G * NH);
    _Float16* ghg    = (_Float16*)(B2f + (size_t)3 * G * NH + (size_t)G * NH3 / 2);
    float*    emb    = B2f + (size_t)3 * G * NH + (size_t)G * NH3;

    const int BLK = 256;
    auto cdiv = [](size_t a, size_t b) { return (int)((a + b - 1) / b); };
    const int gridNodeWave = cdiv(N, 4);
    const int gridEdgeThr = cdiv(E, BLK);
    const int gridNodeThr = cdiv(N, BLK);
    const int CAP = 4096;
    const int gridNodeCap = gridNodeWave < CAP ? gridNodeWave : CAP;

    // ---------- CSR + CSC build (once) ----------
    zero_i32<<<gridNodeThr, BLK, 0, stream>>>(deg, N);
    hist_k<<<gridEdgeThr, BLK, 0, stream>>>(dst, deg, E);
    scan_rowptr<<<1, BLK, 0, stream>>>(deg, rowptr, cursor, N);
    csr_scatter<<<gridEdgeThr, BLK, 0, stream>>>(src, dst, cursor, esrc, pos, E);
    zero_i32<<<gridNodeThr, BLK, 0, stream>>>(deg, N);
    hist_k<<<gridEdgeThr, BLK, 0, stream>>>(src, deg, E);
    scan_rowptr<<<1, BLK, 0, stream>>>(deg, srowptr, cursor, N);
    csc_scatter<<<gridEdgeThr, BLK, 0, stream>>>(src, cursor, seid, E);
    edge_csc_build<<<gridEdgeThr, BLK, 0, stream>>>(edge_attr, seid, pos, ecsc, pcsc, E);
    gptr_build<<<cdiv(G + 1, BLK), BLK, 0, stream>>>(batch, gptr, N, G);

    // Per-layer tail: tmp(B1cat cols 0-255) = elu(hraw@Wh^T + bh);
    // then chunked gemm_gru (srz,inn,hn) + combine2 (xcur in place)
    auto run_tail = [&](const float* Wh, const float* bh,
                        const float* wih, const float* whh,
                        const float* bih, const float* bhh) {
        _Float16* srz  = (_Float16*)B3;
        _Float16* innb = srz + (size_t)CHUNK * LDC2;
        _Float16* hnb  = innb + (size_t)CHUNK * NH;
        build_wcat<<<1024, BLK, 0, stream>>>(wih, whh, wcat);
        dim3 gFull(1, cdiv(N, 64));
        gemm_mfma<2, 1, 1><<<gFull, BLK, 0, stream>>>(B2, Wh, bh, B1cat,
                                                      N, NH, NH, NH, NH, LDC2, 0, NH);
        for (int c0 = 0; c0 < N; c0 += CHUNK) {
            int mc = (N - c0) < CHUNK ? (N - c0) : CHUNK;
            dim3 gG(1, cdiv(mc, 64), 4);
            gemm_gru<<<gG, BLK, 0, stream>>>(B1cat + (size_t)c0 * LDC2, wcat, wih, whh,
                                             srz, innb, hnb, mc);
            gru_combine2<<<cdiv((size_t)mc * 32, BLK), BLK, 0, stream>>>(
                srz, innb, hnb, bih, bhh, B1cat + (size_t)c0 * LDC2, mc);
        }
    };

    dim3 gridNH(1, cdiv(N, 64));

    // ---------- x0 = lrelu(x @ lin1_w^T + lin1_b) -> xcur (B1cat cols 256-511) ----------
    _Float16* xpad = (_Float16*)B3;     // N*160 f16 = 32 MB < B3 (51.2 MB); dead before tails
    pad_cast_f16<<<cdiv((size_t)N * KPAD_X, BLK), BLK, 0, stream>>>(x, xpad, N, FNODE, KPAD_X);
    gemm_mfma<1, 1, 1><<<gridNH, BLK, 0, stream>>>(xpad, lin1_w, lin1_b, B1cat,
                                                   N, KPAD_X, NH, KPAD_X, FNODE, LDC2, NH, FNODE);

    // ---------- GATEConv ----------
    gemm_mfma<0, 1, 1><<<gridNH, BLK, 0, stream>>>(xcur, gate_lin1_w, nullptr, B2,
                                                   N, NH, NH, LDC2, LDW_GATE1, NH, 0, NH);
    node_dot<_Float16><<<gridNodeCap, BLK, 0, stream>>>(xcur, LDC2, gate_att_r, nullptr,
                                                        dotr, nullptr, N);
    gate_part_csc<<<gridNodeCap, BLK, 0, stream>>>(B2, ecsc, gate_lin1_w, gate_att_l,
                                                   srowptr, pcsc, elog, N);
    gate_agg_csr<<<gridNodeWave, BLK, 0, stream>>>(xcur, LDC2, elog, dotr, rowptr, esrc, B2, N);
    run_tail(gate_lin2_w, gate_bias, gru_w_ih, gru_w_hh, gru_b_ih, gru_b_hh);

    // ---------- 3 GATConv layers ----------
    for (int l = 0; l < 3; ++l) {
        const float* wl = atom_lin_w + (size_t)l * NH * NH;
        matvec_left<<<1, BLK, 0, stream>>>(wl, atom_att_src + l * NH, usrc);
        matvec_left<<<1, BLK, 0, stream>>>(wl, atom_att_dst + l * NH, udst);
        node_dot<_Float16><<<gridNodeCap, BLK, 0, stream>>>(xcur, LDC2, usrc, udst, dotr, adst, N);
        gat_agg_csr<<<gridNodeWave, BLK, 0, stream>>>(xcur, LDC2, dotr, adst, rowptr, esrc, B2, N);
        run_tail(wl, atom_bias + l * NH,
                 gru_w_ih + (size_t)(l + 1) * NH3 * NH, gru_w_hh + (size_t)(l + 1) * NH3 * NH,
                 gru_b_ih + (size_t)(l + 1) * NH3, gru_b_hh + (size_t)(l + 1) * NH3);
    }

    // ---------- Molecule pooling ----------
    const int gridGWave = cdiv(G, 4);
    graph_sum_relu<<<gridGWave, BLK, 0, stream>>>(xcur, LDC2, gptr, gout, G);
    matvec_left<<<1, BLK, 0, stream>>>(mol_lin_w, mol_att_src, usrc);
    matvec_left<<<1, BLK, 0, stream>>>(mol_lin_w, mol_att_dst, vvec);
    node_dot<_Float16><<<gridNodeCap, BLK, 0, stream>>>(xcur, LDC2, usrc, nullptr, dotr, nullptr, N);

    dim3 gridGH(1, cdiv(G, 64));
    dim3 gridGD(3, cdiv(G, 64), 2);
    for (int t = 0; t < 2; ++t) {
        node_dot<float><<<gridGWave, BLK, 0, stream>>>(gout, NH, vvec, nullptr, ddot, nullptr, G);
        mol_agg_csr<<<gridGWave, BLK, 0, stream>>>(xcur, LDC2, dotr, ddot, gptr, hraw_g, G);
        gemm_mfma<2, 0, 0><<<gridGH, BLK, 0, stream>>>(hraw_g, mol_lin_w, mol_bias, h_g,
                                                       G, NH, NH, NH, NH, NH, 0, NH);
        gemm_mfma2<0, 1><<<gridGD, BLK, 0, stream>>>(h_g, gout, mol_gru_w_ih, mol_gru_w_hh,
                                                     gig, ghg, G, NH, NH3);
        gru_combine<<<cdiv((size_t)G * 32, BLK), BLK, 0, stream>>>(
            gig, ghg, mol_gru_b_ih, mol_gru_b_hh, gout, gout, G);
    }

    // ---------- readout ----------
    gemm_mfma<0, 0, 0><<<gridGH, BLK, 0, stream>>>(gout, lin2_w, lin2_b, emb,
                                                   G, NH, NH, NH, NH, NH, 0, NH);
    dim3 gridFc(1, cdiv(G, 64));
    gemm_nt<<<gridFc, BLK, 0, stream>>>(emb, fc_w, fc_b, (float*)d_out, G, NH, NTASK, NH, 0);
}

// Round 11
// 3936.856 us; speedup vs baseline: 1.5733x; 1.1086x over previous
//
#include <hip/hip_runtime.h>
#include <math.h>
#include <stdio.h>
#include <stdint.h>

#define NH 256
#define NH3 768
#define FNODE 133
#define FEDGE 7
#define LDW_GATE1 263   // H + F_EDGE
#define NGRAPH 4096
#define NTASK 12
#define SLOPE 0.01f
#define CHUNK 25000
#define PADK 40         // f16 elems per LDS row: 32 + 8 pad (80B stride, 16B aligned)
#define KPAD_X 160      // x padded K (133 -> 160)
#define LDC2 512        // interleaved node-state row stride (f16): [tmp | xcur]
#define SCAN_TILE 2048  // elems per block in hierarchical scan (256 thr x 8)

typedef __attribute__((ext_vector_type(4))) float f32x4;
typedef __attribute__((ext_vector_type(8))) _Float16 f16x8;

static __device__ __forceinline__ float lrelu_f(float x) { return x > 0.f ? x : SLOPE * x; }

// ---------------- MFMA fp16 GEMM core (BM=64, BN=256) ----------------
// C[M rows, cols bn..bn+255 of Nout] = act(A[M,K] @ W[Nout rows, ldW]^T + bias)
// ACT: 0 none, 1 lrelu, 2 elu ; OB: 0 f32 out, 1 f16 out ; AF16: A is f16
// Kw: valid K for W reads (cols >= Kw read 0; A zero-padded there). ldC/ocol: output layout.
template<int ACT, int OB, int AF16>
static __device__ __forceinline__ void gemm_core(
    _Float16* As, _Float16* Ws,
    const void* __restrict__ Av, const float* __restrict__ W,
    const float* __restrict__ bias, void* __restrict__ Cout,
    int M, int K, int Nout, int ldA, int ldW, int ldC, int ocol, int Kw, int bn)
{
    const int bm = blockIdx.y * 64;
    const int tid = threadIdx.x;
    const int wv = tid >> 6, lane = tid & 63;
    const int l15 = lane & 15, l4 = lane >> 4;
    const bool kvec = ((K & 31) == 0) && ((ldA & 3) == 0);
    const bool wvec = ((K & 31) == 0) && ((ldW & 3) == 0) && (Kw == K);
    const int ar = tid >> 2, akq = (tid & 3) * 8;   // 16B-chunk staging (2-way banks, free)

    f32x4 acc[16];
#pragma unroll
    for (int c = 0; c < 16; ++c) acc[c] = (f32x4){0.f, 0.f, 0.f, 0.f};

    for (int k0 = 0; k0 < K; k0 += 32) {
        // ---- stage A: 64 rows x 32 k ; 8 f16 (16B) per thread
        {
            const int ga = bm + ar;
            _Float16* dstA = &As[ar * PADK + akq];
            if (AF16) {
                const _Float16* A = (const _Float16*)Av;
                if (ga < M) {
                    *reinterpret_cast<f16x8*>(dstA) =
                        *reinterpret_cast<const f16x8*>(A + (size_t)ga * ldA + k0 + akq);
                } else {
#pragma unroll
                    for (int j = 0; j < 8; ++j) dstA[j] = (_Float16)0.f;
                }
            } else {
                const float* A = (const float*)Av;
                if (ga < M && kvec) {
                    const float4* ap4 = reinterpret_cast<const float4*>(A + (size_t)ga * ldA + k0 + akq);
                    float4 v0 = ap4[0], v1 = ap4[1];
                    dstA[0] = (_Float16)v0.x; dstA[1] = (_Float16)v0.y;
                    dstA[2] = (_Float16)v0.z; dstA[3] = (_Float16)v0.w;
                    dstA[4] = (_Float16)v1.x; dstA[5] = (_Float16)v1.y;
                    dstA[6] = (_Float16)v1.z; dstA[7] = (_Float16)v1.w;
                } else {
                    const float* ap = A + (size_t)ga * ldA + k0 + akq;
#pragma unroll
                    for (int j = 0; j < 8; ++j) {
                        int gk = k0 + akq + j;
                        float v = (ga < M && gk < K) ? ap[j] : 0.f;
                        dstA[j] = (_Float16)v;
                    }
                }
            }
        }
        // ---- stage W: 256 rows x 32 k ; 4 chunks of 8 f16 per thread
#pragma unroll
        for (int q = 0; q < 4; ++q) {
            const int r = ar + 64 * q;
            const int gw = bn + r;
            _Float16* dstW = &Ws[r * PADK + akq];
            if (gw < Nout && wvec) {
                const float4* wp4 = reinterpret_cast<const float4*>(W + (size_t)gw * ldW + k0 + akq);
                float4 v0 = wp4[0], v1 = wp4[1];
                dstW[0] = (_Float16)v0.x; dstW[1] = (_Float16)v0.y;
                dstW[2] = (_Float16)v0.z; dstW[3] = (_Float16)v0.w;
                dstW[4] = (_Float16)v1.x; dstW[5] = (_Float16)v1.y;
                dstW[6] = (_Float16)v1.z; dstW[7] = (_Float16)v1.w;
            } else {
                const float* wp = W + (size_t)gw * ldW + k0 + akq;
#pragma unroll
                for (int j = 0; j < 8; ++j) {
                    int gk = k0 + akq + j;
                    float v = (gw < Nout && gk < Kw) ? wp[j] : 0.f;
                    dstW[j] = (_Float16)v;
                }
            }
        }
        __syncthreads();
        f16x8 af = *reinterpret_cast<const f16x8*>(&As[(wv * 16 + l15) * PADK + l4 * 8]);
#pragma unroll
        for (int c = 0; c < 16; ++c) {
            f16x8 wf = *reinterpret_cast<const f16x8*>(&Ws[(c * 16 + l15) * PADK + l4 * 8]);
            acc[c] = __builtin_amdgcn_mfma_f32_16x16x32_f16(af, wf, acc[c], 0, 0, 0);
        }
        __syncthreads();
    }

#pragma unroll
    for (int c = 0; c < 16; ++c) {
        int gc = bn + c * 16 + l15;
        if (gc >= Nout) continue;
        float bv = bias ? bias[gc] : 0.f;
#pragma unroll
        for (int q = 0; q < 4; ++q) {
            int gr = bm + wv * 16 + l4 * 4 + q;
            if (gr >= M) continue;
            float v = acc[c][q] + bv;
            if (ACT == 1) v = lrelu_f(v);
            else if (ACT == 2) v = (v > 0.f ? v : expm1f(v));
            size_t off = (size_t)gr * ldC + ocol + gc;
            if (OB) ((_Float16*)Cout)[off] = (_Float16)v;
            else    ((float*)Cout)[off] = v;
        }
    }
}

template<int ACT, int OB, int AF16>
__global__ __launch_bounds__(256, 4) void gemm_mfma(
    const void* __restrict__ A, const float* __restrict__ W,
    const float* __restrict__ bias, void* __restrict__ Cout,
    int M, int K, int Nout, int ldA, int ldW, int ldC, int ocol, int Kw)
{
    __shared__ _Float16 As[64 * PADK];
    __shared__ _Float16 Ws[256 * PADK];
    gemm_core<ACT, OB, AF16>(As, Ws, A, W, bias, Cout, M, K, Nout, ldA, ldW, ldC, ocol, Kw,
                             blockIdx.x * 256);
}

// GRU triple GEMM over interleaved Acat[mc][512] = [tmp | xcur]:
// z=0: srz cols 0-255 ; z=1: srz cols 256-511 (Wcat, K=512)
// z=2: inn = tmp @ wih_n^T ; z=3: hn = xcur @ whh_n^T (K=256)
__global__ __launch_bounds__(256, 4) void gemm_gru(
    const _Float16* __restrict__ Acat, const float* __restrict__ wcat,
    const float* __restrict__ wih, const float* __restrict__ whh,
    _Float16* __restrict__ srz, _Float16* __restrict__ innb, _Float16* __restrict__ hnb, int mc)
{
    __shared__ _Float16 As[64 * PADK];
    __shared__ _Float16 Ws[256 * PADK];
    int z = blockIdx.z;
    if (z == 0)
        gemm_core<0, 1, 1>(As, Ws, Acat, wcat, nullptr, srz, mc, 512, 512, LDC2, 512, 512, 0, 512, 0);
    else if (z == 1)
        gemm_core<0, 1, 1>(As, Ws, Acat, wcat, nullptr, srz, mc, 512, 512, LDC2, 512, 512, 0, 512, 256);
    else if (z == 2)
        gemm_core<0, 1, 1>(As, Ws, Acat, wih + 512 * NH, nullptr, innb, mc, NH, NH, LDC2, NH, NH, 0, NH, 0);
    else
        gemm_core<0, 1, 1>(As, Ws, Acat + NH, whh + 512 * NH, nullptr, hnb, mc, NH, NH, LDC2, NH, NH, 0, NH, 0);
}

// dual GEMM for mol GRU (f32 A): z=0 -> C0=A0@W0^T ; z=1 -> C1=A1@W1^T
template<int ACT, int OB>
__global__ __launch_bounds__(256, 4) void gemm_mfma2(
    const float* __restrict__ A0, const float* __restrict__ A1,
    const float* __restrict__ W0, const float* __restrict__ W1,
    void* __restrict__ C0, void* __restrict__ C1, int M, int K, int Nout)
{
    __shared__ _Float16 As[64 * PADK];
    __shared__ _Float16 Ws[256 * PADK];
    int bn = blockIdx.x * 256;
    if (blockIdx.z == 0)
        gemm_core<ACT, OB, 0>(As, Ws, A0, W0, nullptr, C0, M, K, Nout, K, K, Nout, 0, K, bn);
    else
        gemm_core<ACT, OB, 0>(As, Ws, A1, W1, nullptr, C1, M, K, Nout, K, K, Nout, 0, K, bn);
}

// Wcat[j][k] (512x512): k<256 -> wih[j][k] ; else whh[j][k-256]   (j = r,z gate rows)
__global__ void build_wcat(const float* __restrict__ wih, const float* __restrict__ whh,
                           float* __restrict__ wcat)
{
    int i = blockIdx.x * 256 + threadIdx.x;
    if (i >= 512 * 512) return;
    int j = i >> 9, k = i & 511;
    wcat[i] = (k < 256) ? wih[j * 256 + k] : whh[j * 256 + (k - 256)];
}

// pad + cast: out[r, k] = k < Kin ? (f16)in[r, k] : 0
__global__ void pad_cast_f16(const float* __restrict__ in, _Float16* __restrict__ out,
                             int M, int Kin, int Kout)
{
    size_t i = (size_t)blockIdx.x * 256 + threadIdx.x;
    if (i >= (size_t)M * Kout) return;
    int r = (int)(i / Kout), k = (int)(i % Kout);
    out[i] = (k < Kin) ? (_Float16)in[(size_t)r * Kin + k] : (_Float16)0.f;
}

// ---------------- fp32 fallback GEMM (final 12-col fc only) ----------------
__global__ __launch_bounds__(256) void gemm_nt(
    const float* __restrict__ A, const float* __restrict__ W,
    const float* __restrict__ bias, float* __restrict__ C,
    int M, int K, int Nout, int ldW, int act)
{
    __shared__ float As[16][65];
    __shared__ float Ws[16][65];
    const int bm = blockIdx.y * 64;
    const int bn = blockIdx.x * 64;
    const int tid = threadIdx.x;
    const int tr = tid >> 4, tc = tid & 15;
    const int lrow = tid >> 2, lk = (tid & 3) * 4;
    float acc[4][4] = {};
    for (int k0 = 0; k0 < K; k0 += 16) {
#pragma unroll
        for (int j = 0; j < 4; ++j) {
            int gk = k0 + lk + j;
            int ga = bm + lrow;
            As[lk + j][lrow] = (ga < M && gk < K) ? A[(size_t)ga * K + gk] : 0.f;
            int gw = bn + lrow;
            Ws[lk + j][lrow] = (gw < Nout && gk < K) ? W[(size_t)gw * ldW + gk] : 0.f;
        }
        __syncthreads();
#pragma unroll
        for (int kk = 0; kk < 16; ++kk) {
            float av[4], bv[4];
#pragma unroll
            for (int i = 0; i < 4; ++i) av[i] = As[kk][tr * 4 + i];
#pragma unroll
            for (int i = 0; i < 4; ++i) bv[i] = Ws[kk][tc * 4 + i];
#pragma unroll
            for (int i = 0; i < 4; ++i)
#pragma unroll
                for (int j = 0; j < 4; ++j) acc[i][j] += av[i] * bv[j];
        }
        __syncthreads();
    }
#pragma unroll
    for (int i = 0; i < 4; ++i) {
        int m = bm + tr * 4 + i;
        if (m >= M) continue;
#pragma unroll
        for (int j = 0; j < 4; ++j) {
            int n = bn + tc * 4 + j;
            if (n >= Nout) continue;
            float v = acc[i][j];
            if (bias) v += bias[n];
            if (act == 1) v = lrelu_f(v);
            C[(size_t)m * Nout + n] = v;
        }
    }
}

// ---------------- CSR/CSC build ----------------
__global__ void zero_i32(int* p, int n) {
    int i = blockIdx.x * 256 + threadIdx.x;
    if (i < n) p[i] = 0;
}
__global__ void hist_k(const int* __restrict__ key, int* __restrict__ deg, int E) {
    int i = blockIdx.x * 256 + threadIdx.x;
    if (i < E) atomicAdd(&deg[key[i]], 1);
}

// hierarchical exclusive scan over deg[0..Nn) -> rowptr[0..Nn] (+cursor copy)
// pass 1: per-block (SCAN_TILE elems) total -> bsum[b]
__global__ __launch_bounds__(256) void scan_pass1(
    const int* __restrict__ deg, int* __restrict__ bsum, int Nn)
{
    __shared__ int lds[256];
    int b = blockIdx.x, t = threadIdx.x;
    int base = b * SCAN_TILE + t * 8;
    int s = 0;
#pragma unroll
    for (int q = 0; q < 8; ++q) { int i = base + q; if (i < Nn) s += deg[i]; }
    lds[t] = s;
    __syncthreads();
    for (int off = 128; off; off >>= 1) {
        if (t < off) lds[t] += lds[t + off];
        __syncthreads();
    }
    if (t == 0) bsum[b] = lds[0];
}
// pass 2: single small block scans bsum[0..nb) -> boff (exclusive); total -> rowptr[Nn]
__global__ __launch_bounds__(256) void scan_pass2(
    const int* __restrict__ bsum, int* __restrict__ boff, int nb, int* __restrict__ total)
{
    __shared__ int lds[256];
    int t = threadIdx.x;
    int v = (t < nb) ? bsum[t] : 0;
    lds[t] = v;
    __syncthreads();
    for (int off = 1; off < 256; off <<= 1) {
        int u = (t >= off) ? lds[t - off] : 0;
        __syncthreads();
        lds[t] += u;
        __syncthreads();
    }
    if (t < nb) boff[t] = lds[t] - v;
    if (t == 255 && total) *total = lds[255];
}
// pass 3: per-block local exclusive scan + block offset -> rowptr & cursor
__global__ __launch_bounds__(256) void scan_pass3(
    const int* __restrict__ deg, const int* __restrict__ boff,
    int* __restrict__ rowptr, int* __restrict__ cursor, int Nn)
{
    __shared__ int lds[256];
    int b = blockIdx.x, t = threadIdx.x;
    int base = b * SCAN_TILE + t * 8;
    int v[8];
    int s = 0;
#pragma unroll
    for (int q = 0; q < 8; ++q) { int i = base + q; v[q] = (i < Nn) ? deg[i] : 0; s += v[q]; }
    lds[t] = s;
    __syncthreads();
    for (int off = 1; off < 256; off <<= 1) {
        int u = (t >= off) ? lds[t - off] : 0;
        __syncthreads();
        lds[t] += u;
        __syncthreads();
    }
    int run = boff[b] + lds[t] - s;
#pragma unroll
    for (int q = 0; q < 8; ++q) {
        int i = base + q;
        if (i < Nn) { rowptr[i] = run; cursor[i] = run; run += v[q]; }
    }
}

__global__ void csr_scatter(const int* __restrict__ src, const int* __restrict__ dst,
                            int* __restrict__ cursor, int* __restrict__ esrc,
                            int* __restrict__ pos, int E)
{
    int e = blockIdx.x * 256 + threadIdx.x;
    if (e < E) {
        int p = atomicAdd(&cursor[dst[e]], 1);
        esrc[p] = src[e];
        pos[e] = p;
    }
}
__global__ void csc_scatter(const int* __restrict__ src, int* __restrict__ cursor,
                            int* __restrict__ seid, int E)
{
    int e = blockIdx.x * 256 + threadIdx.x;
    if (e < E) {
        int p = atomicAdd(&cursor[src[e]], 1);
        seid[p] = e;
    }
}
// gather edge_attr + pos into CSC order (one-time): ecsc f16[E][8], pcsc[E]
__global__ void edge_csc_build(const float* __restrict__ edge_attr, const int* __restrict__ seid,
                               const int* __restrict__ pos, _Float16* __restrict__ ecsc,
                               int* __restrict__ pcsc, int E)
{
    int p = blockIdx.x * 256 + threadIdx.x;
    if (p >= E) return;
    int e = seid[p];
    pcsc[p] = pos[e];
    const float* ep = edge_attr + (size_t)e * FEDGE;
#pragma unroll
    for (int f = 0; f < FEDGE; ++f) ecsc[(size_t)p * 8 + f] = (_Float16)ep[f];
    ecsc[(size_t)p * 8 + 7] = (_Float16)0.f;
}
__global__ void gptr_build(const int* __restrict__ batch, int* __restrict__ gptr, int Nn, int G) {
    int g = blockIdx.x * 256 + threadIdx.x;
    if (g > G) return;
    int lo = 0, hi = Nn;
    while (lo < hi) { int mid = (lo + hi) >> 1; if (batch[mid] < g) lo = mid + 1; else hi = mid; }
    gptr[g] = lo;
}

// ---------------- GATE src-side partial logit (CSC, streaming, 4-edge ILP) ----------------
__global__ __launch_bounds__(256) void gate_part_csc(
    const _Float16* __restrict__ nodepart, const _Float16* __restrict__ ecsc,
    const float* __restrict__ gate_lin1_w, const float* __restrict__ att_l,
    const int* __restrict__ srowptr, const int* __restrict__ pcsc,
    float* __restrict__ elogp, int Nn)
{
    int wv = threadIdx.x >> 6, lane = threadIdx.x & 63;
    float wr[4][FEDGE], al[4];
#pragma unroll
    for (int i = 0; i < 4; ++i) {
        int hh = i * 64 + lane;
        al[i] = att_l[hh];
#pragma unroll
        for (int f = 0; f < FEDGE; ++f)
            wr[i][f] = gate_lin1_w[(size_t)hh * LDW_GATE1 + NH + f];
    }
    for (int s = blockIdx.x * 4 + wv; s < Nn; s += gridDim.x * 4) {
        int beg = srowptr[s], end = srowptr[s + 1];
        if (beg >= end) continue;
        float np[4];
#pragma unroll
        for (int i = 0; i < 4; ++i) np[i] = (float)nodepart[(size_t)s * NH + i * 64 + lane];
        for (int j0 = beg; j0 < end; j0 += 4) {
            int nb = end - j0; if (nb > 4) nb = 4;
            float ea[4][FEDGE];
            int pp[4];
#pragma unroll
            for (int k = 0; k < 4; ++k) {
                int j = (k < nb) ? j0 + k : beg;
                pp[k] = pcsc[j];
                f16x8 ev = *reinterpret_cast<const f16x8*>(ecsc + (size_t)j * 8);
#pragma unroll
                for (int f = 0; f < FEDGE; ++f) ea[k][f] = (float)ev[f];
            }
            float acc[4];
#pragma unroll
            for (int k = 0; k < 4; ++k) {
                float a = 0.f;
#pragma unroll
                for (int i = 0; i < 4; ++i) {
                    float v = np[i];
#pragma unroll
                    for (int f = 0; f < FEDGE; ++f) v += ea[k][f] * wr[i][f];
                    a += lrelu_f(v) * al[i];
                }
                acc[k] = a;
            }
#pragma unroll
            for (int off = 32; off; off >>= 1) {
#pragma unroll
                for (int k = 0; k < 4; ++k) acc[k] += __shfl_xor(acc[k], off);
            }
            if (lane == 0) {
#pragma unroll
                for (int k = 0; k < 4; ++k) if (k < nb) elogp[pp[k]] = acc[k];
            }
        }
    }
}

// ---------------- fused attention aggregation (CSR, wave per dst) ----------------
// X rows at stride ldX (f16); hout f16 stride 256
__global__ __launch_bounds__(256) void gat_agg_csr(
    const _Float16* __restrict__ X, int ldX,
    const float* __restrict__ asrc, const float* __restrict__ adst,
    const int* __restrict__ rowptr, const int* __restrict__ esrc,
    _Float16* __restrict__ hout, int Nn)
{
    int wv = threadIdx.x >> 6, lane = threadIdx.x & 63;
    int d = blockIdx.x * 4 + wv;
    if (d >= Nn) return;
    int beg = rowptr[d], end = rowptr[d + 1];
    float a0 = 0.f, a1 = 0.f, a2 = 0.f, a3 = 0.f;
    if (beg < end) {
        float ad = adst[d];
        float m = -3.4e38f;
        for (int j = beg + lane; j < end; j += 64)
            m = fmaxf(m, lrelu_f(asrc[esrc[j]] + ad));
#pragma unroll
        for (int off = 32; off; off >>= 1) m = fmaxf(m, __shfl_xor(m, off));
        float s = 0.f;
        for (int j = beg + lane; j < end; j += 64)
            s += expf(lrelu_f(asrc[esrc[j]] + ad) - m);
#pragma unroll
        for (int off = 32; off; off >>= 1) s += __shfl_xor(s, off);
        float inv = 1.f / (s + 1e-16f);
        for (int j = beg; j < end; ++j) {
            int sj = esrc[j];
            float a = expf(lrelu_f(asrc[sj] + ad) - m) * inv;
            const _Float16* xr = X + (size_t)sj * ldX;
            a0 += a * (float)xr[lane];       a1 += a * (float)xr[64 + lane];
            a2 += a * (float)xr[128 + lane]; a3 += a * (float)xr[192 + lane];
        }
    }
    _Float16* hr = hout + (size_t)d * NH;
    hr[lane] = (_Float16)a0; hr[64 + lane] = (_Float16)a1;
    hr[128 + lane] = (_Float16)a2; hr[192 + lane] = (_Float16)a3;
}

__global__ __launch_bounds__(256) void gate_agg_csr(
    const _Float16* __restrict__ X, int ldX,
    const float* __restrict__ elogp, const float* __restrict__ dotr,
    const int* __restrict__ rowptr, const int* __restrict__ esrc,
    _Float16* __restrict__ hout, int Nn)
{
    int wv = threadIdx.x >> 6, lane = threadIdx.x & 63;
    int d = blockIdx.x * 4 + wv;
    if (d >= Nn) return;
    int beg = rowptr[d], end = rowptr[d + 1];
    float a0 = 0.f, a1 = 0.f, a2 = 0.f, a3 = 0.f;
    if (beg < end) {
        float dd = dotr[d];
        float m = -3.4e38f;
        for (int j = beg + lane; j < end; j += 64)
            m = fmaxf(m, lrelu_f(elogp[j] + dd));
#pragma unroll
        for (int off = 32; off; off >>= 1) m = fmaxf(m, __shfl_xor(m, off));
        float s = 0.f;
        for (int j = beg + lane; j < end; j += 64)
            s += expf(lrelu_f(elogp[j] + dd) - m);
#pragma unroll
        for (int off = 32; off; off >>= 1) s += __shfl_xor(s, off);
        float inv = 1.f / (s + 1e-16f);
        for (int j = beg; j < end; ++j) {
            int sj = esrc[j];
            float a = expf(lrelu_f(elogp[j] + dd) - m) * inv;
            const _Float16* xr = X + (size_t)sj * ldX;
            a0 += a * (float)xr[lane];       a1 += a * (float)xr[64 + lane];
            a2 += a * (float)xr[128 + lane]; a3 += a * (float)xr[192 + lane];
        }
    }
    _Float16* hr = hout + (size_t)d * NH;
    hr[lane] = (_Float16)a0; hr[64 + lane] = (_Float16)a1;
    hr[128 + lane] = (_Float16)a2; hr[192 + lane] = (_Float16)a3;
}

__global__ __launch_bounds__(256) void mol_agg_csr(
    const _Float16* __restrict__ X, int ldX,
    const float* __restrict__ dotr, const float* __restrict__ ddot,
    const int* __restrict__ gptr, float* __restrict__ hout, int G)
{
    int wv = threadIdx.x >> 6, lane = threadIdx.x & 63;
    int g = blockIdx.x * 4 + wv;
    if (g >= G) return;
    int beg = gptr[g], end = gptr[g + 1];
    float a0 = 0.f, a1 = 0.f, a2 = 0.f, a3 = 0.f;
    if (beg < end) {
        float dg = ddot[g];
        float m = -3.4e38f;
        for (int i = beg + lane; i < end; i += 64)
            m = fmaxf(m, lrelu_f(dotr[i] + dg));
#pragma unroll
        for (int off = 32; off; off >>= 1) m = fmaxf(m, __shfl_xor(m, off));
        float s = 0.f;
        for (int i = beg + lane; i < end; i += 64)
            s += expf(lrelu_f(dotr[i] + dg) - m);
#pragma unroll
        for (int off = 32; off; off >>= 1) s += __shfl_xor(s, off);
        float inv = 1.f / (s + 1e-16f);
        for (int i = beg; i < end; ++i) {
            float a = expf(lrelu_f(dotr[i] + dg) - m) * inv;
            const _Float16* xr = X + (size_t)i * ldX;
            a0 += a * (float)xr[lane];       a1 += a * (float)xr[64 + lane];
            a2 += a * (float)xr[128 + lane]; a3 += a * (float)xr[192 + lane];
        }
    }
    float* hr = hout + (size_t)g * NH;
    hr[lane] = a0; hr[64 + lane] = a1; hr[128 + lane] = a2; hr[192 + lane] = a3;
}

__global__ __launch_bounds__(256) void graph_sum_relu(
    const _Float16* __restrict__ X, int ldX, const int* __restrict__ gptr,
    float* __restrict__ out, int G)
{
    int wv = threadIdx.x >> 6, lane = threadIdx.x & 63;
    int g = blockIdx.x * 4 + wv;
    if (g >= G) return;
    int beg = gptr[g], end = gptr[g + 1];
    float a0 = 0.f, a1 = 0.f, a2 = 0.f, a3 = 0.f;
    for (int i = beg; i < end; ++i) {
        const _Float16* xr = X + (size_t)i * ldX;
        a0 += (float)xr[lane];       a1 += (float)xr[64 + lane];
        a2 += (float)xr[128 + lane]; a3 += (float)xr[192 + lane];
    }
    float* hr = out + (size_t)g * NH;
    hr[lane] = fmaxf(a0, 0.f); hr[64 + lane] = fmaxf(a1, 0.f);
    hr[128 + lane] = fmaxf(a2, 0.f); hr[192 + lane] = fmaxf(a3, 0.f);
}

template<typename TX>
__global__ __launch_bounds__(256) void node_dot(
    const TX* __restrict__ X, int ldX, const float* __restrict__ v1, const float* __restrict__ v2,
    float* __restrict__ o1, float* __restrict__ o2, int M)
{
    __shared__ float s1[NH], s2[NH];
    int tid = threadIdx.x;
    s1[tid] = v1[tid];
    s2[tid] = v2 ? v2[tid] : 0.f;
    __syncthreads();
    int wv = tid >> 6, lane = tid & 63;
    for (int n = blockIdx.x * 4 + wv; n < M; n += gridDim.x * 4) {
        float a1 = 0.f, a2 = 0.f;
#pragma unroll
        for (int i = 0; i < 4; ++i) {
            int hh = i * 64 + lane;
            float xv = (float)X[(size_t)n * ldX + hh];
            a1 += xv * s1[hh];
            a2 += xv * s2[hh];
        }
#pragma unroll
        for (int off = 32; off; off >>= 1) { a1 += __shfl_xor(a1, off); a2 += __shfl_xor(a2, off); }
        if (lane == 0) { o1[n] = a1; if (o2) o2[n] = a2; }
    }
}

__global__ __launch_bounds__(256) void matvec_left(
    const float* __restrict__ Wm, const float* __restrict__ a, float* __restrict__ v)
{
    int j = threadIdx.x;
    float s = 0.f;
    for (int i = 0; i < NH; ++i) s += a[i] * Wm[(size_t)i * NH + j];
    v[j] = s;
}

// node GRU combine from srz/inn/hn ; xcur in B1cat cols 256-511 (in place), relu
__global__ __launch_bounds__(256) void gru_combine2(
    const _Float16* __restrict__ srz, const _Float16* __restrict__ innb,
    const _Float16* __restrict__ hnb, const float* __restrict__ b_ih,
    const float* __restrict__ b_hh, _Float16* __restrict__ xcat, int M)
{
    size_t t = (size_t)blockIdx.x * 256 + threadIdx.x;
    if (t >= (size_t)M * 32) return;
    int n = (int)(t >> 5), j0 = ((int)t & 31) * 8;
    f16x8 vr = *reinterpret_cast<const f16x8*>(&srz[(size_t)n * LDC2 + j0]);
    f16x8 vz = *reinterpret_cast<const f16x8*>(&srz[(size_t)n * LDC2 + 256 + j0]);
    f16x8 vi = *reinterpret_cast<const f16x8*>(&innb[(size_t)n * NH + j0]);
    f16x8 vh = *reinterpret_cast<const f16x8*>(&hnb[(size_t)n * NH + j0]);
    _Float16* xp = xcat + (size_t)n * LDC2 + 256 + j0;
    f16x8 hp8 = *reinterpret_cast<const f16x8*>(xp);
    f16x8 o8;
#pragma unroll
    for (int q = 0; q < 8; ++q) {
        int j = j0 + q;
        float r = 1.f / (1.f + expf(-((float)vr[q] + b_ih[j] + b_hh[j])));
        float z = 1.f / (1.f + expf(-((float)vz[q] + b_ih[NH + j] + b_hh[NH + j])));
        float nn = tanhf((float)vi[q] + b_ih[2 * NH + j] + r * ((float)vh[q] + b_hh[2 * NH + j]));
        float hv = (1.f - z) * nn + z * (float)hp8[q];
        o8[q] = (_Float16)fmaxf(hv, 0.f);
    }
    *reinterpret_cast<f16x8*>(xp) = o8;
}

// mol GRU combine (f32 hprev/out), gi/gh f16 dense NH3
__global__ __launch_bounds__(256) void gru_combine(
    const _Float16* __restrict__ gi, const _Float16* __restrict__ gh,
    const float* __restrict__ b_ih, const float* __restrict__ b_hh,
    const float* __restrict__ hprev, float* __restrict__ out, int M)
{
    size_t t = (size_t)blockIdx.x * 256 + threadIdx.x;
    if (t >= (size_t)M * 32) return;
    int n = (int)(t >> 5), j0 = ((int)t & 31) * 8;
    size_t b3 = (size_t)n * NH3;
    f16x8 vir = *reinterpret_cast<const f16x8*>(&gi[b3 + j0]);
    f16x8 viz = *reinterpret_cast<const f16x8*>(&gi[b3 + NH + j0]);
    f16x8 vin = *reinterpret_cast<const f16x8*>(&gi[b3 + 2 * NH + j0]);
    f16x8 vhr = *reinterpret_cast<const f16x8*>(&gh[b3 + j0]);
    f16x8 vhz = *reinterpret_cast<const f16x8*>(&gh[b3 + NH + j0]);
    f16x8 vhn = *reinterpret_cast<const f16x8*>(&gh[b3 + 2 * NH + j0]);
    size_t hb = (size_t)n * NH + j0;
#pragma unroll
    for (int q = 0; q < 8; ++q) {
        int j = j0 + q;
        float r = 1.f / (1.f + expf(-((float)vir[q] + b_ih[j] + (float)vhr[q] + b_hh[j])));
        float z = 1.f / (1.f + expf(-((float)viz[q] + b_ih[NH + j] + (float)vhz[q] + b_hh[NH + j])));
        float nn = tanhf((float)vin[q] + b_ih[2 * NH + j] + r * ((float)vhn[q] + b_hh[2 * NH + j]));
        out[hb + q] = fmaxf((1.f - z) * nn + z * hprev[hb + q], 0.f);
    }
}

extern "C" void kernel_launch(void* const* d_in, const int* in_sizes, int n_in,
                              void* d_out, int out_size, void* d_ws, size_t ws_size,
                              hipStream_t stream)
{
    const float* x          = (const float*)d_in[0];
    const float* edge_attr  = (const float*)d_in[1];
    const float* lin1_w     = (const float*)d_in[2];
    const float* lin1_b     = (const float*)d_in[3];
    const float* gate_att_l = (const float*)d_in[4];
    const float* gate_att_r = (const float*)d_in[5];
    const float* gate_lin1_w= (const float*)d_in[6];
    const float* gate_lin2_w= (const float*)d_in[7];
    const float* gate_bias  = (const float*)d_in[8];
    const float* atom_lin_w = (const float*)d_in[9];
    const float* atom_att_src=(const float*)d_in[10];
    const float* atom_att_dst=(const float*)d_in[11];
    const float* atom_bias  = (const float*)d_in[12];
    const float* gru_w_ih   = (const float*)d_in[13];
    const float* gru_w_hh   = (const float*)d_in[14];
    const float* gru_b_ih   = (const float*)d_in[15];
    const float* gru_b_hh   = (const float*)d_in[16];
    const float* mol_lin_w  = (const float*)d_in[17];
    const float* mol_att_src= (const float*)d_in[18];
    const float* mol_att_dst= (const float*)d_in[19];
    const float* mol_bias   = (const float*)d_in[20];
    const float* mol_gru_w_ih=(const float*)d_in[21];
    const float* mol_gru_w_hh=(const float*)d_in[22];
    const float* mol_gru_b_ih=(const float*)d_in[23];
    const float* mol_gru_b_hh=(const float*)d_in[24];
    const float* lin2_w     = (const float*)d_in[25];
    const float* lin2_b     = (const float*)d_in[26];
    const float* fc_w       = (const float*)d_in[27];
    const float* fc_b       = (const float*)d_in[28];
    const int*   edge_index = (const int*)d_in[29];
    const int*   batch      = (const int*)d_in[30];

    const int N = in_sizes[0] / FNODE;
    const int E = in_sizes[1] / FEDGE;
    const int G = NGRAPH;
    const int* src = edge_index;
    const int* dst = edge_index + E;

    float* w = (float*)d_ws;
    size_t o = 0;
    auto alloc = [&](size_t cnt) { size_t r = o; o += cnt; return r; };
    const size_t o_B1cat = alloc((size_t)N * NH);          // f16 N x 512: [tmp | xcur]
    const size_t o_B2    = alloc((size_t)N * NH / 2);      // f16 nodepart -> hraw ; mol f32 bufs
    const size_t o_B3    = alloc((size_t)CHUNK * 512);     // srz(512)+inn(256)+hn(256) f16 ; xpad
    const size_t o_wcat  = alloc((size_t)512 * 512);
    const size_t o_elog  = alloc((size_t)E);
    const size_t o_dotr  = alloc((size_t)N);
    const size_t o_adst  = alloc((size_t)N);
    const size_t o_ddot  = alloc((size_t)G);
    const size_t o_vvec  = alloc((size_t)NH);
    const size_t o_usrc  = alloc((size_t)NH);
    const size_t o_udst  = alloc((size_t)NH);
    const size_t o_rowp  = alloc((size_t)N + 1);
    const size_t o_srowp = alloc((size_t)N + 1);
    const size_t o_deg   = alloc((size_t)N);
    const size_t o_curs  = alloc((size_t)N);
    const size_t o_bsum  = alloc((size_t)512);             // scan partials + offsets
    const size_t o_esrc  = alloc((size_t)E);
    const size_t o_pos   = alloc((size_t)E);
    const size_t o_seid  = alloc((size_t)E);
    const size_t o_ecsc  = alloc((size_t)E * 4);           // f16 E x 8
    const size_t o_pcsc  = alloc((size_t)E);
    const size_t o_gptr  = alloc((size_t)G + 1);
    if (o * sizeof(float) > ws_size) {
        fprintf(stderr, "kernel_launch: ws too small: need %zu have %zu\n", o * 4, ws_size);
        return;
    }

    _Float16* B1cat = (_Float16*)(w + o_B1cat);
    _Float16* xcur  = B1cat + NH;          // row stride LDC2, cols 256-511
    _Float16* B2 = (_Float16*)(w + o_B2);
    float* B3   = w + o_B3;
    float* wcat = w + o_wcat;
    float* elog = w + o_elog;
    float* dotr = w + o_dotr;
    float* adst = w + o_adst;
    float* ddot = w + o_ddot;
    float* vvec = w + o_vvec;
    float* usrc = w + o_usrc;
    float* udst = w + o_udst;
    int* rowptr  = (int*)(w + o_rowp);
    int* srowptr = (int*)(w + o_srowp);
    int* deg     = (int*)(w + o_deg);
    int* cursor  = (int*)(w + o_curs);
    int* bsum    = (int*)(w + o_bsum);
    int* boff    = bsum + 256;
    int* esrc    = (int*)(w + o_esrc);
    int* pos     = (int*)(w + o_pos);
    int* seid    = (int*)(w + o_seid);
    _Float16* ecsc = (_Float16*)(w + o_ecsc);
    int* pcsc    = (int*)(w + o_pcsc);
    int* gptr    = (int*)(w + o_gptr);

    // mol-phase f32 sub-buffers inside B2 (node hraw dead by then)
    float* B2f = (float*)B2;
    float*    gout   = B2f;
    float*    hraw_g = B2f + (size_t)G * NH;
    float*    h_g    = B2f + (size_t)2 * G * NH;
    _Float16* gig    = (_Float16*)(B2f + (size_t)3 * G * NH);
    _Float16* ghg    = (_Float16*)(B2f + (size_t)3 * G * NH + (size_t)G * NH3 / 2);
    float*    emb    = B2f + (size_t)3 * G * NH + (size_t)G * NH3;

    const int BLK = 256;
    auto cdiv = [](size_t a, size_t b) { return (int)((a + b - 1) / b); };
    const int gridNodeWave = cdiv(N, 4);
    const int gridEdgeThr = cdiv(E, BLK);
    const int gridNodeThr = cdiv(N, BLK);
    const int CAP = 4096;
    const int gridNodeCap = gridNodeWave < CAP ? gridNodeWave : CAP;
    const int nScanB = cdiv(N, SCAN_TILE);   // <= 256 for N <= 524288

    auto run_scan = [&](int* rowp) {
        scan_pass1<<<nScanB, BLK, 0, stream>>>(deg, bsum, N);
        scan_pass2<<<1, BLK, 0, stream>>>(bsum, boff, nScanB, rowp + N);
        scan_pass3<<<nScanB, BLK, 0, stream>>>(deg, boff, rowp, cursor, N);
    };

    // ---------- CSR + CSC build (once) ----------
    zero_i32<<<gridNodeThr, BLK, 0, stream>>>(deg, N);
    hist_k<<<gridEdgeThr, BLK, 0, stream>>>(dst, deg, E);
    run_scan(rowptr);
    csr_scatter<<<gridEdgeThr, BLK, 0, stream>>>(src, dst, cursor, esrc, pos, E);
    zero_i32<<<gridNodeThr, BLK, 0, stream>>>(deg, N);
    hist_k<<<gridEdgeThr, BLK, 0, stream>>>(src, deg, E);
    run_scan(srowptr);
    csc_scatter<<<gridEdgeThr, BLK, 0, stream>>>(src, cursor, seid, E);
    edge_csc_build<<<gridEdgeThr, BLK, 0, stream>>>(edge_attr, seid, pos, ecsc, pcsc, E);
    gptr_build<<<cdiv(G + 1, BLK), BLK, 0, stream>>>(batch, gptr, N, G);

    // Per-layer tail: tmp(B1cat cols 0-255) = elu(hraw@Wh^T + bh);
    // then chunked gemm_gru (srz,inn,hn) + combine2 (xcur in place)
    auto run_tail = [&](const float* Wh, const float* bh,
                        const float* wih, const float* whh,
                        const float* bih, const float* bhh) {
        _Float16* srz  = (_Float16*)B3;
        _Float16* innb = srz + (size_t)CHUNK * LDC2;
        _Float16* hnb  = innb + (size_t)CHUNK * NH;
        build_wcat<<<1024, BLK, 0, stream>>>(wih, whh, wcat);
        dim3 gFull(1, cdiv(N, 64));
        gemm_mfma<2, 1, 1><<<gFull, BLK, 0, stream>>>(B2, Wh, bh, B1cat,
                                                      N, NH, NH, NH, NH, LDC2, 0, NH);
        for (int c0 = 0; c0 < N; c0 += CHUNK) {
            int mc = (N - c0) < CHUNK ? (N - c0) : CHUNK;
            dim3 gG(1, cdiv(mc, 64), 4);
            gemm_gru<<<gG, BLK, 0, stream>>>(B1cat + (size_t)c0 * LDC2, wcat, wih, whh,
                                             srz, innb, hnb, mc);
            gru_combine2<<<cdiv((size_t)mc * 32, BLK), BLK, 0, stream>>>(
                srz, innb, hnb, bih, bhh, B1cat + (size_t)c0 * LDC2, mc);
        }
    };

    dim3 gridNH(1, cdiv(N, 64));

    // ---------- x0 = lrelu(x @ lin1_w^T + lin1_b) -> xcur (B1cat cols 256-511) ----------
    _Float16* xpad = (_Float16*)B3;     // N*160 f16 = 32 MB < B3 (51.2 MB); dead before tails
    pad_cast_f16<<<cdiv((size_t)N * KPAD_X, BLK), BLK, 0, stream>>>(x, xpad, N, FNODE, KPAD_X);
    gemm_mfma<1, 1, 1><<<gridNH, BLK, 0, stream>>>(xpad, lin1_w, lin1_b, B1cat,
                                                   N, KPAD_X, NH, KPAD_X, FNODE, LDC2, NH, FNODE);

    // ---------- GATEConv ----------
    gemm_mfma<0, 1, 1><<<gridNH, BLK, 0, stream>>>(xcur, gate_lin1_w, nullptr, B2,
                                                   N, NH, NH, LDC2, LDW_GATE1, NH, 0, NH);
    node_dot<_Float16><<<gridNodeCap, BLK, 0, stream>>>(xcur, LDC2, gate_att_r, nullptr,
                                                        dotr, nullptr, N);
    gate_part_csc<<<gridNodeCap, BLK, 0, stream>>>(B2, ecsc, gate_lin1_w, gate_att_l,
                                                   srowptr, pcsc, elog, N);
    gate_agg_csr<<<gridNodeWave, BLK, 0, stream>>>(xcur, LDC2, elog, dotr, rowptr, esrc, B2, N);
    run_tail(gate_lin2_w, gate_bias, gru_w_ih, gru_w_hh, gru_b_ih, gru_b_hh);

    // ---------- 3 GATConv layers ----------
    for (int l = 0; l < 3; ++l) {
        const float* wl = atom_lin_w + (size_t)l * NH * NH;
        matvec_left<<<1, BLK, 0, stream>>>(wl, atom_att_src + l * NH, usrc);
        matvec_left<<<1, BLK, 0, stream>>>(wl, atom_att_dst + l * NH, udst);
        node_dot<_Float16><<<gridNodeCap, BLK, 0, stream>>>(xcur, LDC2, usrc, udst, dotr, adst, N);
        gat_agg_csr<<<gridNodeWave, BLK, 0, stream>>>(xcur, LDC2, dotr, adst, rowptr, esrc, B2, N);
        run_tail(wl, atom_bias + l * NH,
                 gru_w_ih + (size_t)(l + 1) * NH3 * NH, gru_w_hh + (size_t)(l + 1) * NH3 * NH,
                 gru_b_ih + (size_t)(l + 1) * NH3, gru_b_hh + (size_t)(l + 1) * NH3);
    }

    // ---------- Molecule pooling ----------
    const int gridGWave = cdiv(G, 4);
    graph_sum_relu<<<gridGWave, BLK, 0, stream>>>(xcur, LDC2, gptr, gout, G);
    matvec_left<<<1, BLK, 0, stream>>>(mol_lin_w, mol_att_src, usrc);
    matvec_left<<<1, BLK, 0, stream>>>(mol_lin_w, mol_att_dst, vvec);
    node_dot<_Float16><<<gridNodeCap, BLK, 0, stream>>>(xcur, LDC2, usrc, nullptr, dotr, nullptr, N);

    dim3 gridGH(1, cdiv(G, 64));
    dim3 gridGD(3, cdiv(G, 64), 2);
    for (int t = 0; t < 2; ++t) {
        node_dot<float><<<gridGWave, BLK, 0, stream>>>(gout, NH, vvec, nullptr, ddot, nullptr, G);
        mol_agg_csr<<<gridGWave, BLK, 0, stream>>>(xcur, LDC2, dotr, ddot, gptr, hraw_g, G);
        gemm_mfma<2, 0, 0><<<gridGH, BLK, 0, stream>>>(hraw_g, mol_lin_w, mol_bias, h_g,
                                                       G, NH, NH, NH, NH, NH, 0, NH);
        gemm_mfma2<0, 1><<<gridGD, BLK, 0, stream>>>(h_g, gout, mol_gru_w_ih, mol_gru_w_hh,
                                                     gig, ghg, G, NH, NH3);
        gru_combine<<<cdiv((size_t)G * 32, BLK), BLK, 0, stream>>>(
            gig, ghg, mol_gru_b_ih, mol_gru_b_hh, gout, gout, G);
    }

    // ---------- readout ----------
    gemm_mfma<0, 0, 0><<<gridGH, BLK, 0, stream>>>(gout, lin2_w, lin2_b, emb,
                                                   G, NH, NH, NH, NH, NH, 0, NH);
    dim3 gridFc(1, cdiv(G, 64));
    gemm_nt<<<gridFc, BLK, 0, stream>>>(emb, fc_w, fc_b, (float*)d_out, G, NH, NTASK, NH, 0);
}

// Round 12
// 3391.920 us; speedup vs baseline: 1.8260x; 1.1607x over previous
//
#include <hip/hip_runtime.h>
#include <math.h>
#include <stdio.h>
#include <stdint.h>

#define NH 256
#define NH3 768
#define FNODE 133
#define FEDGE 7
#define LDW_GATE1 263   // H + F_EDGE
#define NGRAPH 4096
#define NTASK 12
#define SLOPE 0.01f
#define CHUNK 25000
#define PADK 40         // f16 elems per LDS row: 32 + 8 pad (80B stride, 16B aligned)
#define KPAD_X 160      // x padded K (133 -> 160)
#define LDC2 512        // interleaved node-state row stride (f16): [tmp | xcur]
#define SCAN_TILE 2048  // elems per block in hierarchical scan (256 thr x 8)

typedef __attribute__((ext_vector_type(4))) float f32x4;
typedef __attribute__((ext_vector_type(8))) _Float16 f16x8;
typedef __attribute__((ext_vector_type(4))) _Float16 f16x4;
typedef __attribute__((ext_vector_type(2))) _Float16 f16x2;

static __device__ __forceinline__ float lrelu_f(float x) { return x > 0.f ? x : SLOPE * x; }
static __device__ __forceinline__ f16x2 lrelu2(f16x2 v) {
    f16x2 z = {(_Float16)0.f, (_Float16)0.f};
    f16x2 s = {(_Float16)SLOPE, (_Float16)SLOPE};
    return __builtin_elementwise_max(v, z) + __builtin_elementwise_min(v, z) * s;
}

// ---------------- MFMA fp16 GEMM core (BM=64, BN=256) ----------------
// ACT: 0 none, 1 lrelu, 2 elu, 3 sigmoid ; OB: 0 f32 out, 1 f16 out ; AF16: A is f16
template<int ACT, int OB, int AF16>
static __device__ __forceinline__ void gemm_core(
    _Float16* As, _Float16* Ws,
    const void* __restrict__ Av, const float* __restrict__ W,
    const float* __restrict__ bias, const float* __restrict__ bias2,
    void* __restrict__ Cout,
    int M, int K, int Nout, int ldA, int ldW, int ldC, int ocol, int Kw, int bn)
{
    const int bm = blockIdx.y * 64;
    const int tid = threadIdx.x;
    const int wv = tid >> 6, lane = tid & 63;
    const int l15 = lane & 15, l4 = lane >> 4;
    const bool kvec = ((K & 31) == 0) && ((ldA & 3) == 0);
    const bool wvec = ((K & 31) == 0) && ((ldW & 3) == 0) && (Kw == K);
    const int ar = tid >> 2, akq = (tid & 3) * 8;

    f32x4 acc[16];
#pragma unroll
    for (int c = 0; c < 16; ++c) acc[c] = (f32x4){0.f, 0.f, 0.f, 0.f};

    for (int k0 = 0; k0 < K; k0 += 32) {
        {
            const int ga = bm + ar;
            _Float16* dstA = &As[ar * PADK + akq];
            if (AF16) {
                const _Float16* A = (const _Float16*)Av;
                if (ga < M) {
                    *reinterpret_cast<f16x8*>(dstA) =
                        *reinterpret_cast<const f16x8*>(A + (size_t)ga * ldA + k0 + akq);
                } else {
#pragma unroll
                    for (int j = 0; j < 8; ++j) dstA[j] = (_Float16)0.f;
                }
            } else {
                const float* A = (const float*)Av;
                if (ga < M && kvec) {
                    const float4* ap4 = reinterpret_cast<const float4*>(A + (size_t)ga * ldA + k0 + akq);
                    float4 v0 = ap4[0], v1 = ap4[1];
                    dstA[0] = (_Float16)v0.x; dstA[1] = (_Float16)v0.y;
                    dstA[2] = (_Float16)v0.z; dstA[3] = (_Float16)v0.w;
                    dstA[4] = (_Float16)v1.x; dstA[5] = (_Float16)v1.y;
                    dstA[6] = (_Float16)v1.z; dstA[7] = (_Float16)v1.w;
                } else {
                    const float* ap = A + (size_t)ga * ldA + k0 + akq;
#pragma unroll
                    for (int j = 0; j < 8; ++j) {
                        int gk = k0 + akq + j;
                        float v = (ga < M && gk < K) ? ap[j] : 0.f;
                        dstA[j] = (_Float16)v;
                    }
                }
            }
        }
#pragma unroll
        for (int q = 0; q < 4; ++q) {
            const int r = ar + 64 * q;
            const int gw = bn + r;
            _Float16* dstW = &Ws[r * PADK + akq];
            if (gw < Nout && wvec) {
                const float4* wp4 = reinterpret_cast<const float4*>(W + (size_t)gw * ldW + k0 + akq);
                float4 v0 = wp4[0], v1 = wp4[1];
                dstW[0] = (_Float16)v0.x; dstW[1] = (_Float16)v0.y;
                dstW[2] = (_Float16)v0.z; dstW[3] = (_Float16)v0.w;
                dstW[4] = (_Float16)v1.x; dstW[5] = (_Float16)v1.y;
                dstW[6] = (_Float16)v1.z; dstW[7] = (_Float16)v1.w;
            } else {
                const float* wp = W + (size_t)gw * ldW + k0 + akq;
#pragma unroll
                for (int j = 0; j < 8; ++j) {
                    int gk = k0 + akq + j;
                    float v = (gw < Nout && gk < Kw) ? wp[j] : 0.f;
                    dstW[j] = (_Float16)v;
                }
            }
        }
        __syncthreads();
        f16x8 af = *reinterpret_cast<const f16x8*>(&As[(wv * 16 + l15) * PADK + l4 * 8]);
#pragma unroll
        for (int c = 0; c < 16; ++c) {
            f16x8 wf = *reinterpret_cast<const f16x8*>(&Ws[(c * 16 + l15) * PADK + l4 * 8]);
            acc[c] = __builtin_amdgcn_mfma_f32_16x16x32_f16(af, wf, acc[c], 0, 0, 0);
        }
        __syncthreads();
    }

#pragma unroll
    for (int c = 0; c < 16; ++c) {
        int gc = bn + c * 16 + l15;
        if (gc >= Nout) continue;
        float bv = (bias ? bias[gc] : 0.f) + (bias2 ? bias2[gc] : 0.f);
#pragma unroll
        for (int q = 0; q < 4; ++q) {
            int gr = bm + wv * 16 + l4 * 4 + q;
            if (gr >= M) continue;
            float v = acc[c][q] + bv;
            if (ACT == 1) v = lrelu_f(v);
            else if (ACT == 2) v = (v > 0.f ? v : expm1f(v));
            else if (ACT == 3) v = 1.f / (1.f + expf(-v));
            size_t off = (size_t)gr * ldC + ocol + gc;
            if (OB) ((_Float16*)Cout)[off] = (_Float16)v;
            else    ((float*)Cout)[off] = v;
        }
    }
}

template<int ACT, int OB, int AF16>
__global__ __launch_bounds__(256, 4) void gemm_mfma(
    const void* __restrict__ A, const float* __restrict__ W,
    const float* __restrict__ bias, void* __restrict__ Cout,
    int M, int K, int Nout, int ldA, int ldW, int ldC, int ocol, int Kw)
{
    __shared__ _Float16 As[64 * PADK];
    __shared__ _Float16 Ws[256 * PADK];
    gemm_core<ACT, OB, AF16>(As, Ws, A, W, bias, nullptr, Cout,
                             M, K, Nout, ldA, ldW, ldC, ocol, Kw, blockIdx.x * 256);
}

// GRU launch A: z=0/1: srz = sigmoid(Acat@wcat^T + b_ih + b_hh) (r cols 0-255, z cols 256-511)
//               z=2:   inn = tmp @ wih_n^T + b_ih_n
__global__ __launch_bounds__(256, 4) void gemm_gru_a(
    const _Float16* __restrict__ Acat, const float* __restrict__ wcat,
    const float* __restrict__ wih, const float* __restrict__ bih, const float* __restrict__ bhh,
    _Float16* __restrict__ srz, _Float16* __restrict__ innb, int mc)
{
    __shared__ _Float16 As[64 * PADK];
    __shared__ _Float16 Ws[256 * PADK];
    int z = blockIdx.z;
    if (z < 2)
        gemm_core<3, 1, 1>(As, Ws, Acat, wcat, bih, bhh, srz,
                           mc, 512, 512, LDC2, 512, 512, 0, 512, z * 256);
    else
        gemm_core<0, 1, 1>(As, Ws, Acat, wih + 512 * NH, bih + 512, nullptr, innb,
                           mc, NH, NH, LDC2, NH, NH, 0, NH, 0);
}

// GRU launch B: hn = xcur @ whh_n^T + b_hh_n ; in-epilogue GRU combine + ReLU, xcur in place;
// fused per-row dots with us/ud (next layer's attention vectors) -> dotr/adst
__global__ __launch_bounds__(256, 4) void gemm_gru_b(
    _Float16* __restrict__ Acat, const float* __restrict__ whh, const float* __restrict__ bhh,
    const _Float16* __restrict__ srz, const _Float16* __restrict__ innb,
    const float* __restrict__ us, const float* __restrict__ ud,
    float* __restrict__ dotr, float* __restrict__ adst, int mc)
{
    __shared__ _Float16 As[64 * PADK];
    __shared__ _Float16 Ws[256 * PADK];
    const float* Wn = whh + 512 * NH;
    const int bm = blockIdx.y * 64;
    const int tid = threadIdx.x;
    const int wv = tid >> 6, lane = tid & 63;
    const int l15 = lane & 15, l4 = lane >> 4;
    const int ar = tid >> 2, akq = (tid & 3) * 8;

    f32x4 acc[16];
#pragma unroll
    for (int c = 0; c < 16; ++c) acc[c] = (f32x4){0.f, 0.f, 0.f, 0.f};

    for (int k0 = 0; k0 < NH; k0 += 32) {
        {
            const int ga = bm + ar;
            _Float16* dstA = &As[ar * PADK + akq];
            if (ga < mc) {
                *reinterpret_cast<f16x8*>(dstA) =
                    *reinterpret_cast<const f16x8*>(Acat + (size_t)ga * LDC2 + NH + k0 + akq);
            } else {
#pragma unroll
                for (int j = 0; j < 8; ++j) dstA[j] = (_Float16)0.f;
            }
        }
#pragma unroll
        for (int q = 0; q < 4; ++q) {
            const int r = ar + 64 * q;
            _Float16* dstW = &Ws[r * PADK + akq];
            const float4* wp4 = reinterpret_cast<const float4*>(Wn + (size_t)r * NH + k0 + akq);
            float4 v0 = wp4[0], v1 = wp4[1];
            dstW[0] = (_Float16)v0.x; dstW[1] = (_Float16)v0.y;
            dstW[2] = (_Float16)v0.z; dstW[3] = (_Float16)v0.w;
            dstW[4] = (_Float16)v1.x; dstW[5] = (_Float16)v1.y;
            dstW[6] = (_Float16)v1.z; dstW[7] = (_Float16)v1.w;
        }
        __syncthreads();
        f16x8 af = *reinterpret_cast<const f16x8*>(&As[(wv * 16 + l15) * PADK + l4 * 8]);
#pragma unroll
        for (int c = 0; c < 16; ++c) {
            f16x8 wf = *reinterpret_cast<const f16x8*>(&Ws[(c * 16 + l15) * PADK + l4 * 8]);
            acc[c] = __builtin_amdgcn_mfma_f32_16x16x32_f16(af, wf, acc[c], 0, 0, 0);
        }
        __syncthreads();
    }

    float pd1[4] = {0.f, 0.f, 0.f, 0.f};
    float pd2[4] = {0.f, 0.f, 0.f, 0.f};
#pragma unroll
    for (int c = 0; c < 16; ++c) {
        int gc = c * 16 + l15;
        float bhn = bhh[512 + gc];
        float usv = us ? us[gc] : 0.f;
        float udv = ud ? ud[gc] : 0.f;
#pragma unroll
        for (int q = 0; q < 4; ++q) {
            int gr = bm + wv * 16 + l4 * 4 + q;
            if (gr >= mc) continue;
            float hn = acc[c][q] + bhn;
            float rr = (float)srz[(size_t)gr * 512 + gc];
            float zz = (float)srz[(size_t)gr * 512 + 256 + gc];
            float inn = (float)innb[(size_t)gr * NH + gc];
            float nn = tanhf(inn + rr * hn);
            size_t xoff = (size_t)gr * LDC2 + NH + gc;
            float xold = (float)Acat[xoff];
            float hv = fmaxf((1.f - zz) * nn + zz * xold, 0.f);
            Acat[xoff] = (_Float16)hv;
            pd1[q] += hv * usv;
            pd2[q] += hv * udv;
        }
    }
    if (us) {
#pragma unroll
        for (int off = 1; off < 16; off <<= 1) {
#pragma unroll
            for (int q = 0; q < 4; ++q) {
                pd1[q] += __shfl_xor(pd1[q], off);
                pd2[q] += __shfl_xor(pd2[q], off);
            }
        }
        if (l15 == 0) {
#pragma unroll
            for (int q = 0; q < 4; ++q) {
                int gr = bm + wv * 16 + l4 * 4 + q;
                if (gr < mc) {
                    dotr[gr] = pd1[q];
                    if (ud) adst[gr] = pd2[q];
                }
            }
        }
    }
}

// dual GEMM for mol GRU (f32 A)
template<int ACT, int OB>
__global__ __launch_bounds__(256, 4) void gemm_mfma2(
    const float* __restrict__ A0, const float* __restrict__ A1,
    const float* __restrict__ W0, const float* __restrict__ W1,
    void* __restrict__ C0, void* __restrict__ C1, int M, int K, int Nout)
{
    __shared__ _Float16 As[64 * PADK];
    __shared__ _Float16 Ws[256 * PADK];
    int bn = blockIdx.x * 256;
    if (blockIdx.z == 0)
        gemm_core<ACT, OB, 0>(As, Ws, A0, W0, nullptr, nullptr, C0, M, K, Nout, K, K, Nout, 0, K, bn);
    else
        gemm_core<ACT, OB, 0>(As, Ws, A1, W1, nullptr, nullptr, C1, M, K, Nout, K, K, Nout, 0, K, bn);
}

// Wcat[j][k] (512x512): k<256 -> wih[j][k] ; else whh[j][k-256]
__global__ void build_wcat(const float* __restrict__ wih, const float* __restrict__ whh,
                           float* __restrict__ wcat)
{
    int i = blockIdx.x * 256 + threadIdx.x;
    if (i >= 512 * 512) return;
    int j = i >> 9, k = i & 511;
    wcat[i] = (k < 256) ? wih[j * 256 + k] : whh[j * 256 + (k - 256)];
}

__global__ void pad_cast_f16(const float* __restrict__ in, _Float16* __restrict__ out,
                             int M, int Kin, int Kout)
{
    size_t i = (size_t)blockIdx.x * 256 + threadIdx.x;
    if (i >= (size_t)M * Kout) return;
    int r = (int)(i / Kout), k = (int)(i % Kout);
    out[i] = (k < Kin) ? (_Float16)in[(size_t)r * Kin + k] : (_Float16)0.f;
}

// ---------------- fp32 fallback GEMM (final 12-col fc only) ----------------
__global__ __launch_bounds__(256) void gemm_nt(
    const float* __restrict__ A, const float* __restrict__ W,
    const float* __restrict__ bias, float* __restrict__ C,
    int M, int K, int Nout, int ldW, int act)
{
    __shared__ float As[16][65];
    __shared__ float Ws[16][65];
    const int bm = blockIdx.y * 64;
    const int bn = blockIdx.x * 64;
    const int tid = threadIdx.x;
    const int tr = tid >> 4, tc = tid & 15;
    const int lrow = tid >> 2, lk = (tid & 3) * 4;
    float acc[4][4] = {};
    for (int k0 = 0; k0 < K; k0 += 16) {
#pragma unroll
        for (int j = 0; j < 4; ++j) {
            int gk = k0 + lk + j;
            int ga = bm + lrow;
            As[lk + j][lrow] = (ga < M && gk < K) ? A[(size_t)ga * K + gk] : 0.f;
            int gw = bn + lrow;
            Ws[lk + j][lrow] = (gw < Nout && gk < K) ? W[(size_t)gw * ldW + gk] : 0.f;
        }
        __syncthreads();
#pragma unroll
        for (int kk = 0; kk < 16; ++kk) {
            float av[4], bv[4];
#pragma unroll
            for (int i = 0; i < 4; ++i) av[i] = As[kk][tr * 4 + i];
#pragma unroll
            for (int i = 0; i < 4; ++i) bv[i] = Ws[kk][tc * 4 + i];
#pragma unroll
            for (int i = 0; i < 4; ++i)
#pragma unroll
                for (int j = 0; j < 4; ++j) acc[i][j] += av[i] * bv[j];
        }
        __syncthreads();
    }
#pragma unroll
    for (int i = 0; i < 4; ++i) {
        int m = bm + tr * 4 + i;
        if (m >= M) continue;
#pragma unroll
        for (int j = 0; j < 4; ++j) {
            int n = bn + tc * 4 + j;
            if (n >= Nout) continue;
            float v = acc[i][j];
            if (bias) v += bias[n];
            if (act == 1) v = lrelu_f(v);
            C[(size_t)m * Nout + n] = v;
        }
    }
}

// ---------------- CSR/CSC build ----------------
__global__ void zero_i32(int* p, int n) {
    int i = blockIdx.x * 256 + threadIdx.x;
    if (i < n) p[i] = 0;
}
__global__ void hist_k(const int* __restrict__ key, int* __restrict__ deg, int E) {
    int i = blockIdx.x * 256 + threadIdx.x;
    if (i < E) atomicAdd(&deg[key[i]], 1);
}
__global__ __launch_bounds__(256) void scan_pass1(
    const int* __restrict__ deg, int* __restrict__ bsum, int Nn)
{
    __shared__ int lds[256];
    int b = blockIdx.x, t = threadIdx.x;
    int base = b * SCAN_TILE + t * 8;
    int s = 0;
#pragma unroll
    for (int q = 0; q < 8; ++q) { int i = base + q; if (i < Nn) s += deg[i]; }
    lds[t] = s;
    __syncthreads();
    for (int off = 128; off; off >>= 1) {
        if (t < off) lds[t] += lds[t + off];
        __syncthreads();
    }
    if (t == 0) bsum[b] = lds[0];
}
__global__ __launch_bounds__(256) void scan_pass2(
    const int* __restrict__ bsum, int* __restrict__ boff, int nb, int* __restrict__ total)
{
    __shared__ int lds[256];
    int t = threadIdx.x;
    int v = (t < nb) ? bsum[t] : 0;
    lds[t] = v;
    __syncthreads();
    for (int off = 1; off < 256; off <<= 1) {
        int u = (t >= off) ? lds[t - off] : 0;
        __syncthreads();
        lds[t] += u;
        __syncthreads();
    }
    if (t < nb) boff[t] = lds[t] - v;
    if (t == 255 && total) *total = lds[255];
}
__global__ __launch_bounds__(256) void scan_pass3(
    const int* __restrict__ deg, const int* __restrict__ boff,
    int* __restrict__ rowptr, int* __restrict__ cursor, int Nn)
{
    __shared__ int lds[256];
    int b = blockIdx.x, t = threadIdx.x;
    int base = b * SCAN_TILE + t * 8;
    int v[8];
    int s = 0;
#pragma unroll
    for (int q = 0; q < 8; ++q) { int i = base + q; v[q] = (i < Nn) ? deg[i] : 0; s += v[q]; }
    lds[t] = s;
    __syncthreads();
    for (int off = 1; off < 256; off <<= 1) {
        int u = (t >= off) ? lds[t - off] : 0;
        __syncthreads();
        lds[t] += u;
        __syncthreads();
    }
    int run = boff[b] + lds[t] - s;
#pragma unroll
    for (int q = 0; q < 8; ++q) {
        int i = base + q;
        if (i < Nn) { rowptr[i] = run; cursor[i] = run; run += v[q]; }
    }
}
__global__ void csr_scatter(const int* __restrict__ src, const int* __restrict__ dst,
                            int* __restrict__ cursor, int* __restrict__ esrc,
                            int* __restrict__ pos, int E)
{
    int e = blockIdx.x * 256 + threadIdx.x;
    if (e < E) {
        int p = atomicAdd(&cursor[dst[e]], 1);
        esrc[p] = src[e];
        pos[e] = p;
    }
}
__global__ void csc_scatter(const int* __restrict__ src, int* __restrict__ cursor,
                            int* __restrict__ seid, int E)
{
    int e = blockIdx.x * 256 + threadIdx.x;
    if (e < E) {
        int p = atomicAdd(&cursor[src[e]], 1);
        seid[p] = e;
    }
}
__global__ void edge_csc_build(const float* __restrict__ edge_attr, const int* __restrict__ seid,
                               const int* __restrict__ pos, _Float16* __restrict__ ecsc,
                               int* __restrict__ pcsc, int E)
{
    int p = blockIdx.x * 256 + threadIdx.x;
    if (p >= E) return;
    int e = seid[p];
    pcsc[p] = pos[e];
    const float* ep = edge_attr + (size_t)e * FEDGE;
#pragma unroll
    for (int f = 0; f < FEDGE; ++f) ecsc[(size_t)p * 8 + f] = (_Float16)ep[f];
    ecsc[(size_t)p * 8 + 7] = (_Float16)0.f;
}
__global__ void gptr_build(const int* __restrict__ batch, int* __restrict__ gptr, int Nn, int G) {
    int g = blockIdx.x * 256 + threadIdx.x;
    if (g > G) return;
    int lo = 0, hi = Nn;
    while (lo < hi) { int mid = (lo + hi) >> 1; if (batch[mid] < g) lo = mid + 1; else hi = mid; }
    gptr[g] = lo;
}

// ---------------- GATE src-side partial logit (CSC, packed f16, 4-edge ILP) ----------------
__global__ __launch_bounds__(256) void gate_part_csc(
    const _Float16* __restrict__ nodepart, const _Float16* __restrict__ ecsc,
    const float* __restrict__ gate_lin1_w, const float* __restrict__ att_l,
    const int* __restrict__ srowptr, const int* __restrict__ pcsc,
    float* __restrict__ elogp, int Nn)
{
    int wv = threadIdx.x >> 6, lane = threadIdx.x & 63;
    int h0 = lane * 4;
    f16x2 wr2[2][FEDGE], al2[2];
#pragma unroll
    for (int p = 0; p < 2; ++p) {
        int ha = h0 + 2 * p, hb = ha + 1;
#pragma unroll
        for (int f = 0; f < FEDGE; ++f) {
            wr2[p][f][0] = (_Float16)gate_lin1_w[(size_t)ha * LDW_GATE1 + NH + f];
            wr2[p][f][1] = (_Float16)gate_lin1_w[(size_t)hb * LDW_GATE1 + NH + f];
        }
        al2[p][0] = (_Float16)att_l[ha];
        al2[p][1] = (_Float16)att_l[hb];
    }
    for (int s = blockIdx.x * 4 + wv; s < Nn; s += gridDim.x * 4) {
        int beg = srowptr[s], end = srowptr[s + 1];
        if (beg >= end) continue;
        f16x4 np4 = *reinterpret_cast<const f16x4*>(nodepart + (size_t)s * NH + h0);
        f16x2 np2[2];
        np2[0][0] = np4[0]; np2[0][1] = np4[1];
        np2[1][0] = np4[2]; np2[1][1] = np4[3];
        for (int j0 = beg; j0 < end; j0 += 4) {
            int nb = end - j0; if (nb > 4) nb = 4;
            f16x8 ev[4];
            int pp[4];
#pragma unroll
            for (int k = 0; k < 4; ++k) {
                int j = (k < nb) ? j0 + k : beg;
                pp[k] = pcsc[j];
                ev[k] = *reinterpret_cast<const f16x8*>(ecsc + (size_t)j * 8);
            }
            float acc[4];
#pragma unroll
            for (int k = 0; k < 4; ++k) {
                f16x2 v0 = np2[0], v1 = np2[1];
#pragma unroll
                for (int f = 0; f < FEDGE; ++f) {
                    f16x2 e2; e2[0] = ev[k][f]; e2[1] = ev[k][f];
                    v0 += e2 * wr2[0][f];
                    v1 += e2 * wr2[1][f];
                }
                float a = __builtin_amdgcn_fdot2(lrelu2(v0), al2[0], 0.f, false);
                a = __builtin_amdgcn_fdot2(lrelu2(v1), al2[1], a, false);
                acc[k] = a;
            }
#pragma unroll
            for (int off = 32; off; off >>= 1) {
#pragma unroll
                for (int k = 0; k < 4; ++k) acc[k] += __shfl_xor(acc[k], off);
            }
            if (lane == 0) {
#pragma unroll
                for (int k = 0; k < 4; ++k) if (k < nb) elogp[pp[k]] = acc[k];
            }
        }
    }
}

// ---------------- fused attention aggregation (CSR, wave per dst) ----------------
__global__ __launch_bounds__(256) void gat_agg_csr(
    const _Float16* __restrict__ X, int ldX,
    const float* __restrict__ asrc, const float* __restrict__ adst,
    const int* __restrict__ rowptr, const int* __restrict__ esrc,
    _Float16* __restrict__ hout, int Nn)
{
    int wv = threadIdx.x >> 6, lane = threadIdx.x & 63;
    int d = blockIdx.x * 4 + wv;
    if (d >= Nn) return;
    int beg = rowptr[d], end = rowptr[d + 1];
    float a0 = 0.f, a1 = 0.f, a2 = 0.f, a3 = 0.f;
    if (beg < end) {
        float ad = adst[d];
        float m = -3.4e38f;
        for (int j = beg + lane; j < end; j += 64)
            m = fmaxf(m, lrelu_f(asrc[esrc[j]] + ad));
#pragma unroll
        for (int off = 32; off; off >>= 1) m = fmaxf(m, __shfl_xor(m, off));
        float s = 0.f;
        for (int j = beg + lane; j < end; j += 64)
            s += expf(lrelu_f(asrc[esrc[j]] + ad) - m);
#pragma unroll
        for (int off = 32; off; off >>= 1) s += __shfl_xor(s, off);
        float inv = 1.f / (s + 1e-16f);
        for (int j = beg; j < end; ++j) {
            int sj = esrc[j];
            float a = expf(lrelu_f(asrc[sj] + ad) - m) * inv;
            const _Float16* xr = X + (size_t)sj * ldX;
            a0 += a * (float)xr[lane];       a1 += a * (float)xr[64 + lane];
            a2 += a * (float)xr[128 + lane]; a3 += a * (float)xr[192 + lane];
        }
    }
    _Float16* hr = hout + (size_t)d * NH;
    hr[lane] = (_Float16)a0; hr[64 + lane] = (_Float16)a1;
    hr[128 + lane] = (_Float16)a2; hr[192 + lane] = (_Float16)a3;
}

__global__ __launch_bounds__(256) void gate_agg_csr(
    const _Float16* __restrict__ X, int ldX,
    const float* __restrict__ elogp, const float* __restrict__ dotr,
    const int* __restrict__ rowptr, const int* __restrict__ esrc,
    _Float16* __restrict__ hout, int Nn)
{
    int wv = threadIdx.x >> 6, lane = threadIdx.x & 63;
    int d = blockIdx.x * 4 + wv;
    if (d >= Nn) return;
    int beg = rowptr[d], end = rowptr[d + 1];
    float a0 = 0.f, a1 = 0.f, a2 = 0.f, a3 = 0.f;
    if (beg < end) {
        float dd = dotr[d];
        float m = -3.4e38f;
        for (int j = beg + lane; j < end; j += 64)
            m = fmaxf(m, lrelu_f(elogp[j] + dd));
#pragma unroll
        for (int off = 32; off; off >>= 1) m = fmaxf(m, __shfl_xor(m, off));
        float s = 0.f;
        for (int j = beg + lane; j < end; j += 64)
            s += expf(lrelu_f(elogp[j] + dd) - m);
#pragma unroll
        for (int off = 32; off; off >>= 1) s += __shfl_xor(s, off);
        float inv = 1.f / (s + 1e-16f);
        for (int j = beg; j < end; ++j) {
            int sj = esrc[j];
            float a = expf(lrelu_f(elogp[j] + dd) - m) * inv;
            const _Float16* xr = X + (size_t)sj * ldX;
            a0 += a * (float)xr[lane];       a1 += a * (float)xr[64 + lane];
            a2 += a * (float)xr[128 + lane]; a3 += a * (float)xr[192 + lane];
        }
    }
    _Float16* hr = hout + (size_t)d * NH;
    hr[lane] = (_Float16)a0; hr[64 + lane] = (_Float16)a1;
    hr[128 + lane] = (_Float16)a2; hr[192 + lane] = (_Float16)a3;
}

__global__ __launch_bounds__(256) void mol_agg_csr(
    const _Float16* __restrict__ X, int ldX,
    const float* __restrict__ dotr, const float* __restrict__ ddot,
    const int* __restrict__ gptr, float* __restrict__ hout, int G)
{
    int wv = threadIdx.x >> 6, lane = threadIdx.x & 63;
    int g = blockIdx.x * 4 + wv;
    if (g >= G) return;
    int beg = gptr[g], end = gptr[g + 1];
    float a0 = 0.f, a1 = 0.f, a2 = 0.f, a3 = 0.f;
    if (beg < end) {
        float dg = ddot[g];
        float m = -3.4e38f;
        for (int i = beg + lane; i < end; i += 64)
            m = fmaxf(m, lrelu_f(dotr[i] + dg));
#pragma unroll
        for (int off = 32; off; off >>= 1) m = fmaxf(m, __shfl_xor(m, off));
        float s = 0.f;
        for (int i = beg + lane; i < end; i += 64)
            s += expf(lrelu_f(dotr[i] + dg) - m);
#pragma unroll
        for (int off = 32; off; off >>= 1) s += __shfl_xor(s, off);
        float inv = 1.f / (s + 1e-16f);
        for (int i = beg; i < end; ++i) {
            float a = expf(lrelu_f(dotr[i] + dg) - m) * inv;
            const _Float16* xr = X + (size_t)i * ldX;
            a0 += a * (float)xr[lane];       a1 += a * (float)xr[64 + lane];
            a2 += a * (float)xr[128 + lane]; a3 += a * (float)xr[192 + lane];
        }
    }
    float* hr = hout + (size_t)g * NH;
    hr[lane] = a0; hr[64 + lane] = a1; hr[128 + lane] = a2; hr[192 + lane] = a3;
}

__global__ __launch_bounds__(256) void graph_sum_relu(
    const _Float16* __restrict__ X, int ldX, const int* __restrict__ gptr,
    float* __restrict__ out, int G)
{
    int wv = threadIdx.x >> 6, lane = threadIdx.x & 63;
    int g = blockIdx.x * 4 + wv;
    if (g >= G) return;
    int beg = gptr[g], end = gptr[g + 1];
    float a0 = 0.f, a1 = 0.f, a2 = 0.f, a3 = 0.f;
    for (int i = beg; i < end; ++i) {
        const _Float16* xr = X + (size_t)i * ldX;
        a0 += (float)xr[lane];       a1 += (float)xr[64 + lane];
        a2 += (float)xr[128 + lane]; a3 += (float)xr[192 + lane];
    }
    float* hr = out + (size_t)g * NH;
    hr[lane] = fmaxf(a0, 0.f); hr[64 + lane] = fmaxf(a1, 0.f);
    hr[128 + lane] = fmaxf(a2, 0.f); hr[192 + lane] = fmaxf(a3, 0.f);
}

template<typename TX>
__global__ __launch_bounds__(256) void node_dot(
    const TX* __restrict__ X, int ldX, const float* __restrict__ v1, const float* __restrict__ v2,
    float* __restrict__ o1, float* __restrict__ o2, int M)
{
    __shared__ float s1[NH], s2[NH];
    int tid = threadIdx.x;
    s1[tid] = v1[tid];
    s2[tid] = v2 ? v2[tid] : 0.f;
    __syncthreads();
    int wv = tid >> 6, lane = tid & 63;
    for (int n = blockIdx.x * 4 + wv; n < M; n += gridDim.x * 4) {
        float a1 = 0.f, a2 = 0.f;
#pragma unroll
        for (int i = 0; i < 4; ++i) {
            int hh = i * 64 + lane;
            float xv = (float)X[(size_t)n * ldX + hh];
            a1 += xv * s1[hh];
            a2 += xv * s2[hh];
        }
#pragma unroll
        for (int off = 32; off; off >>= 1) { a1 += __shfl_xor(a1, off); a2 += __shfl_xor(a2, off); }
        if (lane == 0) { o1[n] = a1; if (o2) o2[n] = a2; }
    }
}

__global__ __launch_bounds__(256) void matvec_left(
    const float* __restrict__ Wm, const float* __restrict__ a, float* __restrict__ v)
{
    int j = threadIdx.x;
    float s = 0.f;
    for (int i = 0; i < NH; ++i) s += a[i] * Wm[(size_t)i * NH + j];
    v[j] = s;
}

// mol GRU combine (f32 hprev/out), gi/gh f16 dense NH3
__global__ __launch_bounds__(256) void gru_combine(
    const _Float16* __restrict__ gi, const _Float16* __restrict__ gh,
    const float* __restrict__ b_ih, const float* __restrict__ b_hh,
    const float* __restrict__ hprev, float* __restrict__ out, int M)
{
    size_t t = (size_t)blockIdx.x * 256 + threadIdx.x;
    if (t >= (size_t)M * 32) return;
    int n = (int)(t >> 5), j0 = ((int)t & 31) * 8;
    size_t b3 = (size_t)n * NH3;
    f16x8 vir = *reinterpret_cast<const f16x8*>(&gi[b3 + j0]);
    f16x8 viz = *reinterpret_cast<const f16x8*>(&gi[b3 + NH + j0]);
    f16x8 vin = *reinterpret_cast<const f16x8*>(&gi[b3 + 2 * NH + j0]);
    f16x8 vhr = *reinterpret_cast<const f16x8*>(&gh[b3 + j0]);
    f16x8 vhz = *reinterpret_cast<const f16x8*>(&gh[b3 + NH + j0]);
    f16x8 vhn = *reinterpret_cast<const f16x8*>(&gh[b3 + 2 * NH + j0]);
    size_t hb = (size_t)n * NH + j0;
#pragma unroll
    for (int q = 0; q < 8; ++q) {
        int j = j0 + q;
        float r = 1.f / (1.f + expf(-((float)vir[q] + b_ih[j] + (float)vhr[q] + b_hh[j])));
        float z = 1.f / (1.f + expf(-((float)viz[q] + b_ih[NH + j] + (float)vhz[q] + b_hh[NH + j])));
        float nn = tanhf((float)vin[q] + b_ih[2 * NH + j] + r * ((float)vhn[q] + b_hh[2 * NH + j]));
        out[hb + q] = fmaxf((1.f - z) * nn + z * hprev[hb + q], 0.f);
    }
}

extern "C" void kernel_launch(void* const* d_in, const int* in_sizes, int n_in,
                              void* d_out, int out_size, void* d_ws, size_t ws_size,
                              hipStream_t stream)
{
    const float* x          = (const float*)d_in[0];
    const float* edge_attr  = (const float*)d_in[1];
    const float* lin1_w     = (const float*)d_in[2];
    const float* lin1_b     = (const float*)d_in[3];
    const float* gate_att_l = (const float*)d_in[4];
    const float* gate_att_r = (const float*)d_in[5];
    const float* gate_lin1_w= (const float*)d_in[6];
    const float* gate_lin2_w= (const float*)d_in[7];
    const float* gate_bias  = (const float*)d_in[8];
    const float* atom_lin_w = (const float*)d_in[9];
    const float* atom_att_src=(const float*)d_in[10];
    const float* atom_att_dst=(const float*)d_in[11];
    const float* atom_bias  = (const float*)d_in[12];
    const float* gru_w_ih   = (const float*)d_in[13];
    const float* gru_w_hh   = (const float*)d_in[14];
    const float* gru_b_ih   = (const float*)d_in[15];
    const float* gru_b_hh   = (const float*)d_in[16];
    const float* mol_lin_w  = (const float*)d_in[17];
    const float* mol_att_src= (const float*)d_in[18];
    const float* mol_att_dst= (const float*)d_in[19];
    const float* mol_bias   = (const float*)d_in[20];
    const float* mol_gru_w_ih=(const float*)d_in[21];
    const float* mol_gru_w_hh=(const float*)d_in[22];
    const float* mol_gru_b_ih=(const float*)d_in[23];
    const float* mol_gru_b_hh=(const float*)d_in[24];
    const float* lin2_w     = (const float*)d_in[25];
    const float* lin2_b     = (const float*)d_in[26];
    const float* fc_w       = (const float*)d_in[27];
    const float* fc_b       = (const float*)d_in[28];
    const int*   edge_index = (const int*)d_in[29];
    const int*   batch      = (const int*)d_in[30];

    const int N = in_sizes[0] / FNODE;
    const int E = in_sizes[1] / FEDGE;
    const int G = NGRAPH;
    const int* src = edge_index;
    const int* dst = edge_index + E;

    float* w = (float*)d_ws;
    size_t o = 0;
    auto alloc = [&](size_t cnt) { size_t r = o; o += cnt; return r; };
    const size_t o_B1cat = alloc((size_t)N * NH);          // f16 N x 512: [tmp | xcur]
    const size_t o_B2    = alloc((size_t)N * NH / 2);      // f16 nodepart -> hraw ; mol f32 bufs
    const size_t o_B3    = alloc((size_t)CHUNK * 512);     // inn(256)+srz(512) f16 ; xpad
    const size_t o_wcat  = alloc((size_t)512 * 512);
    const size_t o_elog  = alloc((size_t)E);
    const size_t o_dotr  = alloc((size_t)N);
    const size_t o_adst  = alloc((size_t)N);
    const size_t o_ddot  = alloc((size_t)G);
    const size_t o_vvec  = alloc((size_t)NH);
    const size_t o_usrc  = alloc((size_t)NH);
    const size_t o_udst  = alloc((size_t)NH);
    const size_t o_rowp  = alloc((size_t)N + 1);
    const size_t o_srowp = alloc((size_t)N + 1);
    const size_t o_deg   = alloc((size_t)N);
    const size_t o_curs  = alloc((size_t)N);
    const size_t o_bsum  = alloc((size_t)512);
    const size_t o_esrc  = alloc((size_t)E);
    const size_t o_pos   = alloc((size_t)E);
    const size_t o_seid  = alloc((size_t)E);
    const size_t o_ecsc  = alloc((size_t)E * 4);           // f16 E x 8
    const size_t o_pcsc  = alloc((size_t)E);
    const size_t o_gptr  = alloc((size_t)G + 1);
    if (o * sizeof(float) > ws_size) {
        fprintf(stderr, "kernel_launch: ws too small: need %zu have %zu\n", o * 4, ws_size);
        return;
    }

    _Float16* B1cat = (_Float16*)(w + o_B1cat);
    _Float16* xcur  = B1cat + NH;          // row stride LDC2, cols 256-511
    _Float16* B2 = (_Float16*)(w + o_B2);
    float* B3   = w + o_B3;
    float* wcat = w + o_wcat;
    float* elog = w + o_elog;
    float* dotr = w + o_dotr;
    float* adst = w + o_adst;
    float* ddot = w + o_ddot;
    float* vvec = w + o_vvec;
    float* usrc = w + o_usrc;
    float* udst = w + o_udst;
    int* rowptr  = (int*)(w + o_rowp);
    int* srowptr = (int*)(w + o_srowp);
    int* deg     = (int*)(w + o_deg);
    int* cursor  = (int*)(w + o_curs);
    int* bsum    = (int*)(w + o_bsum);
    int* boff    = bsum + 256;
    int* esrc    = (int*)(w + o_esrc);
    int* pos     = (int*)(w + o_pos);
    int* seid    = (int*)(w + o_seid);
    _Float16* ecsc = (_Float16*)(w + o_ecsc);
    int* pcsc    = (int*)(w + o_pcsc);
    int* gptr    = (int*)(w + o_gptr);

    // mol-phase f32 sub-buffers inside B2 (node hraw dead by then)
    float* B2f = (float*)B2;
    float*    gout   = B2f;
    float*    hraw_g = B2f + (size_t)G * NH;
    float*    h_g    = B2f + (size_t)2 * G * NH;
    _Float16* gig    = (_Float16*)(B2f + (size_t)3 * G * NH);
    _Float16* ghg    = (_Float16*)(B2f + (size_t)3 * G * NH + (size_t)G * NH3 / 2);
    float*    emb    = B2f + (size_t)3 * G * NH + (size_t)G * NH3;

    const int BLK = 256;
    auto cdiv = [](size_t a, size_t b) { return (int)((a + b - 1) / b); };
    const int gridNodeWave = cdiv(N, 4);
    const int gridEdgeThr = cdiv(E, BLK);
    const int gridNodeThr = cdiv(N, BLK);
    const int CAP = 4096;
    const int gridNodeCap = gridNodeWave < CAP ? gridNodeWave : CAP;
    const int nScanB = cdiv(N, SCAN_TILE);

    auto run_scan = [&](int* rowp) {
        scan_pass1<<<nScanB, BLK, 0, stream>>>(deg, bsum, N);
        scan_pass2<<<1, BLK, 0, stream>>>(bsum, boff, nScanB, rowp + N);
        scan_pass3<<<nScanB, BLK, 0, stream>>>(deg, boff, rowp, cursor, N);
    };

    // ---------- CSR + CSC build (once) ----------
    zero_i32<<<gridNodeThr, BLK, 0, stream>>>(deg, N);
    hist_k<<<gridEdgeThr, BLK, 0, stream>>>(dst, deg, E);
    run_scan(rowptr);
    csr_scatter<<<gridEdgeThr, BLK, 0, stream>>>(src, dst, cursor, esrc, pos, E);
    zero_i32<<<gridNodeThr, BLK, 0, stream>>>(deg, N);
    hist_k<<<gridEdgeThr, BLK, 0, stream>>>(src, deg, E);
    run_scan(srowptr);
    csc_scatter<<<gridEdgeThr, BLK, 0, stream>>>(src, cursor, seid, E);
    edge_csc_build<<<gridEdgeThr, BLK, 0, stream>>>(edge_attr, seid, pos, ecsc, pcsc, E);
    gptr_build<<<cdiv(G + 1, BLK), BLK, 0, stream>>>(batch, gptr, N, G);

    // Per-layer tail: tmp = elu(hraw@Wh^T + bh); GRU via launch A (r,z,inn) + launch B
    // (hn + fused combine + fused next-layer dots into dotr/adst)
    auto run_tail = [&](const float* Wh, const float* bh,
                        const float* wih, const float* whh,
                        const float* bih, const float* bhh,
                        const float* usv, const float* udv) {
        _Float16* innb = (_Float16*)B3;                     // CHUNK*256 f16
        _Float16* srz  = innb + (size_t)CHUNK * NH;         // CHUNK*512 f16
        build_wcat<<<1024, BLK, 0, stream>>>(wih, whh, wcat);
        dim3 gFull(1, cdiv(N, 64));
        gemm_mfma<2, 1, 1><<<gFull, BLK, 0, stream>>>(B2, Wh, bh, B1cat,
                                                      N, NH, NH, NH, NH, LDC2, 0, NH);
        for (int c0 = 0; c0 < N; c0 += CHUNK) {
            int mc = (N - c0) < CHUNK ? (N - c0) : CHUNK;
            dim3 gA(1, cdiv(mc, 64), 3);
            gemm_gru_a<<<gA, BLK, 0, stream>>>(B1cat + (size_t)c0 * LDC2, wcat, wih,
                                               bih, bhh, srz, innb, mc);
            dim3 gB(1, cdiv(mc, 64));
            gemm_gru_b<<<gB, BLK, 0, stream>>>(B1cat + (size_t)c0 * LDC2, whh, bhh,
                                               srz, innb, usv, udv, dotr + c0, adst + c0, mc);
        }
    };

    dim3 gridNH(1, cdiv(N, 64));

    // ---------- x0 = lrelu(x @ lin1_w^T + lin1_b) -> xcur ----------
    _Float16* xpad = (_Float16*)B3;     // N*160 f16 = 32 MB < B3 (51.2 MB); dead before tails
    pad_cast_f16<<<cdiv((size_t)N * KPAD_X, BLK), BLK, 0, stream>>>(x, xpad, N, FNODE, KPAD_X);
    gemm_mfma<1, 1, 1><<<gridNH, BLK, 0, stream>>>(xpad, lin1_w, lin1_b, B1cat,
                                                   N, KPAD_X, NH, KPAD_X, FNODE, LDC2, NH, FNODE);

    // ---------- GATEConv ----------
    gemm_mfma<0, 1, 1><<<gridNH, BLK, 0, stream>>>(xcur, gate_lin1_w, nullptr, B2,
                                                   N, NH, NH, LDC2, LDW_GATE1, NH, 0, NH);
    node_dot<_Float16><<<gridNodeCap, BLK, 0, stream>>>(xcur, LDC2, gate_att_r, nullptr,
                                                        dotr, nullptr, N);
    gate_part_csc<<<gridNodeCap, BLK, 0, stream>>>(B2, ecsc, gate_lin1_w, gate_att_l,
                                                   srowptr, pcsc, elog, N);
    gate_agg_csr<<<gridNodeWave, BLK, 0, stream>>>(xcur, LDC2, elog, dotr, rowptr, esrc, B2, N);
    // next consumer: atom layer 0
    matvec_left<<<1, BLK, 0, stream>>>(atom_lin_w, atom_att_src, usrc);
    matvec_left<<<1, BLK, 0, stream>>>(atom_lin_w, atom_att_dst, udst);
    run_tail(gate_lin2_w, gate_bias, gru_w_ih, gru_w_hh, gru_b_ih, gru_b_hh, usrc, udst);

    // ---------- 3 GATConv layers (dotr/adst pre-computed by previous tail) ----------
    for (int l = 0; l < 3; ++l) {
        const float* wl = atom_lin_w + (size_t)l * NH * NH;
        gat_agg_csr<<<gridNodeWave, BLK, 0, stream>>>(xcur, LDC2, dotr, adst, rowptr, esrc, B2, N);
        const float* nus = usrc;
        const float* nud = udst;
        if (l < 2) {
            matvec_left<<<1, BLK, 0, stream>>>(atom_lin_w + (size_t)(l + 1) * NH * NH,
                                               atom_att_src + (l + 1) * NH, usrc);
            matvec_left<<<1, BLK, 0, stream>>>(atom_lin_w + (size_t)(l + 1) * NH * NH,
                                               atom_att_dst + (l + 1) * NH, udst);
        } else {
            matvec_left<<<1, BLK, 0, stream>>>(mol_lin_w, mol_att_src, usrc);
            nud = nullptr;
        }
        run_tail(wl, atom_bias + l * NH,
                 gru_w_ih + (size_t)(l + 1) * NH3 * NH, gru_w_hh + (size_t)(l + 1) * NH3 * NH,
                 gru_b_ih + (size_t)(l + 1) * NH3, gru_b_hh + (size_t)(l + 1) * NH3, nus, nud);
    }

    // ---------- Molecule pooling (dotr = xcur . mol usrc, fused above) ----------
    const int gridGWave = cdiv(G, 4);
    graph_sum_relu<<<gridGWave, BLK, 0, stream>>>(xcur, LDC2, gptr, gout, G);
    matvec_left<<<1, BLK, 0, stream>>>(mol_lin_w, mol_att_dst, vvec);

    dim3 gridGH(1, cdiv(G, 64));
    dim3 gridGD(3, cdiv(G, 64), 2);
    for (int t = 0; t < 2; ++t) {
        node_dot<float><<<gridGWave, BLK, 0, stream>>>(gout, NH, vvec, nullptr, ddot, nullptr, G);
        mol_agg_csr<<<gridGWave, BLK, 0, stream>>>(xcur, LDC2, dotr, ddot, gptr, hraw_g, G);
        gemm_mfma<2, 0, 0><<<gridGH, BLK, 0, stream>>>(hraw_g, mol_lin_w, mol_bias, h_g,
                                                       G, NH, NH, NH, NH, NH, 0, NH);
        gemm_mfma2<0, 1><<<gridGD, BLK, 0, stream>>>(h_g, gout, mol_gru_w_ih, mol_gru_w_hh,
                                                     gig, ghg, G, NH, NH3);
        gru_combine<<<cdiv((size_t)G * 32, BLK), BLK, 0, stream>>>(
            gig, ghg, mol_gru_b_ih, mol_gru_b_hh, gout, gout, G);
    }

    // ---------- readout ----------
    gemm_mfma<0, 0, 0><<<gridGH, BLK, 0, stream>>>(gout, lin2_w, lin2_b, emb,
                                                   G, NH, NH, NH, NH, NH, 0, NH);
    dim3 gridFc(1, cdiv(G, 64));
    gemm_nt<<<gridFc, BLK, 0, stream>>>(emb, fc_w, fc_b, (float*)d_out, G, NH, NTASK, NH, 0);
}

// Round 13
// 2978.836 us; speedup vs baseline: 2.0793x; 1.1387x over previous
//
#include <hip/hip_runtime.h>
#include <math.h>
#include <stdio.h>
#include <stdint.h>

#define NH 256
#define NH3 768
#define FNODE 133
#define FEDGE 7
#define LDW_GATE1 263   // H + F_EDGE
#define NGRAPH 4096
#define NTASK 12
#define SLOPE 0.01f
#define CHUNK 25000
#define PADK 40         // f16 elems per LDS row: 32 + 8 pad (80B stride, 16B aligned)
#define KPAD_X 160      // x padded K (133 -> 160)
#define LDC2 512        // interleaved node-state row stride (f16): [tmp | xcur]
#define SCAN_TILE 2048

typedef __attribute__((ext_vector_type(4))) float f32x4;
typedef __attribute__((ext_vector_type(8))) _Float16 f16x8;
typedef __attribute__((ext_vector_type(4))) _Float16 f16x4;
typedef __attribute__((ext_vector_type(2))) _Float16 f16x2;

static __device__ __forceinline__ float lrelu_f(float x) { return x > 0.f ? x : SLOPE * x; }
static __device__ __forceinline__ f16x2 lrelu2(f16x2 v) {
    f16x2 z = {(_Float16)0.f, (_Float16)0.f};
    f16x2 s = {(_Float16)SLOPE, (_Float16)SLOPE};
    return __builtin_elementwise_max(v, z) + __builtin_elementwise_min(v, z) * s;
}

// ============ pipelined f16-weight GEMM core (BM=64, BN=256 fixed) ============
// C[M, ocol..ocol+255 (ldC)] = act(A[M,K f16 ldA] @ Wf[256,K f16]^T + bias + bias2)
// ACT: 0 none, 1 lrelu, 2 elu, 3 sigmoid
template<int ACT>
static __device__ __forceinline__ void gemm16_core(
    _Float16* As, _Float16* Ws,
    const _Float16* __restrict__ A, const _Float16* __restrict__ Wf,
    const float* __restrict__ bias, const float* __restrict__ bias2,
    _Float16* __restrict__ Cout,
    int M, int K, int ldA, int ldC, int ocol)
{
    const int bm = blockIdx.y * 64;
    const int tid = threadIdx.x;
    const int wv = tid >> 6, lane = tid & 63;
    const int l15 = lane & 15, l4 = lane >> 4;
    const int ar = tid >> 2, akq = (tid & 3) * 8;
    const int ga = bm + ar;

    f16x8 ra, rw[4];
    auto loadT = [&](int k0) {
        if (ga < M) ra = *reinterpret_cast<const f16x8*>(A + (size_t)ga * ldA + k0 + akq);
        else { f16x8 z = {}; ra = z; }
#pragma unroll
        for (int q = 0; q < 4; ++q)
            rw[q] = *reinterpret_cast<const f16x8*>(Wf + (size_t)(ar + 64 * q) * K + k0 + akq);
    };

    f32x4 acc[16];
#pragma unroll
    for (int c = 0; c < 16; ++c) acc[c] = (f32x4){0.f, 0.f, 0.f, 0.f};

    loadT(0);
    for (int k0 = 0; k0 < K; k0 += 32) {
        *reinterpret_cast<f16x8*>(&As[ar * PADK + akq]) = ra;
#pragma unroll
        for (int q = 0; q < 4; ++q)
            *reinterpret_cast<f16x8*>(&Ws[(ar + 64 * q) * PADK + akq]) = rw[q];
        __syncthreads();
        if (k0 + 32 < K) loadT(k0 + 32);   // in flight across MFMA section
        f16x8 af = *reinterpret_cast<const f16x8*>(&As[(wv * 16 + l15) * PADK + l4 * 8]);
#pragma unroll
        for (int c = 0; c < 16; ++c) {
            f16x8 wf = *reinterpret_cast<const f16x8*>(&Ws[(c * 16 + l15) * PADK + l4 * 8]);
            acc[c] = __builtin_amdgcn_mfma_f32_16x16x32_f16(af, wf, acc[c], 0, 0, 0);
        }
        __syncthreads();
    }

#pragma unroll
    for (int c = 0; c < 16; ++c) {
        int gc = c * 16 + l15;
        float bv = (bias ? bias[gc] : 0.f) + (bias2 ? bias2[gc] : 0.f);
#pragma unroll
        for (int q = 0; q < 4; ++q) {
            int gr = bm + wv * 16 + l4 * 4 + q;
            if (gr >= M) continue;
            float v = acc[c][q] + bv;
            if (ACT == 1) v = lrelu_f(v);
            else if (ACT == 2) v = (v > 0.f ? v : expm1f(v));
            else if (ACT == 3) v = 1.f / (1.f + expf(-v));
            Cout[(size_t)gr * ldC + ocol + gc] = (_Float16)v;
        }
    }
}

template<int ACT>
__global__ __launch_bounds__(256, 4) void gemm16(
    const _Float16* __restrict__ A, const _Float16* __restrict__ Wf,
    const float* __restrict__ bias, _Float16* __restrict__ Cout,
    int M, int K, int ldA, int ldC, int ocol)
{
    __shared__ _Float16 As[64 * PADK];
    __shared__ _Float16 Ws[256 * PADK];
    gemm16_core<ACT>(As, Ws, A, Wf, bias, nullptr, Cout, M, K, ldA, ldC, ocol);
}

// GRU launch A: z=0/1: srz = sigmoid(Acat@wcat16^T + bih + bhh); z=2: inn = tmp@wihn16^T + bih_n
__global__ __launch_bounds__(256, 4) void gemm_gru_a16(
    const _Float16* __restrict__ Acat, const _Float16* __restrict__ wcat16,
    const _Float16* __restrict__ wihn16,
    const float* __restrict__ bih, const float* __restrict__ bhh,
    _Float16* __restrict__ srz, _Float16* __restrict__ innb, int mc)
{
    __shared__ _Float16 As[64 * PADK];
    __shared__ _Float16 Ws[256 * PADK];
    int z = blockIdx.z;
    if (z < 2)
        gemm16_core<3>(As, Ws, Acat, wcat16 + (size_t)z * 256 * 512, bih + z * 256, bhh + z * 256,
                       srz, mc, 512, LDC2, 512, z * 256);
    else
        gemm16_core<0>(As, Ws, Acat, wihn16, bih + 512, nullptr, innb, mc, 256, LDC2, 256, 0);
}

// GRU launch B: hn = xcur @ whhn16^T + bhh_n ; in-epilogue GRU combine + ReLU (xcur in place);
// fused per-row dots with us/ud -> dotr/adst
__global__ __launch_bounds__(256, 4) void gemm_gru_b16(
    _Float16* __restrict__ Acat, const _Float16* __restrict__ Wn16, const float* __restrict__ bhh,
    const _Float16* __restrict__ srz, const _Float16* __restrict__ innb,
    const float* __restrict__ us, const float* __restrict__ ud,
    float* __restrict__ dotr, float* __restrict__ adst, int mc)
{
    __shared__ _Float16 As[64 * PADK];
    __shared__ _Float16 Ws[256 * PADK];
    const int bm = blockIdx.y * 64;
    const int tid = threadIdx.x;
    const int wv = tid >> 6, lane = tid & 63;
    const int l15 = lane & 15, l4 = lane >> 4;
    const int ar = tid >> 2, akq = (tid & 3) * 8;
    const int ga = bm + ar;

    f16x8 ra, rw[4];
    auto loadT = [&](int k0) {
        if (ga < mc) ra = *reinterpret_cast<const f16x8*>(Acat + (size_t)ga * LDC2 + NH + k0 + akq);
        else { f16x8 z = {}; ra = z; }
#pragma unroll
        for (int q = 0; q < 4; ++q)
            rw[q] = *reinterpret_cast<const f16x8*>(Wn16 + (size_t)(ar + 64 * q) * NH + k0 + akq);
    };

    f32x4 acc[16];
#pragma unroll
    for (int c = 0; c < 16; ++c) acc[c] = (f32x4){0.f, 0.f, 0.f, 0.f};

    loadT(0);
    for (int k0 = 0; k0 < NH; k0 += 32) {
        *reinterpret_cast<f16x8*>(&As[ar * PADK + akq]) = ra;
#pragma unroll
        for (int q = 0; q < 4; ++q)
            *reinterpret_cast<f16x8*>(&Ws[(ar + 64 * q) * PADK + akq]) = rw[q];
        __syncthreads();
        if (k0 + 32 < NH) loadT(k0 + 32);
        f16x8 af = *reinterpret_cast<const f16x8*>(&As[(wv * 16 + l15) * PADK + l4 * 8]);
#pragma unroll
        for (int c = 0; c < 16; ++c) {
            f16x8 wf = *reinterpret_cast<const f16x8*>(&Ws[(c * 16 + l15) * PADK + l4 * 8]);
            acc[c] = __builtin_amdgcn_mfma_f32_16x16x32_f16(af, wf, acc[c], 0, 0, 0);
        }
        __syncthreads();
    }

    float pd1[4] = {0.f, 0.f, 0.f, 0.f};
    float pd2[4] = {0.f, 0.f, 0.f, 0.f};
#pragma unroll
    for (int c = 0; c < 16; ++c) {
        int gc = c * 16 + l15;
        float bhn = bhh[512 + gc];
        float usv = us ? us[gc] : 0.f;
        float udv = ud ? ud[gc] : 0.f;
#pragma unroll
        for (int q = 0; q < 4; ++q) {
            int gr = bm + wv * 16 + l4 * 4 + q;
            if (gr >= mc) continue;
            float hn = acc[c][q] + bhn;
            float rr = (float)srz[(size_t)gr * 512 + gc];
            float zz = (float)srz[(size_t)gr * 512 + 256 + gc];
            float inn = (float)innb[(size_t)gr * NH + gc];
            float nn = tanhf(inn + rr * hn);
            size_t xoff = (size_t)gr * LDC2 + NH + gc;
            float xold = (float)Acat[xoff];
            float hv = fmaxf((1.f - zz) * nn + zz * xold, 0.f);
            Acat[xoff] = (_Float16)hv;
            pd1[q] += hv * usv;
            pd2[q] += hv * udv;
        }
    }
    if (us) {
#pragma unroll
        for (int off = 1; off < 16; off <<= 1) {
#pragma unroll
            for (int q = 0; q < 4; ++q) {
                pd1[q] += __shfl_xor(pd1[q], off);
                pd2[q] += __shfl_xor(pd2[q], off);
            }
        }
        if (l15 == 0) {
#pragma unroll
            for (int q = 0; q < 4; ++q) {
                int gr = bm + wv * 16 + l4 * 4 + q;
                if (gr < mc) {
                    dotr[gr] = pd1[q];
                    if (ud) adst[gr] = pd2[q];
                }
            }
        }
    }
}

// ---------------- legacy f32-W MFMA GEMM (mol phase only) ----------------
template<int ACT, int OB, int AF16>
static __device__ __forceinline__ void gemm_core(
    _Float16* As, _Float16* Ws,
    const void* __restrict__ Av, const float* __restrict__ W,
    const float* __restrict__ bias, void* __restrict__ Cout,
    int M, int K, int Nout, int ldA, int ldW, int ldC, int ocol, int Kw, int bn)
{
    const int bm = blockIdx.y * 64;
    const int tid = threadIdx.x;
    const int wv = tid >> 6, lane = tid & 63;
    const int l15 = lane & 15, l4 = lane >> 4;
    const bool kvec = ((K & 31) == 0) && ((ldA & 3) == 0);
    const bool wvec = ((K & 31) == 0) && ((ldW & 3) == 0) && (Kw == K);
    const int ar = tid >> 2, akq = (tid & 3) * 8;

    f32x4 acc[16];
#pragma unroll
    for (int c = 0; c < 16; ++c) acc[c] = (f32x4){0.f, 0.f, 0.f, 0.f};

    for (int k0 = 0; k0 < K; k0 += 32) {
        {
            const int ga = bm + ar;
            _Float16* dstA = &As[ar * PADK + akq];
            if (AF16) {
                const _Float16* A = (const _Float16*)Av;
                if (ga < M) {
                    *reinterpret_cast<f16x8*>(dstA) =
                        *reinterpret_cast<const f16x8*>(A + (size_t)ga * ldA + k0 + akq);
                } else {
#pragma unroll
                    for (int j = 0; j < 8; ++j) dstA[j] = (_Float16)0.f;
                }
            } else {
                const float* A = (const float*)Av;
                if (ga < M && kvec) {
                    const float4* ap4 = reinterpret_cast<const float4*>(A + (size_t)ga * ldA + k0 + akq);
                    float4 v0 = ap4[0], v1 = ap4[1];
                    dstA[0] = (_Float16)v0.x; dstA[1] = (_Float16)v0.y;
                    dstA[2] = (_Float16)v0.z; dstA[3] = (_Float16)v0.w;
                    dstA[4] = (_Float16)v1.x; dstA[5] = (_Float16)v1.y;
                    dstA[6] = (_Float16)v1.z; dstA[7] = (_Float16)v1.w;
                } else {
                    const float* ap = A + (size_t)ga * ldA + k0 + akq;
#pragma unroll
                    for (int j = 0; j < 8; ++j) {
                        int gk = k0 + akq + j;
                        float v = (ga < M && gk < K) ? ap[j] : 0.f;
                        dstA[j] = (_Float16)v;
                    }
                }
            }
        }
#pragma unroll
        for (int q = 0; q < 4; ++q) {
            const int r = ar + 64 * q;
            const int gw = bn + r;
            _Float16* dstW = &Ws[r * PADK + akq];
            if (gw < Nout && wvec) {
                const float4* wp4 = reinterpret_cast<const float4*>(W + (size_t)gw * ldW + k0 + akq);
                float4 v0 = wp4[0], v1 = wp4[1];
                dstW[0] = (_Float16)v0.x; dstW[1] = (_Float16)v0.y;
                dstW[2] = (_Float16)v0.z; dstW[3] = (_Float16)v0.w;
                dstW[4] = (_Float16)v1.x; dstW[5] = (_Float16)v1.y;
                dstW[6] = (_Float16)v1.z; dstW[7] = (_Float16)v1.w;
            } else {
                const float* wp = W + (size_t)gw * ldW + k0 + akq;
#pragma unroll
                for (int j = 0; j < 8; ++j) {
                    int gk = k0 + akq + j;
                    float v = (gw < Nout && gk < Kw) ? wp[j] : 0.f;
                    dstW[j] = (_Float16)v;
                }
            }
        }
        __syncthreads();
        f16x8 af = *reinterpret_cast<const f16x8*>(&As[(wv * 16 + l15) * PADK + l4 * 8]);
#pragma unroll
        for (int c = 0; c < 16; ++c) {
            f16x8 wf = *reinterpret_cast<const f16x8*>(&Ws[(c * 16 + l15) * PADK + l4 * 8]);
            acc[c] = __builtin_amdgcn_mfma_f32_16x16x32_f16(af, wf, acc[c], 0, 0, 0);
        }
        __syncthreads();
    }

#pragma unroll
    for (int c = 0; c < 16; ++c) {
        int gc = bn + c * 16 + l15;
        if (gc >= Nout) continue;
        float bv = bias ? bias[gc] : 0.f;
#pragma unroll
        for (int q = 0; q < 4; ++q) {
            int gr = bm + wv * 16 + l4 * 4 + q;
            if (gr >= M) continue;
            float v = acc[c][q] + bv;
            if (ACT == 1) v = lrelu_f(v);
            else if (ACT == 2) v = (v > 0.f ? v : expm1f(v));
            size_t off = (size_t)gr * ldC + ocol + gc;
            if (OB) ((_Float16*)Cout)[off] = (_Float16)v;
            else    ((float*)Cout)[off] = v;
        }
    }
}

template<int ACT, int OB, int AF16>
__global__ __launch_bounds__(256, 4) void gemm_mfma(
    const void* __restrict__ A, const float* __restrict__ W,
    const float* __restrict__ bias, void* __restrict__ Cout,
    int M, int K, int Nout, int ldA, int ldW, int ldC, int ocol, int Kw)
{
    __shared__ _Float16 As[64 * PADK];
    __shared__ _Float16 Ws[256 * PADK];
    gemm_core<ACT, OB, AF16>(As, Ws, A, W, bias, Cout, M, K, Nout, ldA, ldW, ldC, ocol, Kw,
                             blockIdx.x * 256);
}

template<int ACT, int OB>
__global__ __launch_bounds__(256, 4) void gemm_mfma2(
    const float* __restrict__ A0, const float* __restrict__ A1,
    const float* __restrict__ W0, const float* __restrict__ W1,
    void* __restrict__ C0, void* __restrict__ C1, int M, int K, int Nout)
{
    __shared__ _Float16 As[64 * PADK];
    __shared__ _Float16 Ws[256 * PADK];
    int bn = blockIdx.x * 256;
    if (blockIdx.z == 0)
        gemm_core<ACT, OB, 0>(As, Ws, A0, W0, nullptr, C0, M, K, Nout, K, K, Nout, 0, K, bn);
    else
        gemm_core<ACT, OB, 0>(As, Ws, A1, W1, nullptr, C1, M, K, Nout, K, K, Nout, 0, K, bn);
}

// ---------------- weight conversion (one-time) ----------------
// dst[r][k] (r<rows, k<kout) = k<cols ? (f16)src[r*ldsrc+k] : 0
__global__ void cast_w16(const float* __restrict__ src, _Float16* __restrict__ dst,
                         int rows, int cols, int ldsrc, int kout)
{
    int i = blockIdx.x * 256 + threadIdx.x;
    if (i >= rows * kout) return;
    int r = i / kout, k = i % kout;
    dst[i] = (k < cols) ? (_Float16)src[(size_t)r * ldsrc + k] : (_Float16)0.f;
}
// wcat16[j][k] (512x512 f16): k<256 -> wih[j][k] else whh[j][k-256]
__global__ void build_wcat16(const float* __restrict__ wih, const float* __restrict__ whh,
                             _Float16* __restrict__ dst)
{
    int i = blockIdx.x * 256 + threadIdx.x;
    if (i >= 512 * 512) return;
    int j = i >> 9, k = i & 511;
    dst[i] = (_Float16)((k < 256) ? wih[j * 256 + k] : whh[j * 256 + (k - 256)]);
}

__global__ void pad_cast_f16(const float* __restrict__ in, _Float16* __restrict__ out,
                             int M, int Kin, int Kout)
{
    size_t i = (size_t)blockIdx.x * 256 + threadIdx.x;
    if (i >= (size_t)M * Kout) return;
    int r = (int)(i / Kout), k = (int)(i % Kout);
    out[i] = (k < Kin) ? (_Float16)in[(size_t)r * Kin + k] : (_Float16)0.f;
}

// ---------------- fp32 fallback GEMM (final 12-col fc only) ----------------
__global__ __launch_bounds__(256) void gemm_nt(
    const float* __restrict__ A, const float* __restrict__ W,
    const float* __restrict__ bias, float* __restrict__ C,
    int M, int K, int Nout, int ldW, int act)
{
    __shared__ float As[16][65];
    __shared__ float Ws[16][65];
    const int bm = blockIdx.y * 64;
    const int bn = blockIdx.x * 64;
    const int tid = threadIdx.x;
    const int tr = tid >> 4, tc = tid & 15;
    const int lrow = tid >> 2, lk = (tid & 3) * 4;
    float acc[4][4] = {};
    for (int k0 = 0; k0 < K; k0 += 16) {
#pragma unroll
        for (int j = 0; j < 4; ++j) {
            int gk = k0 + lk + j;
            int ga = bm + lrow;
            As[lk + j][lrow] = (ga < M && gk < K) ? A[(size_t)ga * K + gk] : 0.f;
            int gw = bn + lrow;
            Ws[lk + j][lrow] = (gw < Nout && gk < K) ? W[(size_t)gw * ldW + gk] : 0.f;
        }
        __syncthreads();
#pragma unroll
        for (int kk = 0; kk < 16; ++kk) {
            float av[4], bv[4];
#pragma unroll
            for (int i = 0; i < 4; ++i) av[i] = As[kk][tr * 4 + i];
#pragma unroll
            for (int i = 0; i < 4; ++i) bv[i] = Ws[kk][tc * 4 + i];
#pragma unroll
            for (int i = 0; i < 4; ++i)
#pragma unroll
                for (int j = 0; j < 4; ++j) acc[i][j] += av[i] * bv[j];
        }
        __syncthreads();
    }
#pragma unroll
    for (int i = 0; i < 4; ++i) {
        int m = bm + tr * 4 + i;
        if (m >= M) continue;
#pragma unroll
        for (int j = 0; j < 4; ++j) {
            int n = bn + tc * 4 + j;
            if (n >= Nout) continue;
            float v = acc[i][j];
            if (bias) v += bias[n];
            if (act == 1) v = lrelu_f(v);
            C[(size_t)m * Nout + n] = v;
        }
    }
}

// ---------------- CSR/CSC build ----------------
__global__ void zero_i32(int* p, int n) {
    int i = blockIdx.x * 256 + threadIdx.x;
    if (i < n) p[i] = 0;
}
__global__ void hist_k(const int* __restrict__ key, int* __restrict__ deg, int E) {
    int i = blockIdx.x * 256 + threadIdx.x;
    if (i < E) atomicAdd(&deg[key[i]], 1);
}
__global__ __launch_bounds__(256) void scan_pass1(
    const int* __restrict__ deg, int* __restrict__ bsum, int Nn)
{
    __shared__ int lds[256];
    int b = blockIdx.x, t = threadIdx.x;
    int base = b * SCAN_TILE + t * 8;
    int s = 0;
#pragma unroll
    for (int q = 0; q < 8; ++q) { int i = base + q; if (i < Nn) s += deg[i]; }
    lds[t] = s;
    __syncthreads();
    for (int off = 128; off; off >>= 1) {
        if (t < off) lds[t] += lds[t + off];
        __syncthreads();
    }
    if (t == 0) bsum[b] = lds[0];
}
__global__ __launch_bounds__(256) void scan_pass2(
    const int* __restrict__ bsum, int* __restrict__ boff, int nb, int* __restrict__ total)
{
    __shared__ int lds[256];
    int t = threadIdx.x;
    int v = (t < nb) ? bsum[t] : 0;
    lds[t] = v;
    __syncthreads();
    for (int off = 1; off < 256; off <<= 1) {
        int u = (t >= off) ? lds[t - off] : 0;
        __syncthreads();
        lds[t] += u;
        __syncthreads();
    }
    if (t < nb) boff[t] = lds[t] - v;
    if (t == 255 && total) *total = lds[255];
}
__global__ __launch_bounds__(256) void scan_pass3(
    const int* __restrict__ deg, const int* __restrict__ boff,
    int* __restrict__ rowptr, int* __restrict__ cursor, int Nn)
{
    __shared__ int lds[256];
    int b = blockIdx.x, t = threadIdx.x;
    int base = b * SCAN_TILE + t * 8;
    int v[8];
    int s = 0;
#pragma unroll
    for (int q = 0; q < 8; ++q) { int i = base + q; v[q] = (i < Nn) ? deg[i] : 0; s += v[q]; }
    lds[t] = s;
    __syncthreads();
    for (int off = 1; off < 256; off <<= 1) {
        int u = (t >= off) ? lds[t - off] : 0;
        __syncthreads();
        lds[t] += u;
        __syncthreads();
    }
    int run = boff[b] + lds[t] - s;
#pragma unroll
    for (int q = 0; q < 8; ++q) {
        int i = base + q;
        if (i < Nn) { rowptr[i] = run; cursor[i] = run; run += v[q]; }
    }
}
__global__ void csr_scatter(const int* __restrict__ src, const int* __restrict__ dst,
                            int* __restrict__ cursor, int* __restrict__ esrc,
                            int* __restrict__ pos, int E)
{
    int e = blockIdx.x * 256 + threadIdx.x;
    if (e < E) {
        int p = atomicAdd(&cursor[dst[e]], 1);
        esrc[p] = src[e];
        pos[e] = p;
    }
}
__global__ void csc_scatter(const int* __restrict__ src, int* __restrict__ cursor,
                            int* __restrict__ seid, int E)
{
    int e = blockIdx.x * 256 + threadIdx.x;
    if (e < E) {
        int p = atomicAdd(&cursor[src[e]], 1);
        seid[p] = e;
    }
}
__global__ void edge_csc_build(const float* __restrict__ edge_attr, const int* __restrict__ seid,
                               const int* __restrict__ pos, _Float16* __restrict__ ecsc,
                               int* __restrict__ pcsc, int E)
{
    int p = blockIdx.x * 256 + threadIdx.x;
    if (p >= E) return;
    int e = seid[p];
    pcsc[p] = pos[e];
    const float* ep = edge_attr + (size_t)e * FEDGE;
#pragma unroll
    for (int f = 0; f < FEDGE; ++f) ecsc[(size_t)p * 8 + f] = (_Float16)ep[f];
    ecsc[(size_t)p * 8 + 7] = (_Float16)0.f;
}
__global__ void gptr_build(const int* __restrict__ batch, int* __restrict__ gptr, int Nn, int G) {
    int g = blockIdx.x * 256 + threadIdx.x;
    if (g > G) return;
    int lo = 0, hi = Nn;
    while (lo < hi) { int mid = (lo + hi) >> 1; if (batch[mid] < g) lo = mid + 1; else hi = mid; }
    gptr[g] = lo;
}

// ---------------- GATE src-side partial logit (CSC, packed f16, 4-edge ILP) ----------------
__global__ __launch_bounds__(256) void gate_part_csc(
    const _Float16* __restrict__ nodepart, const _Float16* __restrict__ ecsc,
    const float* __restrict__ gate_lin1_w, const float* __restrict__ att_l,
    const int* __restrict__ srowptr, const int* __restrict__ pcsc,
    float* __restrict__ elogp, int Nn)
{
    int wv = threadIdx.x >> 6, lane = threadIdx.x & 63;
    int h0 = lane * 4;
    f16x2 wr2[2][FEDGE], al2[2];
#pragma unroll
    for (int p = 0; p < 2; ++p) {
        int ha = h0 + 2 * p, hb = ha + 1;
#pragma unroll
        for (int f = 0; f < FEDGE; ++f) {
            wr2[p][f][0] = (_Float16)gate_lin1_w[(size_t)ha * LDW_GATE1 + NH + f];
            wr2[p][f][1] = (_Float16)gate_lin1_w[(size_t)hb * LDW_GATE1 + NH + f];
        }
        al2[p][0] = (_Float16)att_l[ha];
        al2[p][1] = (_Float16)att_l[hb];
    }
    for (int s = blockIdx.x * 4 + wv; s < Nn; s += gridDim.x * 4) {
        int beg = srowptr[s], end = srowptr[s + 1];
        if (beg >= end) continue;
        f16x4 np4 = *reinterpret_cast<const f16x4*>(nodepart + (size_t)s * NH + h0);
        f16x2 np2[2];
        np2[0][0] = np4[0]; np2[0][1] = np4[1];
        np2[1][0] = np4[2]; np2[1][1] = np4[3];
        for (int j0 = beg; j0 < end; j0 += 4) {
            int nb = end - j0; if (nb > 4) nb = 4;
            f16x8 ev[4];
            int pp[4];
#pragma unroll
            for (int k = 0; k < 4; ++k) {
                int j = (k < nb) ? j0 + k : beg;
                pp[k] = pcsc[j];
                ev[k] = *reinterpret_cast<const f16x8*>(ecsc + (size_t)j * 8);
            }
            float acc[4];
#pragma unroll
            for (int k = 0; k < 4; ++k) {
                f16x2 v0 = np2[0], v1 = np2[1];
#pragma unroll
                for (int f = 0; f < FEDGE; ++f) {
                    f16x2 e2; e2[0] = ev[k][f]; e2[1] = ev[k][f];
                    v0 += e2 * wr2[0][f];
                    v1 += e2 * wr2[1][f];
                }
                float a = __builtin_amdgcn_fdot2(lrelu2(v0), al2[0], 0.f, false);
                a = __builtin_amdgcn_fdot2(lrelu2(v1), al2[1], a, false);
                acc[k] = a;
            }
#pragma unroll
            for (int off = 32; off; off >>= 1) {
#pragma unroll
                for (int k = 0; k < 4; ++k) acc[k] += __shfl_xor(acc[k], off);
            }
            if (lane == 0) {
#pragma unroll
                for (int k = 0; k < 4; ++k) if (k < nb) elogp[pp[k]] = acc[k];
            }
        }
    }
}

// ---------------- fused attention aggregation (CSR, wave per dst) ----------------
__global__ __launch_bounds__(256) void gat_agg_csr(
    const _Float16* __restrict__ X, int ldX,
    const float* __restrict__ asrc, const float* __restrict__ adst,
    const int* __restrict__ rowptr, const int* __restrict__ esrc,
    _Float16* __restrict__ hout, int Nn)
{
    int wv = threadIdx.x >> 6, lane = threadIdx.x & 63;
    int d = blockIdx.x * 4 + wv;
    if (d >= Nn) return;
    int beg = rowptr[d], end = rowptr[d + 1];
    float a0 = 0.f, a1 = 0.f, a2 = 0.f, a3 = 0.f;
    if (beg < end) {
        float ad = adst[d];
        float m = -3.4e38f;
        for (int j = beg + lane; j < end; j += 64)
            m = fmaxf(m, lrelu_f(asrc[esrc[j]] + ad));
#pragma unroll
        for (int off = 32; off; off >>= 1) m = fmaxf(m, __shfl_xor(m, off));
        float s = 0.f;
        for (int j = beg + lane; j < end; j += 64)
            s += expf(lrelu_f(asrc[esrc[j]] + ad) - m);
#pragma unroll
        for (int off = 32; off; off >>= 1) s += __shfl_xor(s, off);
        float inv = 1.f / (s + 1e-16f);
        for (int j = beg; j < end; ++j) {
            int sj = esrc[j];
            float a = expf(lrelu_f(asrc[sj] + ad) - m) * inv;
            const _Float16* xr = X + (size_t)sj * ldX;
            a0 += a * (float)xr[lane];       a1 += a * (float)xr[64 + lane];
            a2 += a * (float)xr[128 + lane]; a3 += a * (float)xr[192 + lane];
        }
    }
    _Float16* hr = hout + (size_t)d * NH;
    hr[lane] = (_Float16)a0; hr[64 + lane] = (_Float16)a1;
    hr[128 + lane] = (_Float16)a2; hr[192 + lane] = (_Float16)a3;
}

__global__ __launch_bounds__(256) void gate_agg_csr(
    const _Float16* __restrict__ X, int ldX,
    const float* __restrict__ elogp, const float* __restrict__ dotr,
    const int* __restrict__ rowptr, const int* __restrict__ esrc,
    _Float16* __restrict__ hout, int Nn)
{
    int wv = threadIdx.x >> 6, lane = threadIdx.x & 63;
    int d = blockIdx.x * 4 + wv;
    if (d >= Nn) return;
    int beg = rowptr[d], end = rowptr[d + 1];
    float a0 = 0.f, a1 = 0.f, a2 = 0.f, a3 = 0.f;
    if (beg < end) {
        float dd = dotr[d];
        float m = -3.4e38f;
        for (int j = beg + lane; j < end; j += 64)
            m = fmaxf(m, lrelu_f(elogp[j] + dd));
#pragma unroll
        for (int off = 32; off; off >>= 1) m = fmaxf(m, __shfl_xor(m, off));
        float s = 0.f;
        for (int j = beg + lane; j < end; j += 64)
            s += expf(lrelu_f(elogp[j] + dd) - m);
#pragma unroll
        for (int off = 32; off; off >>= 1) s += __shfl_xor(s, off);
        float inv = 1.f / (s + 1e-16f);
        for (int j = beg; j < end; ++j) {
            int sj = esrc[j];
            float a = expf(lrelu_f(elogp[j] + dd) - m) * inv;
            const _Float16* xr = X + (size_t)sj * ldX;
            a0 += a * (float)xr[lane];       a1 += a * (float)xr[64 + lane];
            a2 += a * (float)xr[128 + lane]; a3 += a * (float)xr[192 + lane];
        }
    }
    _Float16* hr = hout + (size_t)d * NH;
    hr[lane] = (_Float16)a0; hr[64 + lane] = (_Float16)a1;
    hr[128 + lane] = (_Float16)a2; hr[192 + lane] = (_Float16)a3;
}

__global__ __launch_bounds__(256) void mol_agg_csr(
    const _Float16* __restrict__ X, int ldX,
    const float* __restrict__ dotr, const float* __restrict__ ddot,
    const int* __restrict__ gptr, float* __restrict__ hout, int G)
{
    int wv = threadIdx.x >> 6, lane = threadIdx.x & 63;
    int g = blockIdx.x * 4 + wv;
    if (g >= G) return;
    int beg = gptr[g], end = gptr[g + 1];
    float a0 = 0.f, a1 = 0.f, a2 = 0.f, a3 = 0.f;
    if (beg < end) {
        float dg = ddot[g];
        float m = -3.4e38f;
        for (int i = beg + lane; i < end; i += 64)
            m = fmaxf(m, lrelu_f(dotr[i] + dg));
#pragma unroll
        for (int off = 32; off; off >>= 1) m = fmaxf(m, __shfl_xor(m, off));
        float s = 0.f;
        for (int i = beg + lane; i < end; i += 64)
            s += expf(lrelu_f(dotr[i] + dg) - m);
#pragma unroll
        for (int off = 32; off; off >>= 1) s += __shfl_xor(s, off);
        float inv = 1.f / (s + 1e-16f);
        for (int i = beg; i < end; ++i) {
            float a = expf(lrelu_f(dotr[i] + dg) - m) * inv;
            const _Float16* xr = X + (size_t)i * ldX;
            a0 += a * (float)xr[lane];       a1 += a * (float)xr[64 + lane];
            a2 += a * (float)xr[128 + lane]; a3 += a * (float)xr[192 + lane];
        }
    }
    float* hr = hout + (size_t)g * NH;
    hr[lane] = a0; hr[64 + lane] = a1; hr[128 + lane] = a2; hr[192 + lane] = a3;
}

__global__ __launch_bounds__(256) void graph_sum_relu(
    const _Float16* __restrict__ X, int ldX, const int* __restrict__ gptr,
    float* __restrict__ out, int G)
{
    int wv = threadIdx.x >> 6, lane = threadIdx.x & 63;
    int g = blockIdx.x * 4 + wv;
    if (g >= G) return;
    int beg = gptr[g], end = gptr[g + 1];
    float a0 = 0.f, a1 = 0.f, a2 = 0.f, a3 = 0.f;
    for (int i = beg; i < end; ++i) {
        const _Float16* xr = X + (size_t)i * ldX;
        a0 += (float)xr[lane];       a1 += (float)xr[64 + lane];
        a2 += (float)xr[128 + lane]; a3 += (float)xr[192 + lane];
    }
    float* hr = out + (size_t)g * NH;
    hr[lane] = fmaxf(a0, 0.f); hr[64 + lane] = fmaxf(a1, 0.f);
    hr[128 + lane] = fmaxf(a2, 0.f); hr[192 + lane] = fmaxf(a3, 0.f);
}

template<typename TX>
__global__ __launch_bounds__(256) void node_dot(
    const TX* __restrict__ X, int ldX, const float* __restrict__ v1, const float* __restrict__ v2,
    float* __restrict__ o1, float* __restrict__ o2, int M)
{
    __shared__ float s1[NH], s2[NH];
    int tid = threadIdx.x;
    s1[tid] = v1[tid];
    s2[tid] = v2 ? v2[tid] : 0.f;
    __syncthreads();
    int wv = tid >> 6, lane = tid & 63;
    for (int n = blockIdx.x * 4 + wv; n < M; n += gridDim.x * 4) {
        float a1 = 0.f, a2 = 0.f;
#pragma unroll
        for (int i = 0; i < 4; ++i) {
            int hh = i * 64 + lane;
            float xv = (float)X[(size_t)n * ldX + hh];
            a1 += xv * s1[hh];
            a2 += xv * s2[hh];
        }
#pragma unroll
        for (int off = 32; off; off >>= 1) { a1 += __shfl_xor(a1, off); a2 += __shfl_xor(a2, off); }
        if (lane == 0) { o1[n] = a1; if (o2) o2[n] = a2; }
    }
}

__global__ __launch_bounds__(256) void matvec_left(
    const float* __restrict__ Wm, const float* __restrict__ a, float* __restrict__ v)
{
    int j = threadIdx.x;
    float s = 0.f;
    for (int i = 0; i < NH; ++i) s += a[i] * Wm[(size_t)i * NH + j];
    v[j] = s;
}

// mol GRU combine (f32 hprev/out), gi/gh f16 dense NH3
__global__ __launch_bounds__(256) void gru_combine(
    const _Float16* __restrict__ gi, const _Float16* __restrict__ gh,
    const float* __restrict__ b_ih, const float* __restrict__ b_hh,
    const float* __restrict__ hprev, float* __restrict__ out, int M)
{
    size_t t = (size_t)blockIdx.x * 256 + threadIdx.x;
    if (t >= (size_t)M * 32) return;
    int n = (int)(t >> 5), j0 = ((int)t & 31) * 8;
    size_t b3 = (size_t)n * NH3;
    f16x8 vir = *reinterpret_cast<const f16x8*>(&gi[b3 + j0]);
    f16x8 viz = *reinterpret_cast<const f16x8*>(&gi[b3 + NH + j0]);
    f16x8 vin = *reinterpret_cast<const f16x8*>(&gi[b3 + 2 * NH + j0]);
    f16x8 vhr = *reinterpret_cast<const f16x8*>(&gh[b3 + j0]);
    f16x8 vhz = *reinterpret_cast<const f16x8*>(&gh[b3 + NH + j0]);
    f16x8 vhn = *reinterpret_cast<const f16x8*>(&gh[b3 + 2 * NH + j0]);
    size_t hb = (size_t)n * NH + j0;
#pragma unroll
    for (int q = 0; q < 8; ++q) {
        int j = j0 + q;
        float r = 1.f / (1.f + expf(-((float)vir[q] + b_ih[j] + (float)vhr[q] + b_hh[j])));
        float z = 1.f / (1.f + expf(-((float)viz[q] + b_ih[NH + j] + (float)vhz[q] + b_hh[NH + j])));
        float nn = tanhf((float)vin[q] + b_ih[2 * NH + j] + r * ((float)vhn[q] + b_hh[2 * NH + j]));
        out[hb + q] = fmaxf((1.f - z) * nn + z * hprev[hb + q], 0.f);
    }
}

extern "C" void kernel_launch(void* const* d_in, const int* in_sizes, int n_in,
                              void* d_out, int out_size, void* d_ws, size_t ws_size,
                              hipStream_t stream)
{
    const float* x          = (const float*)d_in[0];
    const float* edge_attr  = (const float*)d_in[1];
    const float* lin1_w     = (const float*)d_in[2];
    const float* lin1_b     = (const float*)d_in[3];
    const float* gate_att_l = (const float*)d_in[4];
    const float* gate_att_r = (const float*)d_in[5];
    const float* gate_lin1_w= (const float*)d_in[6];
    const float* gate_lin2_w= (const float*)d_in[7];
    const float* gate_bias  = (const float*)d_in[8];
    const float* atom_lin_w = (const float*)d_in[9];
    const float* atom_att_src=(const float*)d_in[10];
    const float* atom_att_dst=(const float*)d_in[11];
    const float* atom_bias  = (const float*)d_in[12];
    const float* gru_w_ih   = (const float*)d_in[13];
    const float* gru_w_hh   = (const float*)d_in[14];
    const float* gru_b_ih   = (const float*)d_in[15];
    const float* gru_b_hh   = (const float*)d_in[16];
    const float* mol_lin_w  = (const float*)d_in[17];
    const float* mol_att_src= (const float*)d_in[18];
    const float* mol_att_dst= (const float*)d_in[19];
    const float* mol_bias   = (const float*)d_in[20];
    const float* mol_gru_w_ih=(const float*)d_in[21];
    const float* mol_gru_w_hh=(const float*)d_in[22];
    const float* mol_gru_b_ih=(const float*)d_in[23];
    const float* mol_gru_b_hh=(const float*)d_in[24];
    const float* lin2_w     = (const float*)d_in[25];
    const float* lin2_b     = (const float*)d_in[26];
    const float* fc_w       = (const float*)d_in[27];
    const float* fc_b       = (const float*)d_in[28];
    const int*   edge_index = (const int*)d_in[29];
    const int*   batch      = (const int*)d_in[30];

    const int N = in_sizes[0] / FNODE;
    const int E = in_sizes[1] / FEDGE;
    const int G = NGRAPH;
    const int* src = edge_index;
    const int* dst = edge_index + E;

    float* w = (float*)d_ws;
    size_t o = 0;
    auto alloc = [&](size_t cnt) { size_t r = o; o += cnt; return r; };
    const size_t o_B1cat = alloc((size_t)N * NH);          // f16 N x 512: [tmp | xcur]
    const size_t o_B2    = alloc((size_t)N * NH / 2);      // f16 nodepart -> hraw ; mol f32 bufs
    const size_t o_B3    = alloc((size_t)CHUNK * 512);     // inn+srz f16 ; xpad
    const size_t o_w16   = alloc((size_t)972000);          // f16 weight pool (1.944M f16)
    const size_t o_elog  = alloc((size_t)E);
    const size_t o_dotr  = alloc((size_t)N);
    const size_t o_adst  = alloc((size_t)N);
    const size_t o_ddot  = alloc((size_t)G);
    const size_t o_vvec  = alloc((size_t)NH);
    const size_t o_usrc  = alloc((size_t)NH);
    const size_t o_udst  = alloc((size_t)NH);
    const size_t o_rowp  = alloc((size_t)N + 1);
    const size_t o_srowp = alloc((size_t)N + 1);
    const size_t o_deg   = alloc((size_t)N);
    const size_t o_curs  = alloc((size_t)N);
    const size_t o_bsum  = alloc((size_t)512);
    const size_t o_esrc  = alloc((size_t)E);
    const size_t o_pos   = alloc((size_t)E);
    const size_t o_seid  = alloc((size_t)E);
    const size_t o_ecsc  = alloc((size_t)E * 4);
    const size_t o_pcsc  = alloc((size_t)E);
    const size_t o_gptr  = alloc((size_t)G + 1);
    if (o * sizeof(float) > ws_size) {
        fprintf(stderr, "kernel_launch: ws too small: need %zu have %zu\n", o * 4, ws_size);
        return;
    }

    _Float16* B1cat = (_Float16*)(w + o_B1cat);
    _Float16* xcur  = B1cat + NH;
    _Float16* B2 = (_Float16*)(w + o_B2);
    float* B3   = w + o_B3;
    _Float16* w16 = (_Float16*)(w + o_w16);
    // f16 weight pool layout
    _Float16* lin116   = w16;                       // 256*160
    _Float16* gate1a16 = lin116 + 40960;            // 256*256
    _Float16* gate216  = gate1a16 + 65536;          // 256*256
    _Float16* atom16   = gate216 + 65536;           // 3 * 65536
    _Float16* wihn16   = atom16 + 3 * 65536;        // 4 * 65536
    _Float16* whhn16   = wihn16 + 4 * 65536;        // 4 * 65536
    _Float16* wcat16   = whhn16 + 4 * 65536;        // 4 * 262144
    float* elog = w + o_elog;
    float* dotr = w + o_dotr;
    float* adst = w + o_adst;
    float* ddot = w + o_ddot;
    float* vvec = w + o_vvec;
    float* usrc = w + o_usrc;
    float* udst = w + o_udst;
    int* rowptr  = (int*)(w + o_rowp);
    int* srowptr = (int*)(w + o_srowp);
    int* deg     = (int*)(w + o_deg);
    int* cursor  = (int*)(w + o_curs);
    int* bsum    = (int*)(w + o_bsum);
    int* boff    = bsum + 256;
    int* esrc    = (int*)(w + o_esrc);
    int* pos     = (int*)(w + o_pos);
    int* seid    = (int*)(w + o_seid);
    _Float16* ecsc = (_Float16*)(w + o_ecsc);
    int* pcsc    = (int*)(w + o_pcsc);
    int* gptr    = (int*)(w + o_gptr);

    // mol-phase f32 sub-buffers inside B2
    float* B2f = (float*)B2;
    float*    gout   = B2f;
    float*    hraw_g = B2f + (size_t)G * NH;
    float*    h_g    = B2f + (size_t)2 * G * NH;
    _Float16* gig    = (_Float16*)(B2f + (size_t)3 * G * NH);
    _Float16* ghg    = (_Float16*)(B2f + (size_t)3 * G * NH + (size_t)G * NH3 / 2);
    float*    emb    = B2f + (size_t)3 * G * NH + (size_t)G * NH3;

    const int BLK = 256;
    auto cdiv = [](size_t a, size_t b) { return (int)((a + b - 1) / b); };
    const int gridNodeWave = cdiv(N, 4);
    const int gridEdgeThr = cdiv(E, BLK);
    const int gridNodeThr = cdiv(N, BLK);
    const int CAP = 4096;
    const int gridNodeCap = gridNodeWave < CAP ? gridNodeWave : CAP;
    const int nScanB = cdiv(N, SCAN_TILE);

    auto run_scan = [&](int* rowp) {
        scan_pass1<<<nScanB, BLK, 0, stream>>>(deg, bsum, N);
        scan_pass2<<<1, BLK, 0, stream>>>(bsum, boff, nScanB, rowp + N);
        scan_pass3<<<nScanB, BLK, 0, stream>>>(deg, boff, rowp, cursor, N);
    };

    // ---------- weight conversion (one-time) ----------
    cast_w16<<<cdiv(256 * 160, BLK), BLK, 0, stream>>>(lin1_w, lin116, 256, FNODE, FNODE, 160);
    cast_w16<<<cdiv(65536, BLK), BLK, 0, stream>>>(gate_lin1_w, gate1a16, 256, 256, LDW_GATE1, 256);
    cast_w16<<<cdiv(65536, BLK), BLK, 0, stream>>>(gate_lin2_w, gate216, 256, 256, 256, 256);
    for (int l = 0; l < 3; ++l)
        cast_w16<<<cdiv(65536, BLK), BLK, 0, stream>>>(atom_lin_w + (size_t)l * 65536,
                                                       atom16 + (size_t)l * 65536, 256, 256, 256, 256);
    for (int l = 0; l < 4; ++l) {
        const float* wih = gru_w_ih + (size_t)l * NH3 * NH;
        const float* whh = gru_w_hh + (size_t)l * NH3 * NH;
        build_wcat16<<<1024, BLK, 0, stream>>>(wih, whh, wcat16 + (size_t)l * 262144);
        cast_w16<<<cdiv(65536, BLK), BLK, 0, stream>>>(wih + 512 * NH, wihn16 + (size_t)l * 65536,
                                                       256, 256, 256, 256);
        cast_w16<<<cdiv(65536, BLK), BLK, 0, stream>>>(whh + 512 * NH, whhn16 + (size_t)l * 65536,
                                                       256, 256, 256, 256);
    }

    // ---------- CSR + CSC build (once) ----------
    zero_i32<<<gridNodeThr, BLK, 0, stream>>>(deg, N);
    hist_k<<<gridEdgeThr, BLK, 0, stream>>>(dst, deg, E);
    run_scan(rowptr);
    csr_scatter<<<gridEdgeThr, BLK, 0, stream>>>(src, dst, cursor, esrc, pos, E);
    zero_i32<<<gridNodeThr, BLK, 0, stream>>>(deg, N);
    hist_k<<<gridEdgeThr, BLK, 0, stream>>>(src, deg, E);
    run_scan(srowptr);
    csc_scatter<<<gridEdgeThr, BLK, 0, stream>>>(src, cursor, seid, E);
    edge_csc_build<<<gridEdgeThr, BLK, 0, stream>>>(edge_attr, seid, pos, ecsc, pcsc, E);
    gptr_build<<<cdiv(G + 1, BLK), BLK, 0, stream>>>(batch, gptr, N, G);

    // Per-layer tail
    auto run_tail = [&](const _Float16* Wh16, const float* bh, int l,
                        const float* bih, const float* bhh,
                        const float* usv, const float* udv) {
        _Float16* innb = (_Float16*)B3;                 // CHUNK*256 f16
        _Float16* srz  = innb + (size_t)CHUNK * NH;     // CHUNK*512 f16
        dim3 gFull(1, cdiv(N, 64));
        gemm16<2><<<gFull, BLK, 0, stream>>>(B2, Wh16, bh, B1cat, N, NH, NH, LDC2, 0);
        for (int c0 = 0; c0 < N; c0 += CHUNK) {
            int mc = (N - c0) < CHUNK ? (N - c0) : CHUNK;
            dim3 gA(1, cdiv(mc, 64), 3);
            gemm_gru_a16<<<gA, BLK, 0, stream>>>(B1cat + (size_t)c0 * LDC2,
                                                 wcat16 + (size_t)l * 262144,
                                                 wihn16 + (size_t)l * 65536,
                                                 bih, bhh, srz, innb, mc);
            dim3 gB(1, cdiv(mc, 64));
            gemm_gru_b16<<<gB, BLK, 0, stream>>>(B1cat + (size_t)c0 * LDC2,
                                                 whhn16 + (size_t)l * 65536, bhh,
                                                 srz, innb, usv, udv, dotr + c0, adst + c0, mc);
        }
    };

    dim3 gridNH(1, cdiv(N, 64));

    // ---------- x0 = lrelu(x @ lin1^T + b) -> xcur ----------
    _Float16* xpad = (_Float16*)B3;
    pad_cast_f16<<<cdiv((size_t)N * KPAD_X, BLK), BLK, 0, stream>>>(x, xpad, N, FNODE, KPAD_X);
    gemm16<1><<<gridNH, BLK, 0, stream>>>(xpad, lin116, lin1_b, B1cat, N, KPAD_X, KPAD_X, LDC2, NH);

    // ---------- GATEConv ----------
    gemm16<0><<<gridNH, BLK, 0, stream>>>(xcur, gate1a16, nullptr, B2, N, NH, LDC2, NH, 0);
    node_dot<_Float16><<<gridNodeCap, BLK, 0, stream>>>(xcur, LDC2, gate_att_r, nullptr,
                                                        dotr, nullptr, N);
    gate_part_csc<<<gridNodeCap, BLK, 0, stream>>>(B2, ecsc, gate_lin1_w, gate_att_l,
                                                   srowptr, pcsc, elog, N);
    gate_agg_csr<<<gridNodeWave, BLK, 0, stream>>>(xcur, LDC2, elog, dotr, rowptr, esrc, B2, N);
    matvec_left<<<1, BLK, 0, stream>>>(atom_lin_w, atom_att_src, usrc);
    matvec_left<<<1, BLK, 0, stream>>>(atom_lin_w, atom_att_dst, udst);
    run_tail(gate216, gate_bias, 0, gru_b_ih, gru_b_hh, usrc, udst);

    // ---------- 3 GATConv layers ----------
    for (int l = 0; l < 3; ++l) {
        gat_agg_csr<<<gridNodeWave, BLK, 0, stream>>>(xcur, LDC2, dotr, adst, rowptr, esrc, B2, N);
        const float* nus = usrc;
        const float* nud = udst;
        if (l < 2) {
            matvec_left<<<1, BLK, 0, stream>>>(atom_lin_w + (size_t)(l + 1) * NH * NH,
                                               atom_att_src + (l + 1) * NH, usrc);
            matvec_left<<<1, BLK, 0, stream>>>(atom_lin_w + (size_t)(l + 1) * NH * NH,
                                               atom_att_dst + (l + 1) * NH, udst);
        } else {
            matvec_left<<<1, BLK, 0, stream>>>(mol_lin_w, mol_att_src, usrc);
            nud = nullptr;
        }
        run_tail(atom16 + (size_t)l * 65536, atom_bias + l * NH, l + 1,
                 gru_b_ih + (size_t)(l + 1) * NH3, gru_b_hh + (size_t)(l + 1) * NH3, nus, nud);
    }

    // ---------- Molecule pooling ----------
    const int gridGWave = cdiv(G, 4);
    graph_sum_relu<<<gridGWave, BLK, 0, stream>>>(xcur, LDC2, gptr, gout, G);
    matvec_left<<<1, BLK, 0, stream>>>(mol_lin_w, mol_att_dst, vvec);

    dim3 gridGH(1, cdiv(G, 64));
    dim3 gridGD(3, cdiv(G, 64), 2);
    for (int t = 0; t < 2; ++t) {
        node_dot<float><<<gridGWave, BLK, 0, stream>>>(gout, NH, vvec, nullptr, ddot, nullptr, G);
        mol_agg_csr<<<gridGWave, BLK, 0, stream>>>(xcur, LDC2, dotr, ddot, gptr, hraw_g, G);
        gemm_mfma<2, 0, 0><<<gridGH, BLK, 0, stream>>>(hraw_g, mol_lin_w, mol_bias, h_g,
                                                       G, NH, NH, NH, NH, NH, 0, NH);
        gemm_mfma2<0, 1><<<gridGD, BLK, 0, stream>>>(h_g, gout, mol_gru_w_ih, mol_gru_w_hh,
                                                     gig, ghg, G, NH, NH3);
        gru_combine<<<cdiv((size_t)G * 32, BLK), BLK, 0, stream>>>(
            gig, ghg, mol_gru_b_ih, mol_gru_b_hh, gout, gout, G);
    }

    // ---------- readout ----------
    gemm_mfma<0, 0, 0><<<gridGH, BLK, 0, stream>>>(gout, lin2_w, lin2_b, emb,
                                                   G, NH, NH, NH, NH, NH, 0, NH);
    dim3 gridFc(1, cdiv(G, 64));
    gemm_nt<<<gridFc, BLK, 0, stream>>>(emb, fc_w, fc_b, (float*)d_out, G, NH, NTASK, NH, 0);
}

// Round 14
// 2803.904 us; speedup vs baseline: 2.2090x; 1.0624x over previous
//
#include <hip/hip_runtime.h>
#include <math.h>
#include <stdio.h>
#include <stdint.h>

#define NH 256
#define NH3 768
#define FNODE 133
#define FEDGE 7
#define LDW_GATE1 263   // H + F_EDGE
#define NGRAPH 4096
#define NTASK 12
#define SLOPE 0.01f
#define CHUNK 25000
#define PADK 40         // f16 elems per LDS row: 32 + 8 pad (80B stride, 16B aligned)
#define KPAD_X 160      // x padded K (133 -> 160)
#define LDC2 512        // interleaved node-state row stride (f16): [tmp | xcur]
#define SCAN_TILE 2048

typedef __attribute__((ext_vector_type(4))) float f32x4;
typedef __attribute__((ext_vector_type(8))) _Float16 f16x8;
typedef __attribute__((ext_vector_type(4))) _Float16 f16x4;
typedef __attribute__((ext_vector_type(2))) _Float16 f16x2;

static __device__ __forceinline__ float lrelu_f(float x) { return x > 0.f ? x : SLOPE * x; }
static __device__ __forceinline__ f16x2 lrelu2(f16x2 v) {
    f16x2 z = {(_Float16)0.f, (_Float16)0.f};
    f16x2 s = {(_Float16)SLOPE, (_Float16)SLOPE};
    return __builtin_elementwise_max(v, z) + __builtin_elementwise_min(v, z) * s;
}

// ============ pipelined f16-weight GEMM core (BM=64, BN=256 fixed) ============
template<int ACT>
static __device__ __forceinline__ void gemm16_core(
    _Float16* As, _Float16* Ws,
    const _Float16* __restrict__ A, const _Float16* __restrict__ Wf,
    const float* __restrict__ bias, const float* __restrict__ bias2,
    _Float16* __restrict__ Cout,
    int M, int K, int ldA, int ldC, int ocol)
{
    const int bm = blockIdx.y * 64;
    const int tid = threadIdx.x;
    const int wv = tid >> 6, lane = tid & 63;
    const int l15 = lane & 15, l4 = lane >> 4;
    const int ar = tid >> 2, akq = (tid & 3) * 8;
    const int ga = bm + ar;

    f16x8 ra, rw[4];
    auto loadT = [&](int k0) {
        if (ga < M) ra = *reinterpret_cast<const f16x8*>(A + (size_t)ga * ldA + k0 + akq);
        else { f16x8 z = {}; ra = z; }
#pragma unroll
        for (int q = 0; q < 4; ++q)
            rw[q] = *reinterpret_cast<const f16x8*>(Wf + (size_t)(ar + 64 * q) * K + k0 + akq);
    };

    f32x4 acc[16];
#pragma unroll
    for (int c = 0; c < 16; ++c) acc[c] = (f32x4){0.f, 0.f, 0.f, 0.f};

    loadT(0);
    for (int k0 = 0; k0 < K; k0 += 32) {
        *reinterpret_cast<f16x8*>(&As[ar * PADK + akq]) = ra;
#pragma unroll
        for (int q = 0; q < 4; ++q)
            *reinterpret_cast<f16x8*>(&Ws[(ar + 64 * q) * PADK + akq]) = rw[q];
        __syncthreads();
        if (k0 + 32 < K) loadT(k0 + 32);
        f16x8 af = *reinterpret_cast<const f16x8*>(&As[(wv * 16 + l15) * PADK + l4 * 8]);
#pragma unroll
        for (int c = 0; c < 16; ++c) {
            f16x8 wf = *reinterpret_cast<const f16x8*>(&Ws[(c * 16 + l15) * PADK + l4 * 8]);
            acc[c] = __builtin_amdgcn_mfma_f32_16x16x32_f16(af, wf, acc[c], 0, 0, 0);
        }
        __syncthreads();
    }

#pragma unroll
    for (int c = 0; c < 16; ++c) {
        int gc = c * 16 + l15;
        float bv = (bias ? bias[gc] : 0.f) + (bias2 ? bias2[gc] : 0.f);
#pragma unroll
        for (int q = 0; q < 4; ++q) {
            int gr = bm + wv * 16 + l4 * 4 + q;
            if (gr >= M) continue;
            float v = acc[c][q] + bv;
            if (ACT == 1) v = lrelu_f(v);
            else if (ACT == 2) v = (v > 0.f ? v : expm1f(v));
            else if (ACT == 3) v = 1.f / (1.f + expf(-v));
            Cout[(size_t)gr * ldC + ocol + gc] = (_Float16)v;
        }
    }
}

template<int ACT>
__global__ __launch_bounds__(256, 4) void gemm16(
    const _Float16* __restrict__ A, const _Float16* __restrict__ Wf,
    const float* __restrict__ bias, _Float16* __restrict__ Cout,
    int M, int K, int ldA, int ldC, int ocol)
{
    __shared__ _Float16 As[64 * PADK];
    __shared__ _Float16 Ws[256 * PADK];
    gemm16_core<ACT>(As, Ws, A, Wf, bias, nullptr, Cout, M, K, ldA, ldC, ocol);
}

// GRU launch A: z=0/1: srz = sigmoid(Acat@wcat16^T + bih + bhh); z=2: inn = tmp@wihn16^T + bih_n
__global__ __launch_bounds__(256, 4) void gemm_gru_a16(
    const _Float16* __restrict__ Acat, const _Float16* __restrict__ wcat16,
    const _Float16* __restrict__ wihn16,
    const float* __restrict__ bih, const float* __restrict__ bhh,
    _Float16* __restrict__ srz, _Float16* __restrict__ innb, int mc)
{
    __shared__ _Float16 As[64 * PADK];
    __shared__ _Float16 Ws[256 * PADK];
    int z = blockIdx.z;
    if (z < 2)
        gemm16_core<3>(As, Ws, Acat, wcat16 + (size_t)z * 256 * 512, bih + z * 256, bhh + z * 256,
                       srz, mc, 512, LDC2, 512, z * 256);
    else
        gemm16_core<0>(As, Ws, Acat, wihn16, bih + 512, nullptr, innb, mc, 256, LDC2, 256, 0);
}

// GRU launch B: hn GEMM + in-epilogue GRU combine + ReLU (xcur in place) + fused dots
__global__ __launch_bounds__(256, 4) void gemm_gru_b16(
    _Float16* __restrict__ Acat, const _Float16* __restrict__ Wn16, const float* __restrict__ bhh,
    const _Float16* __restrict__ srz, const _Float16* __restrict__ innb,
    const float* __restrict__ us, const float* __restrict__ ud,
    float* __restrict__ dotr, float* __restrict__ adst, int mc)
{
    __shared__ _Float16 As[64 * PADK];
    __shared__ _Float16 Ws[256 * PADK];
    const int bm = blockIdx.y * 64;
    const int tid = threadIdx.x;
    const int wv = tid >> 6, lane = tid & 63;
    const int l15 = lane & 15, l4 = lane >> 4;
    const int ar = tid >> 2, akq = (tid & 3) * 8;
    const int ga = bm + ar;

    f16x8 ra, rw[4];
    auto loadT = [&](int k0) {
        if (ga < mc) ra = *reinterpret_cast<const f16x8*>(Acat + (size_t)ga * LDC2 + NH + k0 + akq);
        else { f16x8 z = {}; ra = z; }
#pragma unroll
        for (int q = 0; q < 4; ++q)
            rw[q] = *reinterpret_cast<const f16x8*>(Wn16 + (size_t)(ar + 64 * q) * NH + k0 + akq);
    };

    f32x4 acc[16];
#pragma unroll
    for (int c = 0; c < 16; ++c) acc[c] = (f32x4){0.f, 0.f, 0.f, 0.f};

    loadT(0);
    for (int k0 = 0; k0 < NH; k0 += 32) {
        *reinterpret_cast<f16x8*>(&As[ar * PADK + akq]) = ra;
#pragma unroll
        for (int q = 0; q < 4; ++q)
            *reinterpret_cast<f16x8*>(&Ws[(ar + 64 * q) * PADK + akq]) = rw[q];
        __syncthreads();
        if (k0 + 32 < NH) loadT(k0 + 32);
        f16x8 af = *reinterpret_cast<const f16x8*>(&As[(wv * 16 + l15) * PADK + l4 * 8]);
#pragma unroll
        for (int c = 0; c < 16; ++c) {
            f16x8 wf = *reinterpret_cast<const f16x8*>(&Ws[(c * 16 + l15) * PADK + l4 * 8]);
            acc[c] = __builtin_amdgcn_mfma_f32_16x16x32_f16(af, wf, acc[c], 0, 0, 0);
        }
        __syncthreads();
    }

    float pd1[4] = {0.f, 0.f, 0.f, 0.f};
    float pd2[4] = {0.f, 0.f, 0.f, 0.f};
#pragma unroll
    for (int c = 0; c < 16; ++c) {
        int gc = c * 16 + l15;
        float bhn = bhh[512 + gc];
        float usv = us ? us[gc] : 0.f;
        float udv = ud ? ud[gc] : 0.f;
#pragma unroll
        for (int q = 0; q < 4; ++q) {
            int gr = bm + wv * 16 + l4 * 4 + q;
            if (gr >= mc) continue;
            float hn = acc[c][q] + bhn;
            float rr = (float)srz[(size_t)gr * 512 + gc];
            float zz = (float)srz[(size_t)gr * 512 + 256 + gc];
            float inn = (float)innb[(size_t)gr * NH + gc];
            float nn = tanhf(inn + rr * hn);
            size_t xoff = (size_t)gr * LDC2 + NH + gc;
            float xold = (float)Acat[xoff];
            float hv = fmaxf((1.f - zz) * nn + zz * xold, 0.f);
            Acat[xoff] = (_Float16)hv;
            pd1[q] += hv * usv;
            pd2[q] += hv * udv;
        }
    }
    if (us) {
#pragma unroll
        for (int off = 1; off < 16; off <<= 1) {
#pragma unroll
            for (int q = 0; q < 4; ++q) {
                pd1[q] += __shfl_xor(pd1[q], off);
                pd2[q] += __shfl_xor(pd2[q], off);
            }
        }
        if (l15 == 0) {
#pragma unroll
            for (int q = 0; q < 4; ++q) {
                int gr = bm + wv * 16 + l4 * 4 + q;
                if (gr < mc) {
                    dotr[gr] = pd1[q];
                    if (ud) adst[gr] = pd2[q];
                }
            }
        }
    }
}

// ---------------- legacy f32-W MFMA GEMM (mol phase only) ----------------
template<int ACT, int OB, int AF16>
static __device__ __forceinline__ void gemm_core(
    _Float16* As, _Float16* Ws,
    const void* __restrict__ Av, const float* __restrict__ W,
    const float* __restrict__ bias, void* __restrict__ Cout,
    int M, int K, int Nout, int ldA, int ldW, int ldC, int ocol, int Kw, int bn)
{
    const int bm = blockIdx.y * 64;
    const int tid = threadIdx.x;
    const int wv = tid >> 6, lane = tid & 63;
    const int l15 = lane & 15, l4 = lane >> 4;
    const bool kvec = ((K & 31) == 0) && ((ldA & 3) == 0);
    const bool wvec = ((K & 31) == 0) && ((ldW & 3) == 0) && (Kw == K);
    const int ar = tid >> 2, akq = (tid & 3) * 8;

    f32x4 acc[16];
#pragma unroll
    for (int c = 0; c < 16; ++c) acc[c] = (f32x4){0.f, 0.f, 0.f, 0.f};

    for (int k0 = 0; k0 < K; k0 += 32) {
        {
            const int ga = bm + ar;
            _Float16* dstA = &As[ar * PADK + akq];
            if (AF16) {
                const _Float16* A = (const _Float16*)Av;
                if (ga < M) {
                    *reinterpret_cast<f16x8*>(dstA) =
                        *reinterpret_cast<const f16x8*>(A + (size_t)ga * ldA + k0 + akq);
                } else {
#pragma unroll
                    for (int j = 0; j < 8; ++j) dstA[j] = (_Float16)0.f;
                }
            } else {
                const float* A = (const float*)Av;
                if (ga < M && kvec) {
                    const float4* ap4 = reinterpret_cast<const float4*>(A + (size_t)ga * ldA + k0 + akq);
                    float4 v0 = ap4[0], v1 = ap4[1];
                    dstA[0] = (_Float16)v0.x; dstA[1] = (_Float16)v0.y;
                    dstA[2] = (_Float16)v0.z; dstA[3] = (_Float16)v0.w;
                    dstA[4] = (_Float16)v1.x; dstA[5] = (_Float16)v1.y;
                    dstA[6] = (_Float16)v1.z; dstA[7] = (_Float16)v1.w;
                } else {
                    const float* ap = A + (size_t)ga * ldA + k0 + akq;
#pragma unroll
                    for (int j = 0; j < 8; ++j) {
                        int gk = k0 + akq + j;
                        float v = (ga < M && gk < K) ? ap[j] : 0.f;
                        dstA[j] = (_Float16)v;
                    }
                }
            }
        }
#pragma unroll
        for (int q = 0; q < 4; ++q) {
            const int r = ar + 64 * q;
            const int gw = bn + r;
            _Float16* dstW = &Ws[r * PADK + akq];
            if (gw < Nout && wvec) {
                const float4* wp4 = reinterpret_cast<const float4*>(W + (size_t)gw * ldW + k0 + akq);
                float4 v0 = wp4[0], v1 = wp4[1];
                dstW[0] = (_Float16)v0.x; dstW[1] = (_Float16)v0.y;
                dstW[2] = (_Float16)v0.z; dstW[3] = (_Float16)v0.w;
                dstW[4] = (_Float16)v1.x; dstW[5] = (_Float16)v1.y;
                dstW[6] = (_Float16)v1.z; dstW[7] = (_Float16)v1.w;
            } else {
                const float* wp = W + (size_t)gw * ldW + k0 + akq;
#pragma unroll
                for (int j = 0; j < 8; ++j) {
                    int gk = k0 + akq + j;
                    float v = (gw < Nout && gk < Kw) ? wp[j] : 0.f;
                    dstW[j] = (_Float16)v;
                }
            }
        }
        __syncthreads();
        f16x8 af = *reinterpret_cast<const f16x8*>(&As[(wv * 16 + l15) * PADK + l4 * 8]);
#pragma unroll
        for (int c = 0; c < 16; ++c) {
            f16x8 wf = *reinterpret_cast<const f16x8*>(&Ws[(c * 16 + l15) * PADK + l4 * 8]);
            acc[c] = __builtin_amdgcn_mfma_f32_16x16x32_f16(af, wf, acc[c], 0, 0, 0);
        }
        __syncthreads();
    }

#pragma unroll
    for (int c = 0; c < 16; ++c) {
        int gc = bn + c * 16 + l15;
        if (gc >= Nout) continue;
        float bv = bias ? bias[gc] : 0.f;
#pragma unroll
        for (int q = 0; q < 4; ++q) {
            int gr = bm + wv * 16 + l4 * 4 + q;
            if (gr >= M) continue;
            float v = acc[c][q] + bv;
            if (ACT == 1) v = lrelu_f(v);
            else if (ACT == 2) v = (v > 0.f ? v : expm1f(v));
            size_t off = (size_t)gr * ldC + ocol + gc;
            if (OB) ((_Float16*)Cout)[off] = (_Float16)v;
            else    ((float*)Cout)[off] = v;
        }
    }
}

template<int ACT, int OB, int AF16>
__global__ __launch_bounds__(256, 4) void gemm_mfma(
    const void* __restrict__ A, const float* __restrict__ W,
    const float* __restrict__ bias, void* __restrict__ Cout,
    int M, int K, int Nout, int ldA, int ldW, int ldC, int ocol, int Kw)
{
    __shared__ _Float16 As[64 * PADK];
    __shared__ _Float16 Ws[256 * PADK];
    gemm_core<ACT, OB, AF16>(As, Ws, A, W, bias, Cout, M, K, Nout, ldA, ldW, ldC, ocol, Kw,
                             blockIdx.x * 256);
}

template<int ACT, int OB>
__global__ __launch_bounds__(256, 4) void gemm_mfma2(
    const float* __restrict__ A0, const float* __restrict__ A1,
    const float* __restrict__ W0, const float* __restrict__ W1,
    void* __restrict__ C0, void* __restrict__ C1, int M, int K, int Nout)
{
    __shared__ _Float16 As[64 * PADK];
    __shared__ _Float16 Ws[256 * PADK];
    int bn = blockIdx.x * 256;
    if (blockIdx.z == 0)
        gemm_core<ACT, OB, 0>(As, Ws, A0, W0, nullptr, C0, M, K, Nout, K, K, Nout, 0, K, bn);
    else
        gemm_core<ACT, OB, 0>(As, Ws, A1, W1, nullptr, C1, M, K, Nout, K, K, Nout, 0, K, bn);
}

// ---------------- weight conversion (one-time) ----------------
__global__ void cast_w16(const float* __restrict__ src, _Float16* __restrict__ dst,
                         int rows, int cols, int ldsrc, int kout)
{
    int i = blockIdx.x * 256 + threadIdx.x;
    if (i >= rows * kout) return;
    int r = i / kout, k = i % kout;
    dst[i] = (k < cols) ? (_Float16)src[(size_t)r * ldsrc + k] : (_Float16)0.f;
}
__global__ void build_wcat16(const float* __restrict__ wih, const float* __restrict__ whh,
                             _Float16* __restrict__ dst)
{
    int i = blockIdx.x * 256 + threadIdx.x;
    if (i >= 512 * 512) return;
    int j = i >> 9, k = i & 511;
    dst[i] = (_Float16)((k < 256) ? wih[j * 256 + k] : whh[j * 256 + (k - 256)]);
}

__global__ void pad_cast_f16(const float* __restrict__ in, _Float16* __restrict__ out,
                             int M, int Kin, int Kout)
{
    size_t i = (size_t)blockIdx.x * 256 + threadIdx.x;
    if (i >= (size_t)M * Kout) return;
    int r = (int)(i / Kout), k = (int)(i % Kout);
    out[i] = (k < Kin) ? (_Float16)in[(size_t)r * Kin + k] : (_Float16)0.f;
}

// ---------------- fp32 fallback GEMM (final 12-col fc only) ----------------
__global__ __launch_bounds__(256) void gemm_nt(
    const float* __restrict__ A, const float* __restrict__ W,
    const float* __restrict__ bias, float* __restrict__ C,
    int M, int K, int Nout, int ldW, int act)
{
    __shared__ float As[16][65];
    __shared__ float Ws[16][65];
    const int bm = blockIdx.y * 64;
    const int bn = blockIdx.x * 64;
    const int tid = threadIdx.x;
    const int tr = tid >> 4, tc = tid & 15;
    const int lrow = tid >> 2, lk = (tid & 3) * 4;
    float acc[4][4] = {};
    for (int k0 = 0; k0 < K; k0 += 16) {
#pragma unroll
        for (int j = 0; j < 4; ++j) {
            int gk = k0 + lk + j;
            int ga = bm + lrow;
            As[lk + j][lrow] = (ga < M && gk < K) ? A[(size_t)ga * K + gk] : 0.f;
            int gw = bn + lrow;
            Ws[lk + j][lrow] = (gw < Nout && gk < K) ? W[(size_t)gw * ldW + gk] : 0.f;
        }
        __syncthreads();
#pragma unroll
        for (int kk = 0; kk < 16; ++kk) {
            float av[4], bv[4];
#pragma unroll
            for (int i = 0; i < 4; ++i) av[i] = As[kk][tr * 4 + i];
#pragma unroll
            for (int i = 0; i < 4; ++i) bv[i] = Ws[kk][tc * 4 + i];
#pragma unroll
            for (int i = 0; i < 4; ++i)
#pragma unroll
                for (int j = 0; j < 4; ++j) acc[i][j] += av[i] * bv[j];
        }
        __syncthreads();
    }
#pragma unroll
    for (int i = 0; i < 4; ++i) {
        int m = bm + tr * 4 + i;
        if (m >= M) continue;
#pragma unroll
        for (int j = 0; j < 4; ++j) {
            int n = bn + tc * 4 + j;
            if (n >= Nout) continue;
            float v = acc[i][j];
            if (bias) v += bias[n];
            if (act == 1) v = lrelu_f(v);
            C[(size_t)m * Nout + n] = v;
        }
    }
}

// ---------------- CSR/CSC build ----------------
__global__ void zero_i32(int* p, int n) {
    int i = blockIdx.x * 256 + threadIdx.x;
    if (i < n) p[i] = 0;
}
__global__ void hist_k(const int* __restrict__ key, int* __restrict__ deg, int E) {
    int i = blockIdx.x * 256 + threadIdx.x;
    if (i < E) atomicAdd(&deg[key[i]], 1);
}
__global__ __launch_bounds__(256) void scan_pass1(
    const int* __restrict__ deg, int* __restrict__ bsum, int Nn)
{
    __shared__ int lds[256];
    int b = blockIdx.x, t = threadIdx.x;
    int base = b * SCAN_TILE + t * 8;
    int s = 0;
#pragma unroll
    for (int q = 0; q < 8; ++q) { int i = base + q; if (i < Nn) s += deg[i]; }
    lds[t] = s;
    __syncthreads();
    for (int off = 128; off; off >>= 1) {
        if (t < off) lds[t] += lds[t + off];
        __syncthreads();
    }
    if (t == 0) bsum[b] = lds[0];
}
__global__ __launch_bounds__(256) void scan_pass2(
    const int* __restrict__ bsum, int* __restrict__ boff, int nb, int* __restrict__ total)
{
    __shared__ int lds[256];
    int t = threadIdx.x;
    int v = (t < nb) ? bsum[t] : 0;
    lds[t] = v;
    __syncthreads();
    for (int off = 1; off < 256; off <<= 1) {
        int u = (t >= off) ? lds[t - off] : 0;
        __syncthreads();
        lds[t] += u;
        __syncthreads();
    }
    if (t < nb) boff[t] = lds[t] - v;
    if (t == 255 && total) *total = lds[255];
}
__global__ __launch_bounds__(256) void scan_pass3(
    const int* __restrict__ deg, const int* __restrict__ boff,
    int* __restrict__ rowptr, int* __restrict__ cursor, int Nn)
{
    __shared__ int lds[256];
    int b = blockIdx.x, t = threadIdx.x;
    int base = b * SCAN_TILE + t * 8;
    int v[8];
    int s = 0;
#pragma unroll
    for (int q = 0; q < 8; ++q) { int i = base + q; v[q] = (i < Nn) ? deg[i] : 0; s += v[q]; }
    lds[t] = s;
    __syncthreads();
    for (int off = 1; off < 256; off <<= 1) {
        int u = (t >= off) ? lds[t - off] : 0;
        __syncthreads();
        lds[t] += u;
        __syncthreads();
    }
    int run = boff[b] + lds[t] - s;
#pragma unroll
    for (int q = 0; q < 8; ++q) {
        int i = base + q;
        if (i < Nn) { rowptr[i] = run; cursor[i] = run; run += v[q]; }
    }
}
__global__ void csr_scatter(const int* __restrict__ src, const int* __restrict__ dst,
                            int* __restrict__ cursor, int* __restrict__ esrc,
                            int* __restrict__ pos, int E)
{
    int e = blockIdx.x * 256 + threadIdx.x;
    if (e < E) {
        int p = atomicAdd(&cursor[dst[e]], 1);
        esrc[p] = src[e];
        pos[e] = p;
    }
}
__global__ void csc_scatter(const int* __restrict__ src, int* __restrict__ cursor,
                            int* __restrict__ seid, int E)
{
    int e = blockIdx.x * 256 + threadIdx.x;
    if (e < E) {
        int p = atomicAdd(&cursor[src[e]], 1);
        seid[p] = e;
    }
}
__global__ void edge_csc_build(const float* __restrict__ edge_attr, const int* __restrict__ seid,
                               const int* __restrict__ pos, _Float16* __restrict__ ecsc,
                               int* __restrict__ pcsc, int E)
{
    int p = blockIdx.x * 256 + threadIdx.x;
    if (p >= E) return;
    int e = seid[p];
    pcsc[p] = pos[e];
    const float* ep = edge_attr + (size_t)e * FEDGE;
#pragma unroll
    for (int f = 0; f < FEDGE; ++f) ecsc[(size_t)p * 8 + f] = (_Float16)ep[f];
    ecsc[(size_t)p * 8 + 7] = (_Float16)0.f;
}
__global__ void gptr_build(const int* __restrict__ batch, int* __restrict__ gptr, int Nn, int G) {
    int g = blockIdx.x * 256 + threadIdx.x;
    if (g > G) return;
    int lo = 0, hi = Nn;
    while (lo < hi) { int mid = (lo + hi) >> 1; if (batch[mid] < g) lo = mid + 1; else hi = mid; }
    gptr[g] = lo;
}

// ---------------- GATE src-side partial logit (CSC, packed f16, 4-edge ILP) ----------------
__global__ __launch_bounds__(256) void gate_part_csc(
    const _Float16* __restrict__ nodepart, const _Float16* __restrict__ ecsc,
    const float* __restrict__ gate_lin1_w, const float* __restrict__ att_l,
    const int* __restrict__ srowptr, const int* __restrict__ pcsc,
    float* __restrict__ elogp, int Nn)
{
    int wv = threadIdx.x >> 6, lane = threadIdx.x & 63;
    int h0 = lane * 4;
    f16x2 wr2[2][FEDGE], al2[2];
#pragma unroll
    for (int p = 0; p < 2; ++p) {
        int ha = h0 + 2 * p, hb = ha + 1;
#pragma unroll
        for (int f = 0; f < FEDGE; ++f) {
            wr2[p][f][0] = (_Float16)gate_lin1_w[(size_t)ha * LDW_GATE1 + NH + f];
            wr2[p][f][1] = (_Float16)gate_lin1_w[(size_t)hb * LDW_GATE1 + NH + f];
        }
        al2[p][0] = (_Float16)att_l[ha];
        al2[p][1] = (_Float16)att_l[hb];
    }
    for (int s = blockIdx.x * 4 + wv; s < Nn; s += gridDim.x * 4) {
        int beg = srowptr[s], end = srowptr[s + 1];
        if (beg >= end) continue;
        f16x4 np4 = *reinterpret_cast<const f16x4*>(nodepart + (size_t)s * NH + h0);
        f16x2 np2[2];
        np2[0][0] = np4[0]; np2[0][1] = np4[1];
        np2[1][0] = np4[2]; np2[1][1] = np4[3];
        for (int j0 = beg; j0 < end; j0 += 4) {
            int nb = end - j0; if (nb > 4) nb = 4;
            f16x8 ev[4];
            int pp[4];
#pragma unroll
            for (int k = 0; k < 4; ++k) {
                int j = (k < nb) ? j0 + k : beg;
                pp[k] = pcsc[j];
                ev[k] = *reinterpret_cast<const f16x8*>(ecsc + (size_t)j * 8);
            }
            float acc[4];
#pragma unroll
            for (int k = 0; k < 4; ++k) {
                f16x2 v0 = np2[0], v1 = np2[1];
#pragma unroll
                for (int f = 0; f < FEDGE; ++f) {
                    f16x2 e2; e2[0] = ev[k][f]; e2[1] = ev[k][f];
                    v0 += e2 * wr2[0][f];
                    v1 += e2 * wr2[1][f];
                }
                float a = __builtin_amdgcn_fdot2(lrelu2(v0), al2[0], 0.f, false);
                a = __builtin_amdgcn_fdot2(lrelu2(v1), al2[1], a, false);
                acc[k] = a;
            }
#pragma unroll
            for (int off = 32; off; off >>= 1) {
#pragma unroll
                for (int k = 0; k < 4; ++k) acc[k] += __shfl_xor(acc[k], off);
            }
            if (lane == 0) {
#pragma unroll
                for (int k = 0; k < 4; ++k) if (k < nb) elogp[pp[k]] = acc[k];
            }
        }
    }
}

// ---------------- fused attention aggregation (CSR, wave per dst, LDS alpha cache) ----------------
// lane owns output cols 4*lane .. 4*lane+3 ; single f16x4 gather per edge
__global__ __launch_bounds__(256) void gat_agg_csr(
    const _Float16* __restrict__ X, int ldX,
    const float* __restrict__ asrc, const float* __restrict__ adst,
    const int* __restrict__ rowptr, const int* __restrict__ esrc,
    _Float16* __restrict__ hout, int Nn)
{
    __shared__ float salpha[4][64];
    int wv = threadIdx.x >> 6, lane = threadIdx.x & 63;
    int d = blockIdx.x * 4 + wv;
    if (d >= Nn) return;
    int beg = rowptr[d], end = rowptr[d + 1];
    float a0 = 0.f, a1 = 0.f, a2 = 0.f, a3 = 0.f, ssum = 0.f;
    if (beg < end) {
        float ad = adst[d];
        float m = -3.4e38f;
        for (int j = beg + lane; j < end; j += 64)
            m = fmaxf(m, lrelu_f(asrc[esrc[j]] + ad));
#pragma unroll
        for (int off = 32; off; off >>= 1) m = fmaxf(m, __shfl_xor(m, off));
        for (int c0 = beg; c0 < end; c0 += 64) {
            int j = c0 + lane;
            float e = (j < end) ? expf(lrelu_f(asrc[esrc[j]] + ad) - m) : 0.f;
            salpha[wv][lane] = e;
            ssum += e;
            int cend = end - c0; if (cend > 64) cend = 64;
            for (int k = 0; k < cend; ++k) {
                float alk = salpha[wv][k];
                int sj = esrc[c0 + k];
                f16x4 xv = *reinterpret_cast<const f16x4*>(X + (size_t)sj * ldX + lane * 4);
                a0 += alk * (float)xv[0]; a1 += alk * (float)xv[1];
                a2 += alk * (float)xv[2]; a3 += alk * (float)xv[3];
            }
        }
#pragma unroll
        for (int off = 32; off; off >>= 1) ssum += __shfl_xor(ssum, off);
        float inv = 1.f / (ssum + 1e-16f);
        a0 *= inv; a1 *= inv; a2 *= inv; a3 *= inv;
    }
    f16x4 o;
    o[0] = (_Float16)a0; o[1] = (_Float16)a1; o[2] = (_Float16)a2; o[3] = (_Float16)a3;
    *reinterpret_cast<f16x4*>(hout + (size_t)d * NH + lane * 4) = o;
}

__global__ __launch_bounds__(256) void gate_agg_csr(
    const _Float16* __restrict__ X, int ldX,
    const float* __restrict__ elogp, const float* __restrict__ dotr,
    const int* __restrict__ rowptr, const int* __restrict__ esrc,
    _Float16* __restrict__ hout, int Nn)
{
    __shared__ float salpha[4][64];
    int wv = threadIdx.x >> 6, lane = threadIdx.x & 63;
    int d = blockIdx.x * 4 + wv;
    if (d >= Nn) return;
    int beg = rowptr[d], end = rowptr[d + 1];
    float a0 = 0.f, a1 = 0.f, a2 = 0.f, a3 = 0.f, ssum = 0.f;
    if (beg < end) {
        float dd = dotr[d];
        float m = -3.4e38f;
        for (int j = beg + lane; j < end; j += 64)
            m = fmaxf(m, lrelu_f(elogp[j] + dd));
#pragma unroll
        for (int off = 32; off; off >>= 1) m = fmaxf(m, __shfl_xor(m, off));
        for (int c0 = beg; c0 < end; c0 += 64) {
            int j = c0 + lane;
            float e = (j < end) ? expf(lrelu_f(elogp[j] + dd) - m) : 0.f;
            salpha[wv][lane] = e;
            ssum += e;
            int cend = end - c0; if (cend > 64) cend = 64;
            for (int k = 0; k < cend; ++k) {
                float alk = salpha[wv][k];
                int sj = esrc[c0 + k];
                f16x4 xv = *reinterpret_cast<const f16x4*>(X + (size_t)sj * ldX + lane * 4);
                a0 += alk * (float)xv[0]; a1 += alk * (float)xv[1];
                a2 += alk * (float)xv[2]; a3 += alk * (float)xv[3];
            }
        }
#pragma unroll
        for (int off = 32; off; off >>= 1) ssum += __shfl_xor(ssum, off);
        float inv = 1.f / (ssum + 1e-16f);
        a0 *= inv; a1 *= inv; a2 *= inv; a3 *= inv;
    }
    f16x4 o;
    o[0] = (_Float16)a0; o[1] = (_Float16)a1; o[2] = (_Float16)a2; o[3] = (_Float16)a3;
    *reinterpret_cast<f16x4*>(hout + (size_t)d * NH + lane * 4) = o;
}

__global__ __launch_bounds__(256) void mol_agg_csr(
    const _Float16* __restrict__ X, int ldX,
    const float* __restrict__ dotr, const float* __restrict__ ddot,
    const int* __restrict__ gptr, float* __restrict__ hout, int G)
{
    __shared__ float salpha[4][64];
    int wv = threadIdx.x >> 6, lane = threadIdx.x & 63;
    int g = blockIdx.x * 4 + wv;
    if (g >= G) return;
    int beg = gptr[g], end = gptr[g + 1];
    float a0 = 0.f, a1 = 0.f, a2 = 0.f, a3 = 0.f, ssum = 0.f;
    if (beg < end) {
        float dg = ddot[g];
        float m = -3.4e38f;
        for (int i = beg + lane; i < end; i += 64)
            m = fmaxf(m, lrelu_f(dotr[i] + dg));
#pragma unroll
        for (int off = 32; off; off >>= 1) m = fmaxf(m, __shfl_xor(m, off));
        for (int c0 = beg; c0 < end; c0 += 64) {
            int i = c0 + lane;
            float e = (i < end) ? expf(lrelu_f(dotr[i] + dg) - m) : 0.f;
            salpha[wv][lane] = e;
            ssum += e;
            int cend = end - c0; if (cend > 64) cend = 64;
            for (int k = 0; k < cend; ++k) {
                float alk = salpha[wv][k];
                f16x4 xv = *reinterpret_cast<const f16x4*>(X + (size_t)(c0 + k) * ldX + lane * 4);
                a0 += alk * (float)xv[0]; a1 += alk * (float)xv[1];
                a2 += alk * (float)xv[2]; a3 += alk * (float)xv[3];
            }
        }
#pragma unroll
        for (int off = 32; off; off >>= 1) ssum += __shfl_xor(ssum, off);
        float inv = 1.f / (ssum + 1e-16f);
        a0 *= inv; a1 *= inv; a2 *= inv; a3 *= inv;
    }
    float* hr = hout + (size_t)g * NH + lane * 4;
    hr[0] = a0; hr[1] = a1; hr[2] = a2; hr[3] = a3;
}

__global__ __launch_bounds__(256) void graph_sum_relu(
    const _Float16* __restrict__ X, int ldX, const int* __restrict__ gptr,
    float* __restrict__ out, int G)
{
    int wv = threadIdx.x >> 6, lane = threadIdx.x & 63;
    int g = blockIdx.x * 4 + wv;
    if (g >= G) return;
    int beg = gptr[g], end = gptr[g + 1];
    float a0 = 0.f, a1 = 0.f, a2 = 0.f, a3 = 0.f;
    for (int i = beg; i < end; ++i) {
        f16x4 xv = *reinterpret_cast<const f16x4*>(X + (size_t)i * ldX + lane * 4);
        a0 += (float)xv[0]; a1 += (float)xv[1]; a2 += (float)xv[2]; a3 += (float)xv[3];
    }
    float* hr = out + (size_t)g * NH + lane * 4;
    hr[0] = fmaxf(a0, 0.f); hr[1] = fmaxf(a1, 0.f);
    hr[2] = fmaxf(a2, 0.f); hr[3] = fmaxf(a3, 0.f);
}

template<typename TX>
__global__ __launch_bounds__(256) void node_dot(
    const TX* __restrict__ X, int ldX, const float* __restrict__ v1, const float* __restrict__ v2,
    float* __restrict__ o1, float* __restrict__ o2, int M)
{
    __shared__ float s1[NH], s2[NH];
    int tid = threadIdx.x;
    s1[tid] = v1[tid];
    s2[tid] = v2 ? v2[tid] : 0.f;
    __syncthreads();
    int wv = tid >> 6, lane = tid & 63;
    for (int n = blockIdx.x * 4 + wv; n < M; n += gridDim.x * 4) {
        float a1 = 0.f, a2 = 0.f;
#pragma unroll
        for (int i = 0; i < 4; ++i) {
            int hh = i * 64 + lane;
            float xv = (float)X[(size_t)n * ldX + hh];
            a1 += xv * s1[hh];
            a2 += xv * s2[hh];
        }
#pragma unroll
        for (int off = 32; off; off >>= 1) { a1 += __shfl_xor(a1, off); a2 += __shfl_xor(a2, off); }
        if (lane == 0) { o1[n] = a1; if (o2) o2[n] = a2; }
    }
}

__global__ __launch_bounds__(256) void matvec_left(
    const float* __restrict__ Wm, const float* __restrict__ a, float* __restrict__ v)
{
    int j = threadIdx.x;
    float s = 0.f;
    for (int i = 0; i < NH; ++i) s += a[i] * Wm[(size_t)i * NH + j];
    v[j] = s;
}

// mol GRU combine (f32 hprev/out), gi/gh f16 dense NH3
__global__ __launch_bounds__(256) void gru_combine(
    const _Float16* __restrict__ gi, const _Float16* __restrict__ gh,
    const float* __restrict__ b_ih, const float* __restrict__ b_hh,
    const float* __restrict__ hprev, float* __restrict__ out, int M)
{
    size_t t = (size_t)blockIdx.x * 256 + threadIdx.x;
    if (t >= (size_t)M * 32) return;
    int n = (int)(t >> 5), j0 = ((int)t & 31) * 8;
    size_t b3 = (size_t)n * NH3;
    f16x8 vir = *reinterpret_cast<const f16x8*>(&gi[b3 + j0]);
    f16x8 viz = *reinterpret_cast<const f16x8*>(&gi[b3 + NH + j0]);
    f16x8 vin = *reinterpret_cast<const f16x8*>(&gi[b3 + 2 * NH + j0]);
    f16x8 vhr = *reinterpret_cast<const f16x8*>(&gh[b3 + j0]);
    f16x8 vhz = *reinterpret_cast<const f16x8*>(&gh[b3 + NH + j0]);
    f16x8 vhn = *reinterpret_cast<const f16x8*>(&gh[b3 + 2 * NH + j0]);
    size_t hb = (size_t)n * NH + j0;
#pragma unroll
    for (int q = 0; q < 8; ++q) {
        int j = j0 + q;
        float r = 1.f / (1.f + expf(-((float)vir[q] + b_ih[j] + (float)vhr[q] + b_hh[j])));
        float z = 1.f / (1.f + expf(-((float)viz[q] + b_ih[NH + j] + (float)vhz[q] + b_hh[NH + j])));
        float nn = tanhf((float)vin[q] + b_ih[2 * NH + j] + r * ((float)vhn[q] + b_hh[2 * NH + j]));
        out[hb + q] = fmaxf((1.f - z) * nn + z * hprev[hb + q], 0.f);
    }
}

extern "C" void kernel_launch(void* const* d_in, const int* in_sizes, int n_in,
                              void* d_out, int out_size, void* d_ws, size_t ws_size,
                              hipStream_t stream)
{
    const float* x          = (const float*)d_in[0];
    const float* edge_attr  = (const float*)d_in[1];
    const float* lin1_w     = (const float*)d_in[2];
    const float* lin1_b     = (const float*)d_in[3];
    const float* gate_att_l = (const float*)d_in[4];
    const float* gate_att_r = (const float*)d_in[5];
    const float* gate_lin1_w= (const float*)d_in[6];
    const float* gate_lin2_w= (const float*)d_in[7];
    const float* gate_bias  = (const float*)d_in[8];
    const float* atom_lin_w = (const float*)d_in[9];
    const float* atom_att_src=(const float*)d_in[10];
    const float* atom_att_dst=(const float*)d_in[11];
    const float* atom_bias  = (const float*)d_in[12];
    const float* gru_w_ih   = (const float*)d_in[13];
    const float* gru_w_hh   = (const float*)d_in[14];
    const float* gru_b_ih   = (const float*)d_in[15];
    const float* gru_b_hh   = (const float*)d_in[16];
    const float* mol_lin_w  = (const float*)d_in[17];
    const float* mol_att_src= (const float*)d_in[18];
    const float* mol_att_dst= (const float*)d_in[19];
    const float* mol_bias   = (const float*)d_in[20];
    const float* mol_gru_w_ih=(const float*)d_in[21];
    const float* mol_gru_w_hh=(const float*)d_in[22];
    const float* mol_gru_b_ih=(const float*)d_in[23];
    const float* mol_gru_b_hh=(const float*)d_in[24];
    const float* lin2_w     = (const float*)d_in[25];
    const float* lin2_b     = (const float*)d_in[26];
    const float* fc_w       = (const float*)d_in[27];
    const float* fc_b       = (const float*)d_in[28];
    const int*   edge_index = (const int*)d_in[29];
    const int*   batch      = (const int*)d_in[30];

    const int N = in_sizes[0] / FNODE;
    const int E = in_sizes[1] / FEDGE;
    const int G = NGRAPH;
    const int* src = edge_index;
    const int* dst = edge_index + E;

    float* w = (float*)d_ws;
    size_t o = 0;
    auto alloc = [&](size_t cnt) { size_t r = o; o += cnt; return r; };
    const size_t o_B1cat = alloc((size_t)N * NH);          // f16 N x 512: [tmp | xcur]
    const size_t o_B2    = alloc((size_t)N * NH / 2);      // f16 nodepart -> hraw ; mol f32 bufs
    const size_t o_B3    = alloc((size_t)CHUNK * 512);     // inn+srz f16 ; xpad
    const size_t o_w16   = alloc((size_t)972000);          // f16 weight pool
    const size_t o_elog  = alloc((size_t)E);
    const size_t o_dotr  = alloc((size_t)N);
    const size_t o_adst  = alloc((size_t)N);
    const size_t o_ddot  = alloc((size_t)G);
    const size_t o_vvec  = alloc((size_t)NH);
    const size_t o_usrc  = alloc((size_t)NH);
    const size_t o_udst  = alloc((size_t)NH);
    const size_t o_rowp  = alloc((size_t)N + 1);
    const size_t o_srowp = alloc((size_t)N + 1);
    const size_t o_deg   = alloc((size_t)N);
    const size_t o_curs  = alloc((size_t)N);
    const size_t o_bsum  = alloc((size_t)512);
    const size_t o_esrc  = alloc((size_t)E);
    const size_t o_pos   = alloc((size_t)E);
    const size_t o_seid  = alloc((size_t)E);
    const size_t o_ecsc  = alloc((size_t)E * 4);
    const size_t o_pcsc  = alloc((size_t)E);
    const size_t o_gptr  = alloc((size_t)G + 1);
    if (o * sizeof(float) > ws_size) {
        fprintf(stderr, "kernel_launch: ws too small: need %zu have %zu\n", o * 4, ws_size);
        return;
    }

    _Float16* B1cat = (_Float16*)(w + o_B1cat);
    _Float16* xcur  = B1cat + NH;
    _Float16* B2 = (_Float16*)(w + o_B2);
    float* B3   = w + o_B3;
    _Float16* w16 = (_Float16*)(w + o_w16);
    _Float16* lin116   = w16;                       // 256*160
    _Float16* gate1a16 = lin116 + 40960;            // 256*256
    _Float16* gate216  = gate1a16 + 65536;          // 256*256
    _Float16* atom16   = gate216 + 65536;           // 3 * 65536
    _Float16* wihn16   = atom16 + 3 * 65536;        // 4 * 65536
    _Float16* whhn16   = wihn16 + 4 * 65536;        // 4 * 65536
    _Float16* wcat16   = whhn16 + 4 * 65536;        // 4 * 262144
    float* elog = w + o_elog;
    float* dotr = w + o_dotr;
    float* adst = w + o_adst;
    float* ddot = w + o_ddot;
    float* vvec = w + o_vvec;
    float* usrc = w + o_usrc;
    float* udst = w + o_udst;
    int* rowptr  = (int*)(w + o_rowp);
    int* srowptr = (int*)(w + o_srowp);
    int* deg     = (int*)(w + o_deg);
    int* cursor  = (int*)(w + o_curs);
    int* bsum    = (int*)(w + o_bsum);
    int* boff    = bsum + 256;
    int* esrc    = (int*)(w + o_esrc);
    int* pos     = (int*)(w + o_pos);
    int* seid    = (int*)(w + o_seid);
    _Float16* ecsc = (_Float16*)(w + o_ecsc);
    int* pcsc    = (int*)(w + o_pcsc);
    int* gptr    = (int*)(w + o_gptr);

    // mol-phase f32 sub-buffers inside B2
    float* B2f = (float*)B2;
    float*    gout   = B2f;
    float*    hraw_g = B2f + (size_t)G * NH;
    float*    h_g    = B2f + (size_t)2 * G * NH;
    _Float16* gig    = (_Float16*)(B2f + (size_t)3 * G * NH);
    _Float16* ghg    = (_Float16*)(B2f + (size_t)3 * G * NH + (size_t)G * NH3 / 2);
    float*    emb    = B2f + (size_t)3 * G * NH + (size_t)G * NH3;

    const int BLK = 256;
    auto cdiv = [](size_t a, size_t b) { return (int)((a + b - 1) / b); };
    const int gridNodeWave = cdiv(N, 4);
    const int gridEdgeThr = cdiv(E, BLK);
    const int gridNodeThr = cdiv(N, BLK);
    const int CAP = 4096;
    const int gridNodeCap = gridNodeWave < CAP ? gridNodeWave : CAP;
    const int nScanB = cdiv(N, SCAN_TILE);

    auto run_scan = [&](int* rowp) {
        scan_pass1<<<nScanB, BLK, 0, stream>>>(deg, bsum, N);
        scan_pass2<<<1, BLK, 0, stream>>>(bsum, boff, nScanB, rowp + N);
        scan_pass3<<<nScanB, BLK, 0, stream>>>(deg, boff, rowp, cursor, N);
    };

    // ---------- weight conversion (one-time) ----------
    cast_w16<<<cdiv(256 * 160, BLK), BLK, 0, stream>>>(lin1_w, lin116, 256, FNODE, FNODE, 160);
    cast_w16<<<cdiv(65536, BLK), BLK, 0, stream>>>(gate_lin1_w, gate1a16, 256, 256, LDW_GATE1, 256);
    cast_w16<<<cdiv(65536, BLK), BLK, 0, stream>>>(gate_lin2_w, gate216, 256, 256, 256, 256);
    for (int l = 0; l < 3; ++l)
        cast_w16<<<cdiv(65536, BLK), BLK, 0, stream>>>(atom_lin_w + (size_t)l * 65536,
                                                       atom16 + (size_t)l * 65536, 256, 256, 256, 256);
    for (int l = 0; l < 4; ++l) {
        const float* wih = gru_w_ih + (size_t)l * NH3 * NH;
        const float* whh = gru_w_hh + (size_t)l * NH3 * NH;
        build_wcat16<<<1024, BLK, 0, stream>>>(wih, whh, wcat16 + (size_t)l * 262144);
        cast_w16<<<cdiv(65536, BLK), BLK, 0, stream>>>(wih + 512 * NH, wihn16 + (size_t)l * 65536,
                                                       256, 256, 256, 256);
        cast_w16<<<cdiv(65536, BLK), BLK, 0, stream>>>(whh + 512 * NH, whhn16 + (size_t)l * 65536,
                                                       256, 256, 256, 256);
    }

    // ---------- CSR + CSC build (once) ----------
    zero_i32<<<gridNodeThr, BLK, 0, stream>>>(deg, N);
    hist_k<<<gridEdgeThr, BLK, 0, stream>>>(dst, deg, E);
    run_scan(rowptr);
    csr_scatter<<<gridEdgeThr, BLK, 0, stream>>>(src, dst, cursor, esrc, pos, E);
    zero_i32<<<gridNodeThr, BLK, 0, stream>>>(deg, N);
    hist_k<<<gridEdgeThr, BLK, 0, stream>>>(src, deg, E);
    run_scan(srowptr);
    csc_scatter<<<gridEdgeThr, BLK, 0, stream>>>(src, cursor, seid, E);
    edge_csc_build<<<gridEdgeThr, BLK, 0, stream>>>(edge_attr, seid, pos, ecsc, pcsc, E);
    gptr_build<<<cdiv(G + 1, BLK), BLK, 0, stream>>>(batch, gptr, N, G);

    // Per-layer tail
    auto run_tail = [&](const _Float16* Wh16, const float* bh, int l,
                        const float* bih, const float* bhh,
                        const float* usv, const float* udv) {
        _Float16* innb = (_Float16*)B3;                 // CHUNK*256 f16
        _Float16* srz  = innb + (size_t)CHUNK * NH;     // CHUNK*512 f16
        dim3 gFull(1, cdiv(N, 64));
        gemm16<2><<<gFull, BLK, 0, stream>>>(B2, Wh16, bh, B1cat, N, NH, NH, LDC2, 0);
        for (int c0 = 0; c0 < N; c0 += CHUNK) {
            int mc = (N - c0) < CHUNK ? (N - c0) : CHUNK;
            dim3 gA(1, cdiv(mc, 64), 3);
            gemm_gru_a16<<<gA, BLK, 0, stream>>>(B1cat + (size_t)c0 * LDC2,
                                                 wcat16 + (size_t)l * 262144,
                                                 wihn16 + (size_t)l * 65536,
                                                 bih, bhh, srz, innb, mc);
            dim3 gB(1, cdiv(mc, 64));
            gemm_gru_b16<<<gB, BLK, 0, stream>>>(B1cat + (size_t)c0 * LDC2,
                                                 whhn16 + (size_t)l * 65536, bhh,
                                                 srz, innb, usv, udv, dotr + c0, adst + c0, mc);
        }
    };

    dim3 gridNH(1, cdiv(N, 64));

    // ---------- x0 = lrelu(x @ lin1^T + b) -> xcur ----------
    _Float16* xpad = (_Float16*)B3;
    pad_cast_f16<<<cdiv((size_t)N * KPAD_X, BLK), BLK, 0, stream>>>(x, xpad, N, FNODE, KPAD_X);
    gemm16<1><<<gridNH, BLK, 0, stream>>>(xpad, lin116, lin1_b, B1cat, N, KPAD_X, KPAD_X, LDC2, NH);

    // ---------- GATEConv ----------
    gemm16<0><<<gridNH, BLK, 0, stream>>>(xcur, gate1a16, nullptr, B2, N, NH, LDC2, NH, 0);
    node_dot<_Float16><<<gridNodeCap, BLK, 0, stream>>>(xcur, LDC2, gate_att_r, nullptr,
                                                        dotr, nullptr, N);
    gate_part_csc<<<gridNodeCap, BLK, 0, stream>>>(B2, ecsc, gate_lin1_w, gate_att_l,
                                                   srowptr, pcsc, elog, N);
    gate_agg_csr<<<gridNodeWave, BLK, 0, stream>>>(xcur, LDC2, elog, dotr, rowptr, esrc, B2, N);
    matvec_left<<<1, BLK, 0, stream>>>(atom_lin_w, atom_att_src, usrc);
    matvec_left<<<1, BLK, 0, stream>>>(atom_lin_w, atom_att_dst, udst);
    run_tail(gate216, gate_bias, 0, gru_b_ih, gru_b_hh, usrc, udst);

    // ---------- 3 GATConv layers ----------
    for (int l = 0; l < 3; ++l) {
        gat_agg_csr<<<gridNodeWave, BLK, 0, stream>>>(xcur, LDC2, dotr, adst, rowptr, esrc, B2, N);
        const float* nus = usrc;
        const float* nud = udst;
        if (l < 2) {
            matvec_left<<<1, BLK, 0, stream>>>(atom_lin_w + (size_t)(l + 1) * NH * NH,
                                               atom_att_src + (l + 1) * NH, usrc);
            matvec_left<<<1, BLK, 0, stream>>>(atom_lin_w + (size_t)(l + 1) * NH * NH,
                                               atom_att_dst + (l + 1) * NH, udst);
        } else {
            matvec_left<<<1, BLK, 0, stream>>>(mol_lin_w, mol_att_src, usrc);
            nud = nullptr;
        }
        run_tail(atom16 + (size_t)l * 65536, atom_bias + l * NH, l + 1,
                 gru_b_ih + (size_t)(l + 1) * NH3, gru_b_hh + (size_t)(l + 1) * NH3, nus, nud);
    }

    // ---------- Molecule pooling ----------
    const int gridGWave = cdiv(G, 4);
    graph_sum_relu<<<gridGWave, BLK, 0, stream>>>(xcur, LDC2, gptr, gout, G);
    matvec_left<<<1, BLK, 0, stream>>>(mol_lin_w, mol_att_dst, vvec);

    dim3 gridGH(1, cdiv(G, 64));
    dim3 gridGD(3, cdiv(G, 64), 2);
    for (int t = 0; t < 2; ++t) {
        node_dot<float><<<gridGWave, BLK, 0, stream>>>(gout, NH, vvec, nullptr, ddot, nullptr, G);
        mol_agg_csr<<<gridGWave, BLK, 0, stream>>>(xcur, LDC2, dotr, ddot, gptr, hraw_g, G);
        gemm_mfma<2, 0, 0><<<gridGH, BLK, 0, stream>>>(hraw_g, mol_lin_w, mol_bias, h_g,
                                                       G, NH, NH, NH, NH, NH, 0, NH);
        gemm_mfma2<0, 1><<<gridGD, BLK, 0, stream>>>(h_g, gout, mol_gru_w_ih, mol_gru_w_hh,
                                                     gig, ghg, G, NH, NH3);
        gru_combine<<<cdiv((size_t)G * 32, BLK), BLK, 0, stream>>>(
            gig, ghg, mol_gru_b_ih, mol_gru_b_hh, gout, gout, G);
    }

    // ---------- readout ----------
    gemm_mfma<0, 0, 0><<<gridGH, BLK, 0, stream>>>(gout, lin2_w, lin2_b, emb,
                                                   G, NH, NH, NH, NH, NH, 0, NH);
    dim3 gridFc(1, cdiv(G, 64));
    gemm_nt<<<gridFc, BLK, 0, stream>>>(emb, fc_w, fc_b, (float*)d_out, G, NH, NTASK, NH, 0);
}